// Round 3
// baseline (3437.768 us; speedup 1.0000x reference)
//
#include <hip/hip_runtime.h>

constexpr int NU_ = 200000, NI_ = 100000;
constexpr int E_UB = 1000000, E_IU = 1000000, E_II = 500000;
constexpr int SXS = 136;  // LDS row stride (floats) for 128-wide rows, padded

// ================= CSR build =================
__global__ void deg_kernel(const int* __restrict__ dst, int E, int* __restrict__ deg) {
    int i = blockIdx.x * blockDim.x + threadIdx.x;
    if (i < E) atomicAdd(&deg[dst[i]], 1);
}

// per-block (1024 elems) sums
__global__ void scanA_kernel(const int* __restrict__ deg, int N, int* __restrict__ bsum) {
    __shared__ int s[256];
    int b = blockIdx.x, t = threadIdx.x;
    int base = b * 1024 + t * 4;
    int v = 0;
#pragma unroll
    for (int j = 0; j < 4; ++j) { int i = base + j; if (i < N) v += deg[i]; }
    s[t] = v; __syncthreads();
    for (int off = 1; off < 256; off <<= 1) {
        int x = (t >= off) ? s[t - off] : 0;
        __syncthreads();
        s[t] += x;
        __syncthreads();
    }
    if (t == 255) bsum[b] = s[255];
}

// single-block exclusive scan of block sums (nb <= 256)
__global__ void scanB_kernel(int* __restrict__ bsum, int nb) {
    __shared__ int s[256];
    int t = threadIdx.x;
    int v = (t < nb) ? bsum[t] : 0;
    s[t] = v; __syncthreads();
    for (int off = 1; off < 256; off <<= 1) {
        int x = (t >= off) ? s[t - off] : 0;
        __syncthreads();
        s[t] += x;
        __syncthreads();
    }
    if (t < nb) bsum[t] = s[t] - v;  // exclusive
}

__global__ void scanC_kernel(const int* __restrict__ deg, int N, const int* __restrict__ boff,
                             int* __restrict__ rp, int E) {
    __shared__ int s[256];
    int b = blockIdx.x, t = threadIdx.x;
    int base = b * 1024 + t * 4;
    int d[4]; int v = 0;
#pragma unroll
    for (int j = 0; j < 4; ++j) { int i = base + j; d[j] = (i < N) ? deg[i] : 0; v += d[j]; }
    s[t] = v; __syncthreads();
    for (int off = 1; off < 256; off <<= 1) {
        int x = (t >= off) ? s[t - off] : 0;
        __syncthreads();
        s[t] += x;
        __syncthreads();
    }
    int ex = boff[b] + s[t] - v;
#pragma unroll
    for (int j = 0; j < 4; ++j) { int i = base + j; if (i < N) rp[i] = ex; ex += d[j]; }
    if (b == 0 && t == 0) rp[N] = E;
}

__global__ void inv_from_deg(const int* __restrict__ deg, float* __restrict__ inv, int N) {
    int i = blockIdx.x * blockDim.x + threadIdx.x;
    if (i < N) inv[i] = 1.0f / fmaxf((float)deg[i], 1.0f);
}

__global__ void fill_kernel(const int* __restrict__ src, const int* __restrict__ dst, int E,
                            const int* __restrict__ rp, int* __restrict__ cur, int* __restrict__ col) {
    int e = blockIdx.x * blockDim.x + threadIdx.x;
    if (e < E) {
        int d = dst[e];
        int p = atomicAdd(&cur[d], 1);
        col[rp[d] + p] = src[e];
    }
}

// ================= fused update building blocks =================
// Block = 256 threads, 32 dst rows. Gather mapping: (r = tid>>3 row, cg = tid&7).
// GEMM mapping: (rg = tid>>5 -> rows rg*4..+4, cq = tid&31 -> cols cq*CPT..).

// mean-aggregate neighbors of 32 nodes into sX[32][SXS] (row length K)
template<int K>
__device__ inline void gather_avg(const float* __restrict__ xsrc,
                                  const int* __restrict__ rp, const int* __restrict__ col,
                                  const float* __restrict__ inv,
                                  int rowBase, int N, float* sX) {
    const int tid = threadIdx.x;
    const int r = tid >> 3, cg = tid & 7;
    constexpr int F4 = K / 32;  // float4s per thread
    float4 a[F4];
#pragma unroll
    for (int j = 0; j < F4; ++j) a[j] = make_float4(0.f, 0.f, 0.f, 0.f);
    const int node = rowBase + r;
    if (node < N) {
        int s = rp[node], e = rp[node + 1];
        // unrolled x2 for memory-level parallelism
        for (; s + 2 <= e; s += 2) {
            int c0 = col[s], c1 = col[s + 1];
            const float4* r0 = reinterpret_cast<const float4*>(xsrc + (size_t)c0 * K);
            const float4* r1 = reinterpret_cast<const float4*>(xsrc + (size_t)c1 * K);
            float4 v0[F4], v1[F4];
#pragma unroll
            for (int j = 0; j < F4; ++j) { v0[j] = r0[cg + 8 * j]; v1[j] = r1[cg + 8 * j]; }
#pragma unroll
            for (int j = 0; j < F4; ++j) {
                a[j].x += v0[j].x + v1[j].x;
                a[j].y += v0[j].y + v1[j].y;
                a[j].z += v0[j].z + v1[j].z;
                a[j].w += v0[j].w + v1[j].w;
            }
        }
        if (s < e) {
            int c = col[s];
            const float4* row = reinterpret_cast<const float4*>(xsrc + (size_t)c * K);
#pragma unroll
            for (int j = 0; j < F4; ++j) {
                float4 v = row[cg + 8 * j];
                a[j].x += v.x; a[j].y += v.y; a[j].z += v.z; a[j].w += v.w;
            }
        }
        float sc = inv[node];
#pragma unroll
        for (int j = 0; j < F4; ++j) { a[j].x *= sc; a[j].y *= sc; a[j].z *= sc; a[j].w *= sc; }
    }
    float4* so = reinterpret_cast<float4*>(sX + r * SXS);
#pragma unroll
    for (int j = 0; j < F4; ++j) so[cg + 8 * j] = a[j];
}

// stage 32 self rows into sX
template<int K>
__device__ inline void stage_self(const float* __restrict__ x, int rowBase, int N, float* sX) {
    const int tid = threadIdx.x;
    const int r = tid >> 3, cg = tid & 7;
    constexpr int F4 = K / 32;
    const int node = rowBase + r;
    float4* so = reinterpret_cast<float4*>(sX + r * SXS);
    if (node < N) {
        const float4* row = reinterpret_cast<const float4*>(x + (size_t)node * K);
#pragma unroll
        for (int j = 0; j < F4; ++j) so[cg + 8 * j] = row[cg + 8 * j];
    } else {
#pragma unroll
        for (int j = 0; j < F4; ++j) so[cg + 8 * j] = make_float4(0.f, 0.f, 0.f, 0.f);
    }
}

// acc[4][CPT] += sX[32][K] @ W[K][NCOL]   (W staged in 32-row LDS chunks)
// k-unrolled x4 with float4 broadcast reads of sX -> VALU-bound inner loop.
template<int K, int NCOL>
__device__ inline void gemm_lds(const float* __restrict__ sX, const float* __restrict__ W,
                                float* sW, float* acc) {
    const int tid = threadIdx.x;
    const int rg = tid >> 5;
    const int cq = tid & 31;
    constexpr int CPT = NCOL / 32;
    for (int kc = 0; kc < K; kc += 32) {
        __syncthreads();
        const float4* Wg = reinterpret_cast<const float4*>(W + (size_t)kc * NCOL);
        float4* sW4 = reinterpret_cast<float4*>(sW);
#pragma unroll
        for (int j = 0; j < NCOL / 32; ++j) sW4[tid + j * 256] = Wg[tid + j * 256];
        __syncthreads();
#pragma unroll
        for (int k0 = 0; k0 < 32; k0 += 4) {
            float4 xv0 = *reinterpret_cast<const float4*>(sX + (rg * 4 + 0) * SXS + kc + k0);
            float4 xv1 = *reinterpret_cast<const float4*>(sX + (rg * 4 + 1) * SXS + kc + k0);
            float4 xv2 = *reinterpret_cast<const float4*>(sX + (rg * 4 + 2) * SXS + kc + k0);
            float4 xv3 = *reinterpret_cast<const float4*>(sX + (rg * 4 + 3) * SXS + kc + k0);
#pragma unroll
            for (int kk = 0; kk < 4; ++kk) {
                const float x0 = (&xv0.x)[kk];
                const float x1 = (&xv1.x)[kk];
                const float x2 = (&xv2.x)[kk];
                const float x3 = (&xv3.x)[kk];
                const float* wr = sW + (k0 + kk) * NCOL + cq * CPT;
#pragma unroll
                for (int j = 0; j < CPT; ++j) {
                    float w = wr[j];
                    acc[0 * CPT + j] = fmaf(x0, w, acc[0 * CPT + j]);
                    acc[1 * CPT + j] = fmaf(x1, w, acc[1 * CPT + j]);
                    acc[2 * CPT + j] = fmaf(x2, w, acc[2 * CPT + j]);
                    acc[3 * CPT + j] = fmaf(x3, w, acc[3 * CPT + j]);
                }
            }
        }
    }
}

// ================= user update: out = relu(agg@Wl + self@Wr + b) =================
template<int KAGG, int KS>
__global__ __launch_bounds__(256, 4) void user_kernel(
    const float* __restrict__ xagg, const int* __restrict__ rp, const int* __restrict__ col,
    const float* __restrict__ inv, const float* xself,
    const float* __restrict__ Wl, const float* __restrict__ Wr, const float* __restrict__ bias,
    float* out, int N) {
    __shared__ float sX[32 * SXS];
    __shared__ float sW[32 * 128];
    float acc[16];
    const int tid = threadIdx.x;
    const int rg = tid >> 5, cq = tid & 31;
    const int rowBase = blockIdx.x * 32;
#pragma unroll
    for (int i = 0; i < 4; ++i)
#pragma unroll
        for (int j = 0; j < 4; ++j) acc[i * 4 + j] = bias[cq * 4 + j];
    gather_avg<KAGG>(xagg, rp, col, inv, rowBase, N, sX);
    gemm_lds<KAGG, 128>(sX, Wl, sW, acc);
    __syncthreads();
    stage_self<KS>(xself, rowBase, N, sX);
    gemm_lds<KS, 128>(sX, Wr, sW, acc);
#pragma unroll
    for (int i = 0; i < 4; ++i) {
        int row = rowBase + rg * 4 + i;
        if (row < N) {
            float4 v;
            v.x = fmaxf(acc[i * 4 + 0], 0.f);
            v.y = fmaxf(acc[i * 4 + 1], 0.f);
            v.z = fmaxf(acc[i * 4 + 2], 0.f);
            v.w = fmaxf(acc[i * 4 + 3], 0.f);
            *reinterpret_cast<float4*>(out + (size_t)row * 128 + cq * 4) = v;
        }
    }
}

// ====== item update: out = relu(0.5*(aggA@WlA + aggB@WlB + self@WrA + self@WrB + bA + bB)) ======
template<int KA, int KB, int KS>
__global__ __launch_bounds__(256, 4) void item_kernel(
    const float* __restrict__ xsrcA, const int* __restrict__ rpA, const int* __restrict__ colA,
    const float* __restrict__ invA,
    const float* __restrict__ WlA, const float* __restrict__ WrA, const float* __restrict__ bA,
    const float* __restrict__ xsrcB, const int* __restrict__ rpB, const int* __restrict__ colB,
    const float* __restrict__ invB,
    const float* __restrict__ WlB, const float* __restrict__ WrB, const float* __restrict__ bB,
    const float* __restrict__ xself, float* __restrict__ out, int N) {
    __shared__ float sX[32 * SXS];
    __shared__ float sW[32 * 128];
    float acc[16];
    const int tid = threadIdx.x;
    const int rg = tid >> 5, cq = tid & 31;
    const int rowBase = blockIdx.x * 32;
#pragma unroll
    for (int i = 0; i < 4; ++i)
#pragma unroll
        for (int j = 0; j < 4; ++j) acc[i * 4 + j] = bA[cq * 4 + j] + bB[cq * 4 + j];
    gather_avg<KA>(xsrcA, rpA, colA, invA, rowBase, N, sX);
    gemm_lds<KA, 128>(sX, WlA, sW, acc);
    __syncthreads();
    gather_avg<KB>(xsrcB, rpB, colB, invB, rowBase, N, sX);
    gemm_lds<KB, 128>(sX, WlB, sW, acc);
    __syncthreads();
    stage_self<KS>(xself, rowBase, N, sX);
    gemm_lds<KS, 128>(sX, WrA, sW, acc);
    gemm_lds<KS, 128>(sX, WrB, sW, acc);
#pragma unroll
    for (int i = 0; i < 4; ++i) {
        int row = rowBase + rg * 4 + i;
        if (row < N) {
            float4 v;
            v.x = fmaxf(0.5f * acc[i * 4 + 0], 0.f);
            v.y = fmaxf(0.5f * acc[i * 4 + 1], 0.f);
            v.z = fmaxf(0.5f * acc[i * 4 + 2], 0.f);
            v.w = fmaxf(0.5f * acc[i * 4 + 3], 0.f);
            *reinterpret_cast<float4*>(out + (size_t)row * 128 + cq * 4) = v;
        }
    }
}

// ================= final linear 128 -> 64 (no relu) =================
__global__ __launch_bounds__(256, 4) void final_kernel(
    const float* __restrict__ x, const float* __restrict__ W, const float* __restrict__ bias,
    float* __restrict__ out, int N) {
    __shared__ float sX[32 * SXS];
    __shared__ float sW[32 * 64];
    float acc[8];
    const int tid = threadIdx.x;
    const int rg = tid >> 5, cq = tid & 31;
    const int rowBase = blockIdx.x * 32;
#pragma unroll
    for (int i = 0; i < 4; ++i)
#pragma unroll
        for (int j = 0; j < 2; ++j) acc[i * 2 + j] = bias[cq * 2 + j];
    stage_self<128>(x, rowBase, N, sX);
    gemm_lds<128, 64>(sX, W, sW, acc);
#pragma unroll
    for (int i = 0; i < 4; ++i) {
        int row = rowBase + rg * 4 + i;
        if (row < N) {
            float2 v;
            v.x = acc[i * 2 + 0];
            v.y = acc[i * 2 + 1];
            *reinterpret_cast<float2*>(out + (size_t)row * 64 + cq * 2) = v;
        }
    }
}

// ================= host =================
static void build_csr(const int* src, const int* dst, int E, int N,
                      int* deg, int* bsum, int* rp, int* col, float* inv, hipStream_t stream) {
    const int B = 256;
    hipMemsetAsync(deg, 0, (size_t)N * sizeof(int), stream);
    deg_kernel<<<(E + B - 1) / B, B, 0, stream>>>(dst, E, deg);
    int nb = (N + 1023) / 1024;
    scanA_kernel<<<nb, B, 0, stream>>>(deg, N, bsum);
    scanB_kernel<<<1, B, 0, stream>>>(bsum, nb);
    scanC_kernel<<<nb, B, 0, stream>>>(deg, N, bsum, rp, E);
    inv_from_deg<<<(N + B - 1) / B, B, 0, stream>>>(deg, inv, N);
    hipMemsetAsync(deg, 0, (size_t)N * sizeof(int), stream);  // reuse as cursor
    fill_kernel<<<(E + B - 1) / B, B, 0, stream>>>(src, dst, E, rp, deg, col);
}

extern "C" void kernel_launch(void* const* d_in, const int* in_sizes, int n_in,
                              void* d_out, int out_size, void* d_ws, size_t ws_size,
                              hipStream_t stream) {
    const float* x_user = (const float*)d_in[0];
    const float* x_item = (const float*)d_in[1];
    const int* ub_src = (const int*)d_in[2];
    const int* ub_dst = (const int*)d_in[3];
    const int* iu_src = (const int*)d_in[4];
    const int* iu_dst = (const int*)d_in[5];
    const int* ii_src = (const int*)d_in[6];
    const int* ii_dst = (const int*)d_in[7];
    const float* W1l_ub = (const float*)d_in[8];
    const float* W1r_ub = (const float*)d_in[9];
    const float* b1_ub = (const float*)d_in[10];
    const float* W1l_iu = (const float*)d_in[11];
    const float* W1r_iu = (const float*)d_in[12];
    const float* b1_iu = (const float*)d_in[13];
    const float* W1l_ii = (const float*)d_in[14];
    const float* W1r_ii = (const float*)d_in[15];
    const float* b1_ii = (const float*)d_in[16];
    const float* W23l = (const float*)d_in[17];
    const float* W23r = (const float*)d_in[18];
    const float* b23 = (const float*)d_in[19];
    const float* Wf_user = (const float*)d_in[20];
    const float* bf_user = (const float*)d_in[21];
    const float* Wf_item = (const float*)d_in[22];
    const float* bf_item = (const float*)d_in[23];

    // ---- workspace layout (~168 MB) ----
    char* p = (char*)d_ws;
    float* xu = (float*)p;            p += (size_t)NU_ * 128 * sizeof(float);
    float* xiA = (float*)p;           p += (size_t)NI_ * 128 * sizeof(float);
    float* inv_iu = (float*)p;        p += (size_t)NU_ * sizeof(float);
    float* inv_ub = (float*)p;        p += (size_t)NI_ * sizeof(float);
    float* inv_ii = (float*)p;        p += (size_t)NI_ * sizeof(float);
    int* rp_iu = (int*)p;             p += (size_t)(NU_ + 4) * sizeof(int);
    int* rp_ub = (int*)p;             p += (size_t)(NI_ + 4) * sizeof(int);
    int* rp_ii = (int*)p;             p += (size_t)(NI_ + 4) * sizeof(int);
    int* col_iu = (int*)p;            p += (size_t)E_IU * sizeof(int);
    int* col_ub = (int*)p;            p += (size_t)E_UB * sizeof(int);
    int* col_ii = (int*)p;            p += (size_t)E_II * sizeof(int);
    int* deg = (int*)p;               p += (size_t)NU_ * sizeof(int);
    int* bsum = (int*)p;              p += 256 * sizeof(int);
    // xi ping-pong buffer B lives in d_out (dead before final kernels write it)
    float* xiB = (float*)d_out;

    // ---- CSR build (per relation) ----
    build_csr(iu_src, iu_dst, E_IU, NU_, deg, bsum, rp_iu, col_iu, inv_iu, stream);
    build_csr(ub_src, ub_dst, E_UB, NI_, deg, bsum, rp_ub, col_ub, inv_ub, stream);
    build_csr(ii_src, ii_dst, E_II, NI_, deg, bsum, rp_ii, col_ii, inv_ii, stream);

    const int gU = NU_ / 32;  // 6250
    const int gI = NI_ / 32;  // 3125

    // ---- layer 1 (reads only inputs) ----
    item_kernel<64, 128, 128><<<gI, 256, 0, stream>>>(
        x_user, rp_ub, col_ub, inv_ub, W1l_ub, W1r_ub, b1_ub,
        x_item, rp_ii, col_ii, inv_ii, W1l_ii, W1r_ii, b1_ii,
        x_item, xiA, NI_);
    user_kernel<128, 64><<<gU, 256, 0, stream>>>(
        x_item, rp_iu, col_iu, inv_iu, x_user, W1l_iu, W1r_iu, b1_iu, xu, NU_);

    // ---- layers 2-3 ----
    for (int l = 0; l < 2; ++l) {
        const float* cur = (l == 0) ? xiA : xiB;
        float* nxt = (l == 0) ? xiB : xiA;
        const size_t WSZ = 128 * 128;
        const float* Wl_ub = W23l + (size_t)(l * 3 + 0) * WSZ;
        const float* Wr_ub = W23r + (size_t)(l * 3 + 0) * WSZ;
        const float* b_ub = b23 + (size_t)(l * 3 + 0) * 128;
        const float* Wl_iu = W23l + (size_t)(l * 3 + 1) * WSZ;
        const float* Wr_iu = W23r + (size_t)(l * 3 + 1) * WSZ;
        const float* b_iu = b23 + (size_t)(l * 3 + 1) * 128;
        const float* Wl_ii = W23l + (size_t)(l * 3 + 2) * WSZ;
        const float* Wr_ii = W23r + (size_t)(l * 3 + 2) * WSZ;
        const float* b_ii = b23 + (size_t)(l * 3 + 2) * 128;

        // item first (its ub-gather needs the pre-update xu)
        item_kernel<128, 128, 128><<<gI, 256, 0, stream>>>(
            xu, rp_ub, col_ub, inv_ub, Wl_ub, Wr_ub, b_ub,
            cur, rp_ii, col_ii, inv_ii, Wl_ii, Wr_ii, b_ii,
            cur, nxt, NI_);
        // user in-place (gathers from cur, self rows only within own block)
        user_kernel<128, 128><<<gU, 256, 0, stream>>>(
            cur, rp_iu, col_iu, inv_iu, xu, Wl_iu, Wr_iu, b_iu, xu, NU_);
    }

    // ---- final linear: user first (overwrites xiB region), item reads xiA ----
    float* out = (float*)d_out;
    final_kernel<<<gU, 256, 0, stream>>>(xu, Wf_user, bf_user, out, NU_);
    final_kernel<<<gI, 256, 0, stream>>>(xiA, Wf_item, bf_item, out + (size_t)NU_ * 64, NI_);
}

// Round 4
// 3281.695 us; speedup vs baseline: 1.0476x; 1.0476x over previous
//
#include <hip/hip_runtime.h>

constexpr int NU_ = 200000, NI_ = 100000;
constexpr int E_UB = 1000000, E_IU = 1000000, E_II = 500000;
constexpr int SXS = 136;  // LDS row stride (floats) for 128-wide rows, padded

// ================= CSR build =================
__global__ void deg_kernel(const int* __restrict__ dst, int E, int* __restrict__ deg) {
    int i = blockIdx.x * blockDim.x + threadIdx.x;
    if (i < E) atomicAdd(&deg[dst[i]], 1);
}

// per-block (1024 elems) sums
__global__ void scanA_kernel(const int* __restrict__ deg, int N, int* __restrict__ bsum) {
    __shared__ int s[256];
    int b = blockIdx.x, t = threadIdx.x;
    int base = b * 1024 + t * 4;
    int v = 0;
#pragma unroll
    for (int j = 0; j < 4; ++j) { int i = base + j; if (i < N) v += deg[i]; }
    s[t] = v; __syncthreads();
    for (int off = 1; off < 256; off <<= 1) {
        int x = (t >= off) ? s[t - off] : 0;
        __syncthreads();
        s[t] += x;
        __syncthreads();
    }
    if (t == 255) bsum[b] = s[255];
}

// single-block exclusive scan of block sums (nb <= 256)
__global__ void scanB_kernel(int* __restrict__ bsum, int nb) {
    __shared__ int s[256];
    int t = threadIdx.x;
    int v = (t < nb) ? bsum[t] : 0;
    s[t] = v; __syncthreads();
    for (int off = 1; off < 256; off <<= 1) {
        int x = (t >= off) ? s[t - off] : 0;
        __syncthreads();
        s[t] += x;
        __syncthreads();
    }
    if (t < nb) bsum[t] = s[t] - v;  // exclusive
}

__global__ void scanC_kernel(const int* __restrict__ deg, int N, const int* __restrict__ boff,
                             int* __restrict__ rp, int E) {
    __shared__ int s[256];
    int b = blockIdx.x, t = threadIdx.x;
    int base = b * 1024 + t * 4;
    int d[4]; int v = 0;
#pragma unroll
    for (int j = 0; j < 4; ++j) { int i = base + j; d[j] = (i < N) ? deg[i] : 0; v += d[j]; }
    s[t] = v; __syncthreads();
    for (int off = 1; off < 256; off <<= 1) {
        int x = (t >= off) ? s[t - off] : 0;
        __syncthreads();
        s[t] += x;
        __syncthreads();
    }
    int ex = boff[b] + s[t] - v;
#pragma unroll
    for (int j = 0; j < 4; ++j) { int i = base + j; if (i < N) rp[i] = ex; ex += d[j]; }
    if (b == 0 && t == 0) rp[N] = E;
}

__global__ void inv_from_deg(const int* __restrict__ deg, float* __restrict__ inv, int N) {
    int i = blockIdx.x * blockDim.x + threadIdx.x;
    if (i < N) inv[i] = 1.0f / fmaxf((float)deg[i], 1.0f);
}

__global__ void fill_kernel(const int* __restrict__ src, const int* __restrict__ dst, int E,
                            const int* __restrict__ rp, int* __restrict__ cur, int* __restrict__ col) {
    int e = blockIdx.x * blockDim.x + threadIdx.x;
    if (e < E) {
        int d = dst[e];
        int p = atomicAdd(&cur[d], 1);
        col[rp[d] + p] = src[e];
    }
}

// ================= fused update building blocks =================
// Block = 256 threads, 32 dst rows. Gather mapping: (r = tid>>3 row, cg = tid&7).
// GEMM mapping: (rg = tid>>5 -> rows rg*4..+4, cq = tid&31 -> cols cq*CPT..).

// mean-aggregate neighbors of 32 nodes into sX[32][SXS] (row length K)
template<int K>
__device__ inline void gather_avg(const float* __restrict__ xsrc,
                                  const int* __restrict__ rp, const int* __restrict__ col,
                                  const float* __restrict__ inv,
                                  int rowBase, int N, float* sX) {
    const int tid = threadIdx.x;
    const int r = tid >> 3, cg = tid & 7;
    constexpr int F4 = K / 32;  // float4s per thread
    float4 a[F4];
#pragma unroll
    for (int j = 0; j < F4; ++j) a[j] = make_float4(0.f, 0.f, 0.f, 0.f);
    const int node = rowBase + r;
    if (node < N) {
        int s = rp[node], e = rp[node + 1];
        for (; s < e; ++s) {
            int c = col[s];
            const float4* row = reinterpret_cast<const float4*>(xsrc + (size_t)c * K);
#pragma unroll
            for (int j = 0; j < F4; ++j) {
                float4 v = row[cg + 8 * j];
                a[j].x += v.x; a[j].y += v.y; a[j].z += v.z; a[j].w += v.w;
            }
        }
        float sc = inv[node];
#pragma unroll
        for (int j = 0; j < F4; ++j) { a[j].x *= sc; a[j].y *= sc; a[j].z *= sc; a[j].w *= sc; }
    }
    float4* so = reinterpret_cast<float4*>(sX + r * SXS);
#pragma unroll
    for (int j = 0; j < F4; ++j) so[cg + 8 * j] = a[j];
}

// stage 32 self rows into sX
template<int K>
__device__ inline void stage_self(const float* __restrict__ x, int rowBase, int N, float* sX) {
    const int tid = threadIdx.x;
    const int r = tid >> 3, cg = tid & 7;
    constexpr int F4 = K / 32;
    const int node = rowBase + r;
    float4* so = reinterpret_cast<float4*>(sX + r * SXS);
    if (node < N) {
        const float4* row = reinterpret_cast<const float4*>(x + (size_t)node * K);
#pragma unroll
        for (int j = 0; j < F4; ++j) so[cg + 8 * j] = row[cg + 8 * j];
    } else {
#pragma unroll
        for (int j = 0; j < F4; ++j) so[cg + 8 * j] = make_float4(0.f, 0.f, 0.f, 0.f);
    }
}

// acc[4][CPT] += sX[32][K] @ W[K][NCOL]   (W staged in 32-row LDS chunks)
// k-unrolled x4 with float4 broadcast reads of sX -> VALU-bound inner loop.
template<int K, int NCOL>
__device__ inline void gemm_lds(const float* __restrict__ sX, const float* __restrict__ W,
                                float* sW, float* acc) {
    const int tid = threadIdx.x;
    const int rg = tid >> 5;
    const int cq = tid & 31;
    constexpr int CPT = NCOL / 32;
    for (int kc = 0; kc < K; kc += 32) {
        __syncthreads();
        const float4* Wg = reinterpret_cast<const float4*>(W + (size_t)kc * NCOL);
        float4* sW4 = reinterpret_cast<float4*>(sW);
#pragma unroll
        for (int j = 0; j < NCOL / 32; ++j) sW4[tid + j * 256] = Wg[tid + j * 256];
        __syncthreads();
#pragma unroll
        for (int k0 = 0; k0 < 32; k0 += 4) {
            float4 xv0 = *reinterpret_cast<const float4*>(sX + (rg * 4 + 0) * SXS + kc + k0);
            float4 xv1 = *reinterpret_cast<const float4*>(sX + (rg * 4 + 1) * SXS + kc + k0);
            float4 xv2 = *reinterpret_cast<const float4*>(sX + (rg * 4 + 2) * SXS + kc + k0);
            float4 xv3 = *reinterpret_cast<const float4*>(sX + (rg * 4 + 3) * SXS + kc + k0);
#pragma unroll
            for (int kk = 0; kk < 4; ++kk) {
                const float x0 = (&xv0.x)[kk];
                const float x1 = (&xv1.x)[kk];
                const float x2 = (&xv2.x)[kk];
                const float x3 = (&xv3.x)[kk];
                const float* wr = sW + (k0 + kk) * NCOL + cq * CPT;
#pragma unroll
                for (int j = 0; j < CPT; ++j) {
                    float w = wr[j];
                    acc[0 * CPT + j] = fmaf(x0, w, acc[0 * CPT + j]);
                    acc[1 * CPT + j] = fmaf(x1, w, acc[1 * CPT + j]);
                    acc[2 * CPT + j] = fmaf(x2, w, acc[2 * CPT + j]);
                    acc[3 * CPT + j] = fmaf(x3, w, acc[3 * CPT + j]);
                }
            }
        }
    }
}

// ================= user update: out = relu(agg@Wl + self@Wr + b) =================
template<int KAGG, int KS>
__global__ __launch_bounds__(256, 3) void user_kernel(
    const float* __restrict__ xagg, const int* __restrict__ rp, const int* __restrict__ col,
    const float* __restrict__ inv, const float* xself,
    const float* __restrict__ Wl, const float* __restrict__ Wr, const float* __restrict__ bias,
    float* out, int N) {
    __shared__ float sX[32 * SXS];
    __shared__ float sW[32 * 128];
    float acc[16];
    const int tid = threadIdx.x;
    const int rg = tid >> 5, cq = tid & 31;
    const int rowBase = blockIdx.x * 32;
#pragma unroll
    for (int i = 0; i < 4; ++i)
#pragma unroll
        for (int j = 0; j < 4; ++j) acc[i * 4 + j] = bias[cq * 4 + j];
    gather_avg<KAGG>(xagg, rp, col, inv, rowBase, N, sX);
    gemm_lds<KAGG, 128>(sX, Wl, sW, acc);
    __syncthreads();
    stage_self<KS>(xself, rowBase, N, sX);
    gemm_lds<KS, 128>(sX, Wr, sW, acc);
#pragma unroll
    for (int i = 0; i < 4; ++i) {
        int row = rowBase + rg * 4 + i;
        if (row < N) {
            float4 v;
            v.x = fmaxf(acc[i * 4 + 0], 0.f);
            v.y = fmaxf(acc[i * 4 + 1], 0.f);
            v.z = fmaxf(acc[i * 4 + 2], 0.f);
            v.w = fmaxf(acc[i * 4 + 3], 0.f);
            *reinterpret_cast<float4*>(out + (size_t)row * 128 + cq * 4) = v;
        }
    }
}

// ====== item update: out = relu(0.5*(aggA@WlA + aggB@WlB + self@WrA + self@WrB + bA + bB)) ======
template<int KA, int KB, int KS>
__global__ __launch_bounds__(256, 3) void item_kernel(
    const float* __restrict__ xsrcA, const int* __restrict__ rpA, const int* __restrict__ colA,
    const float* __restrict__ invA,
    const float* __restrict__ WlA, const float* __restrict__ WrA, const float* __restrict__ bA,
    const float* __restrict__ xsrcB, const int* __restrict__ rpB, const int* __restrict__ colB,
    const float* __restrict__ invB,
    const float* __restrict__ WlB, const float* __restrict__ WrB, const float* __restrict__ bB,
    const float* __restrict__ xself, float* __restrict__ out, int N) {
    __shared__ float sX[32 * SXS];
    __shared__ float sW[32 * 128];
    float acc[16];
    const int tid = threadIdx.x;
    const int rg = tid >> 5, cq = tid & 31;
    const int rowBase = blockIdx.x * 32;
#pragma unroll
    for (int i = 0; i < 4; ++i)
#pragma unroll
        for (int j = 0; j < 4; ++j) acc[i * 4 + j] = bA[cq * 4 + j] + bB[cq * 4 + j];
    gather_avg<KA>(xsrcA, rpA, colA, invA, rowBase, N, sX);
    gemm_lds<KA, 128>(sX, WlA, sW, acc);
    __syncthreads();
    gather_avg<KB>(xsrcB, rpB, colB, invB, rowBase, N, sX);
    gemm_lds<KB, 128>(sX, WlB, sW, acc);
    __syncthreads();
    stage_self<KS>(xself, rowBase, N, sX);
    gemm_lds<KS, 128>(sX, WrA, sW, acc);
    gemm_lds<KS, 128>(sX, WrB, sW, acc);
#pragma unroll
    for (int i = 0; i < 4; ++i) {
        int row = rowBase + rg * 4 + i;
        if (row < N) {
            float4 v;
            v.x = fmaxf(0.5f * acc[i * 4 + 0], 0.f);
            v.y = fmaxf(0.5f * acc[i * 4 + 1], 0.f);
            v.z = fmaxf(0.5f * acc[i * 4 + 2], 0.f);
            v.w = fmaxf(0.5f * acc[i * 4 + 3], 0.f);
            *reinterpret_cast<float4*>(out + (size_t)row * 128 + cq * 4) = v;
        }
    }
}

// ================= final linear 128 -> 64 (no relu) =================
__global__ __launch_bounds__(256, 3) void final_kernel(
    const float* __restrict__ x, const float* __restrict__ W, const float* __restrict__ bias,
    float* __restrict__ out, int N) {
    __shared__ float sX[32 * SXS];
    __shared__ float sW[32 * 64];
    float acc[8];
    const int tid = threadIdx.x;
    const int rg = tid >> 5, cq = tid & 31;
    const int rowBase = blockIdx.x * 32;
#pragma unroll
    for (int i = 0; i < 4; ++i)
#pragma unroll
        for (int j = 0; j < 2; ++j) acc[i * 2 + j] = bias[cq * 2 + j];
    stage_self<128>(x, rowBase, N, sX);
    gemm_lds<128, 64>(sX, W, sW, acc);
#pragma unroll
    for (int i = 0; i < 4; ++i) {
        int row = rowBase + rg * 4 + i;
        if (row < N) {
            float2 v;
            v.x = acc[i * 2 + 0];
            v.y = acc[i * 2 + 1];
            *reinterpret_cast<float2*>(out + (size_t)row * 64 + cq * 2) = v;
        }
    }
}

// ================= host =================
static void build_csr(const int* src, const int* dst, int E, int N,
                      int* deg, int* bsum, int* rp, int* col, float* inv, hipStream_t stream) {
    const int B = 256;
    hipMemsetAsync(deg, 0, (size_t)N * sizeof(int), stream);
    deg_kernel<<<(E + B - 1) / B, B, 0, stream>>>(dst, E, deg);
    int nb = (N + 1023) / 1024;
    scanA_kernel<<<nb, B, 0, stream>>>(deg, N, bsum);
    scanB_kernel<<<1, B, 0, stream>>>(bsum, nb);
    scanC_kernel<<<nb, B, 0, stream>>>(deg, N, bsum, rp, E);
    inv_from_deg<<<(N + B - 1) / B, B, 0, stream>>>(deg, inv, N);
    hipMemsetAsync(deg, 0, (size_t)N * sizeof(int), stream);  // reuse as cursor
    fill_kernel<<<(E + B - 1) / B, B, 0, stream>>>(src, dst, E, rp, deg, col);
}

extern "C" void kernel_launch(void* const* d_in, const int* in_sizes, int n_in,
                              void* d_out, int out_size, void* d_ws, size_t ws_size,
                              hipStream_t stream) {
    const float* x_user = (const float*)d_in[0];
    const float* x_item = (const float*)d_in[1];
    const int* ub_src = (const int*)d_in[2];
    const int* ub_dst = (const int*)d_in[3];
    const int* iu_src = (const int*)d_in[4];
    const int* iu_dst = (const int*)d_in[5];
    const int* ii_src = (const int*)d_in[6];
    const int* ii_dst = (const int*)d_in[7];
    const float* W1l_ub = (const float*)d_in[8];
    const float* W1r_ub = (const float*)d_in[9];
    const float* b1_ub = (const float*)d_in[10];
    const float* W1l_iu = (const float*)d_in[11];
    const float* W1r_iu = (const float*)d_in[12];
    const float* b1_iu = (const float*)d_in[13];
    const float* W1l_ii = (const float*)d_in[14];
    const float* W1r_ii = (const float*)d_in[15];
    const float* b1_ii = (const float*)d_in[16];
    const float* W23l = (const float*)d_in[17];
    const float* W23r = (const float*)d_in[18];
    const float* b23 = (const float*)d_in[19];
    const float* Wf_user = (const float*)d_in[20];
    const float* bf_user = (const float*)d_in[21];
    const float* Wf_item = (const float*)d_in[22];
    const float* bf_item = (const float*)d_in[23];

    // ---- workspace layout (~168 MB) ----
    char* p = (char*)d_ws;
    float* xu = (float*)p;            p += (size_t)NU_ * 128 * sizeof(float);
    float* xiA = (float*)p;           p += (size_t)NI_ * 128 * sizeof(float);
    float* inv_iu = (float*)p;        p += (size_t)NU_ * sizeof(float);
    float* inv_ub = (float*)p;        p += (size_t)NI_ * sizeof(float);
    float* inv_ii = (float*)p;        p += (size_t)NI_ * sizeof(float);
    int* rp_iu = (int*)p;             p += (size_t)(NU_ + 4) * sizeof(int);
    int* rp_ub = (int*)p;             p += (size_t)(NI_ + 4) * sizeof(int);
    int* rp_ii = (int*)p;             p += (size_t)(NI_ + 4) * sizeof(int);
    int* col_iu = (int*)p;            p += (size_t)E_IU * sizeof(int);
    int* col_ub = (int*)p;            p += (size_t)E_UB * sizeof(int);
    int* col_ii = (int*)p;            p += (size_t)E_II * sizeof(int);
    int* deg = (int*)p;               p += (size_t)NU_ * sizeof(int);
    int* bsum = (int*)p;              p += 256 * sizeof(int);
    // xi ping-pong buffer B lives in d_out (dead before final kernels write it)
    float* xiB = (float*)d_out;

    // ---- CSR build (per relation) ----
    build_csr(iu_src, iu_dst, E_IU, NU_, deg, bsum, rp_iu, col_iu, inv_iu, stream);
    build_csr(ub_src, ub_dst, E_UB, NI_, deg, bsum, rp_ub, col_ub, inv_ub, stream);
    build_csr(ii_src, ii_dst, E_II, NI_, deg, bsum, rp_ii, col_ii, inv_ii, stream);

    const int gU = NU_ / 32;  // 6250
    const int gI = NI_ / 32;  // 3125

    // ---- layer 1 (reads only inputs) ----
    item_kernel<64, 128, 128><<<gI, 256, 0, stream>>>(
        x_user, rp_ub, col_ub, inv_ub, W1l_ub, W1r_ub, b1_ub,
        x_item, rp_ii, col_ii, inv_ii, W1l_ii, W1r_ii, b1_ii,
        x_item, xiA, NI_);
    user_kernel<128, 64><<<gU, 256, 0, stream>>>(
        x_item, rp_iu, col_iu, inv_iu, x_user, W1l_iu, W1r_iu, b1_iu, xu, NU_);

    // ---- layers 2-3 ----
    for (int l = 0; l < 2; ++l) {
        const float* cur = (l == 0) ? xiA : xiB;
        float* nxt = (l == 0) ? xiB : xiA;
        const size_t WSZ = 128 * 128;
        const float* Wl_ub = W23l + (size_t)(l * 3 + 0) * WSZ;
        const float* Wr_ub = W23r + (size_t)(l * 3 + 0) * WSZ;
        const float* b_ub = b23 + (size_t)(l * 3 + 0) * 128;
        const float* Wl_iu = W23l + (size_t)(l * 3 + 1) * WSZ;
        const float* Wr_iu = W23r + (size_t)(l * 3 + 1) * WSZ;
        const float* b_iu = b23 + (size_t)(l * 3 + 1) * 128;
        const float* Wl_ii = W23l + (size_t)(l * 3 + 2) * WSZ;
        const float* Wr_ii = W23r + (size_t)(l * 3 + 2) * WSZ;
        const float* b_ii = b23 + (size_t)(l * 3 + 2) * 128;

        // item first (its ub-gather needs the pre-update xu)
        item_kernel<128, 128, 128><<<gI, 256, 0, stream>>>(
            xu, rp_ub, col_ub, inv_ub, Wl_ub, Wr_ub, b_ub,
            cur, rp_ii, col_ii, inv_ii, Wl_ii, Wr_ii, b_ii,
            cur, nxt, NI_);
        // user in-place (gathers from cur, self rows only within own block)
        user_kernel<128, 128><<<gU, 256, 0, stream>>>(
            cur, rp_iu, col_iu, inv_iu, xu, Wl_iu, Wr_iu, b_iu, xu, NU_);
    }

    // ---- final linear: user first (overwrites xiB region), item reads xiA ----
    float* out = (float*)d_out;
    final_kernel<<<gU, 256, 0, stream>>>(xu, Wf_user, bf_user, out, NU_);
    final_kernel<<<gI, 256, 0, stream>>>(xiA, Wf_item, bf_item, out + (size_t)NU_ * 64, NI_);
}

// Round 5
// 3097.541 us; speedup vs baseline: 1.1098x; 1.0595x over previous
//
#include <hip/hip_runtime.h>

constexpr int NU_ = 200000, NI_ = 100000;
constexpr int E_UB = 1000000, E_IU = 1000000, E_II = 500000;
constexpr int SXS = 136;  // LDS row stride (floats) for 128-wide rows, padded

// ================= CSR build =================
__global__ void deg_kernel(const int* __restrict__ dst, int E, int* __restrict__ deg) {
    int i = blockIdx.x * blockDim.x + threadIdx.x;
    if (i < E) atomicAdd(&deg[dst[i]], 1);
}

// per-block (1024 elems) sums
__global__ void scanA_kernel(const int* __restrict__ deg, int N, int* __restrict__ bsum) {
    __shared__ int s[256];
    int b = blockIdx.x, t = threadIdx.x;
    int base = b * 1024 + t * 4;
    int v = 0;
#pragma unroll
    for (int j = 0; j < 4; ++j) { int i = base + j; if (i < N) v += deg[i]; }
    s[t] = v; __syncthreads();
    for (int off = 1; off < 256; off <<= 1) {
        int x = (t >= off) ? s[t - off] : 0;
        __syncthreads();
        s[t] += x;
        __syncthreads();
    }
    if (t == 255) bsum[b] = s[255];
}

// single-block exclusive scan of block sums (nb <= 256)
__global__ void scanB_kernel(int* __restrict__ bsum, int nb) {
    __shared__ int s[256];
    int t = threadIdx.x;
    int v = (t < nb) ? bsum[t] : 0;
    s[t] = v; __syncthreads();
    for (int off = 1; off < 256; off <<= 1) {
        int x = (t >= off) ? s[t - off] : 0;
        __syncthreads();
        s[t] += x;
        __syncthreads();
    }
    if (t < nb) bsum[t] = s[t] - v;  // exclusive
}

__global__ void scanC_kernel(const int* __restrict__ deg, int N, const int* __restrict__ boff,
                             int* __restrict__ rp, int E) {
    __shared__ int s[256];
    int b = blockIdx.x, t = threadIdx.x;
    int base = b * 1024 + t * 4;
    int d[4]; int v = 0;
#pragma unroll
    for (int j = 0; j < 4; ++j) { int i = base + j; d[j] = (i < N) ? deg[i] : 0; v += d[j]; }
    s[t] = v; __syncthreads();
    for (int off = 1; off < 256; off <<= 1) {
        int x = (t >= off) ? s[t - off] : 0;
        __syncthreads();
        s[t] += x;
        __syncthreads();
    }
    int ex = boff[b] + s[t] - v;
#pragma unroll
    for (int j = 0; j < 4; ++j) { int i = base + j; if (i < N) rp[i] = ex; ex += d[j]; }
    if (b == 0 && t == 0) rp[N] = E;
}

__global__ void inv_from_deg(const int* __restrict__ deg, float* __restrict__ inv, int N) {
    int i = blockIdx.x * blockDim.x + threadIdx.x;
    if (i < N) inv[i] = 1.0f / fmaxf((float)deg[i], 1.0f);
}

__global__ void fill_kernel(const int* __restrict__ src, const int* __restrict__ dst, int E,
                            const int* __restrict__ rp, int* __restrict__ cur, int* __restrict__ col) {
    int e = blockIdx.x * blockDim.x + threadIdx.x;
    if (e < E) {
        int d = dst[e];
        int p = atomicAdd(&cur[d], 1);
        col[rp[d] + p] = src[e];
    }
}

// ================= fused update building blocks =================
// Block = 256 threads, 32 dst rows. Gather mapping: (r = tid>>3 row, cg = tid&7).
// GEMM mapping: (rg = tid>>5 -> rows rg*4..+4, cq = tid&31 -> cols cq*CPT..).

// mean-aggregate neighbors of 32 nodes into sX[32][SXS] (row length K)
template<int K>
__device__ inline void gather_avg(const float* __restrict__ xsrc,
                                  const int* __restrict__ rp, const int* __restrict__ col,
                                  const float* __restrict__ inv,
                                  int rowBase, int N, float* sX) {
    const int tid = threadIdx.x;
    const int r = tid >> 3, cg = tid & 7;
    constexpr int F4 = K / 32;  // float4s per thread
    float4 a[F4];
#pragma unroll
    for (int j = 0; j < F4; ++j) a[j] = make_float4(0.f, 0.f, 0.f, 0.f);
    const int node = rowBase + r;
    if (node < N) {
        int s = rp[node], e = rp[node + 1];
        for (; s < e; ++s) {
            int c = col[s];
            const float4* row = reinterpret_cast<const float4*>(xsrc + (size_t)c * K);
#pragma unroll
            for (int j = 0; j < F4; ++j) {
                float4 v = row[cg + 8 * j];
                a[j].x += v.x; a[j].y += v.y; a[j].z += v.z; a[j].w += v.w;
            }
        }
        float sc = inv[node];
#pragma unroll
        for (int j = 0; j < F4; ++j) { a[j].x *= sc; a[j].y *= sc; a[j].z *= sc; a[j].w *= sc; }
    }
    float4* so = reinterpret_cast<float4*>(sX + r * SXS);
#pragma unroll
    for (int j = 0; j < F4; ++j) so[cg + 8 * j] = a[j];
}

// stage 32 self rows into sX
template<int K>
__device__ inline void stage_self(const float* __restrict__ x, int rowBase, int N, float* sX) {
    const int tid = threadIdx.x;
    const int r = tid >> 3, cg = tid & 7;
    constexpr int F4 = K / 32;
    const int node = rowBase + r;
    float4* so = reinterpret_cast<float4*>(sX + r * SXS);
    if (node < N) {
        const float4* row = reinterpret_cast<const float4*>(x + (size_t)node * K);
#pragma unroll
        for (int j = 0; j < F4; ++j) so[cg + 8 * j] = row[cg + 8 * j];
    } else {
#pragma unroll
        for (int j = 0; j < F4; ++j) so[cg + 8 * j] = make_float4(0.f, 0.f, 0.f, 0.f);
    }
}

// acc[4][CPT] += sX[32][K] @ W[K][NCOL]   (W staged in 32-row LDS chunks)
// round-2 style scalar sX reads: modest register footprint, no spill.
template<int K, int NCOL>
__device__ inline void gemm_lds(const float* __restrict__ sX, const float* __restrict__ W,
                                float* sW, float* acc) {
    const int tid = threadIdx.x;
    const int rg = tid >> 5;
    const int cq = tid & 31;
    constexpr int CPT = NCOL / 32;
    for (int kc = 0; kc < K; kc += 32) {
        __syncthreads();
        const float4* Wg = reinterpret_cast<const float4*>(W + (size_t)kc * NCOL);
        float4* sW4 = reinterpret_cast<float4*>(sW);
#pragma unroll
        for (int j = 0; j < NCOL / 32; ++j) sW4[tid + j * 256] = Wg[tid + j * 256];
        __syncthreads();
#pragma unroll
        for (int k = 0; k < 32; ++k) {
            const float* wr = sW + k * NCOL + cq * CPT;
            float x0 = sX[(rg * 4 + 0) * SXS + kc + k];
            float x1 = sX[(rg * 4 + 1) * SXS + kc + k];
            float x2 = sX[(rg * 4 + 2) * SXS + kc + k];
            float x3 = sX[(rg * 4 + 3) * SXS + kc + k];
#pragma unroll
            for (int j = 0; j < CPT; ++j) {
                float w = wr[j];
                acc[0 * CPT + j] = fmaf(x0, w, acc[0 * CPT + j]);
                acc[1 * CPT + j] = fmaf(x1, w, acc[1 * CPT + j]);
                acc[2 * CPT + j] = fmaf(x2, w, acc[2 * CPT + j]);
                acc[3 * CPT + j] = fmaf(x3, w, acc[3 * CPT + j]);
            }
        }
    }
}

// ================= user update: out = relu(agg@Wl + self@Wr + b) =================
template<int KAGG, int KS>
__global__ __launch_bounds__(256, 2) void user_kernel(
    const float* __restrict__ xagg, const int* __restrict__ rp, const int* __restrict__ col,
    const float* __restrict__ inv, const float* xself,
    const float* __restrict__ Wl, const float* __restrict__ Wr, const float* __restrict__ bias,
    float* out, int N) {
    __shared__ float sX[32 * SXS];
    __shared__ float sW[32 * 128];
    float acc[16];
    const int tid = threadIdx.x;
    const int rg = tid >> 5, cq = tid & 31;
    const int rowBase = blockIdx.x * 32;
#pragma unroll
    for (int i = 0; i < 4; ++i)
#pragma unroll
        for (int j = 0; j < 4; ++j) acc[i * 4 + j] = bias[cq * 4 + j];
    gather_avg<KAGG>(xagg, rp, col, inv, rowBase, N, sX);
    gemm_lds<KAGG, 128>(sX, Wl, sW, acc);
    __syncthreads();
    stage_self<KS>(xself, rowBase, N, sX);
    gemm_lds<KS, 128>(sX, Wr, sW, acc);
#pragma unroll
    for (int i = 0; i < 4; ++i) {
        int row = rowBase + rg * 4 + i;
        if (row < N) {
            float4 v;
            v.x = fmaxf(acc[i * 4 + 0], 0.f);
            v.y = fmaxf(acc[i * 4 + 1], 0.f);
            v.z = fmaxf(acc[i * 4 + 2], 0.f);
            v.w = fmaxf(acc[i * 4 + 3], 0.f);
            *reinterpret_cast<float4*>(out + (size_t)row * 128 + cq * 4) = v;
        }
    }
}

// ====== item update: out = relu(0.5*(aggA@WlA + aggB@WlB + self@WrA + self@WrB + bA + bB)) ======
template<int KA, int KB, int KS>
__global__ __launch_bounds__(256, 2) void item_kernel(
    const float* __restrict__ xsrcA, const int* __restrict__ rpA, const int* __restrict__ colA,
    const float* __restrict__ invA,
    const float* __restrict__ WlA, const float* __restrict__ WrA, const float* __restrict__ bA,
    const float* __restrict__ xsrcB, const int* __restrict__ rpB, const int* __restrict__ colB,
    const float* __restrict__ invB,
    const float* __restrict__ WlB, const float* __restrict__ WrB, const float* __restrict__ bB,
    const float* __restrict__ xself, float* __restrict__ out, int N) {
    __shared__ float sX[32 * SXS];
    __shared__ float sW[32 * 128];
    float acc[16];
    const int tid = threadIdx.x;
    const int rg = tid >> 5, cq = tid & 31;
    const int rowBase = blockIdx.x * 32;
#pragma unroll
    for (int i = 0; i < 4; ++i)
#pragma unroll
        for (int j = 0; j < 4; ++j) acc[i * 4 + j] = bA[cq * 4 + j] + bB[cq * 4 + j];
    gather_avg<KA>(xsrcA, rpA, colA, invA, rowBase, N, sX);
    gemm_lds<KA, 128>(sX, WlA, sW, acc);
    __syncthreads();
    gather_avg<KB>(xsrcB, rpB, colB, invB, rowBase, N, sX);
    gemm_lds<KB, 128>(sX, WlB, sW, acc);
    __syncthreads();
    stage_self<KS>(xself, rowBase, N, sX);
    gemm_lds<KS, 128>(sX, WrA, sW, acc);
    gemm_lds<KS, 128>(sX, WrB, sW, acc);
#pragma unroll
    for (int i = 0; i < 4; ++i) {
        int row = rowBase + rg * 4 + i;
        if (row < N) {
            float4 v;
            v.x = fmaxf(0.5f * acc[i * 4 + 0], 0.f);
            v.y = fmaxf(0.5f * acc[i * 4 + 1], 0.f);
            v.z = fmaxf(0.5f * acc[i * 4 + 2], 0.f);
            v.w = fmaxf(0.5f * acc[i * 4 + 3], 0.f);
            *reinterpret_cast<float4*>(out + (size_t)row * 128 + cq * 4) = v;
        }
    }
}

// ================= final linear 128 -> 64 (no relu) =================
__global__ __launch_bounds__(256, 2) void final_kernel(
    const float* __restrict__ x, const float* __restrict__ W, const float* __restrict__ bias,
    float* __restrict__ out, int N) {
    __shared__ float sX[32 * SXS];
    __shared__ float sW[32 * 64];
    float acc[8];
    const int tid = threadIdx.x;
    const int rg = tid >> 5, cq = tid & 31;
    const int rowBase = blockIdx.x * 32;
#pragma unroll
    for (int i = 0; i < 4; ++i)
#pragma unroll
        for (int j = 0; j < 2; ++j) acc[i * 2 + j] = bias[cq * 2 + j];
    stage_self<128>(x, rowBase, N, sX);
    gemm_lds<128, 64>(sX, W, sW, acc);
#pragma unroll
    for (int i = 0; i < 4; ++i) {
        int row = rowBase + rg * 4 + i;
        if (row < N) {
            float2 v;
            v.x = acc[i * 2 + 0];
            v.y = acc[i * 2 + 1];
            *reinterpret_cast<float2*>(out + (size_t)row * 64 + cq * 2) = v;
        }
    }
}

// ================= host =================
static void build_csr(const int* src, const int* dst, int E, int N,
                      int* deg, int* bsum, int* rp, int* col, float* inv, hipStream_t stream) {
    const int B = 256;
    hipMemsetAsync(deg, 0, (size_t)N * sizeof(int), stream);
    deg_kernel<<<(E + B - 1) / B, B, 0, stream>>>(dst, E, deg);
    int nb = (N + 1023) / 1024;
    scanA_kernel<<<nb, B, 0, stream>>>(deg, N, bsum);
    scanB_kernel<<<1, B, 0, stream>>>(bsum, nb);
    scanC_kernel<<<nb, B, 0, stream>>>(deg, N, bsum, rp, E);
    inv_from_deg<<<(N + B - 1) / B, B, 0, stream>>>(deg, inv, N);
    hipMemsetAsync(deg, 0, (size_t)N * sizeof(int), stream);  // reuse as cursor
    fill_kernel<<<(E + B - 1) / B, B, 0, stream>>>(src, dst, E, rp, deg, col);
}

extern "C" void kernel_launch(void* const* d_in, const int* in_sizes, int n_in,
                              void* d_out, int out_size, void* d_ws, size_t ws_size,
                              hipStream_t stream) {
    const float* x_user = (const float*)d_in[0];
    const float* x_item = (const float*)d_in[1];
    const int* ub_src = (const int*)d_in[2];
    const int* ub_dst = (const int*)d_in[3];
    const int* iu_src = (const int*)d_in[4];
    const int* iu_dst = (const int*)d_in[5];
    const int* ii_src = (const int*)d_in[6];
    const int* ii_dst = (const int*)d_in[7];
    const float* W1l_ub = (const float*)d_in[8];
    const float* W1r_ub = (const float*)d_in[9];
    const float* b1_ub = (const float*)d_in[10];
    const float* W1l_iu = (const float*)d_in[11];
    const float* W1r_iu = (const float*)d_in[12];
    const float* b1_iu = (const float*)d_in[13];
    const float* W1l_ii = (const float*)d_in[14];
    const float* W1r_ii = (const float*)d_in[15];
    const float* b1_ii = (const float*)d_in[16];
    const float* W23l = (const float*)d_in[17];
    const float* W23r = (const float*)d_in[18];
    const float* b23 = (const float*)d_in[19];
    const float* Wf_user = (const float*)d_in[20];
    const float* bf_user = (const float*)d_in[21];
    const float* Wf_item = (const float*)d_in[22];
    const float* bf_item = (const float*)d_in[23];

    // ---- workspace layout (~168 MB) ----
    char* p = (char*)d_ws;
    float* xu = (float*)p;            p += (size_t)NU_ * 128 * sizeof(float);
    float* xiA = (float*)p;           p += (size_t)NI_ * 128 * sizeof(float);
    float* inv_iu = (float*)p;        p += (size_t)NU_ * sizeof(float);
    float* inv_ub = (float*)p;        p += (size_t)NI_ * sizeof(float);
    float* inv_ii = (float*)p;        p += (size_t)NI_ * sizeof(float);
    int* rp_iu = (int*)p;             p += (size_t)(NU_ + 4) * sizeof(int);
    int* rp_ub = (int*)p;             p += (size_t)(NI_ + 4) * sizeof(int);
    int* rp_ii = (int*)p;             p += (size_t)(NI_ + 4) * sizeof(int);
    int* col_iu = (int*)p;            p += (size_t)E_IU * sizeof(int);
    int* col_ub = (int*)p;            p += (size_t)E_UB * sizeof(int);
    int* col_ii = (int*)p;            p += (size_t)E_II * sizeof(int);
    int* deg = (int*)p;               p += (size_t)NU_ * sizeof(int);
    int* bsum = (int*)p;              p += 256 * sizeof(int);
    // xi ping-pong buffer B lives in d_out (dead before final kernels write it)
    float* xiB = (float*)d_out;

    // ---- CSR build (per relation) ----
    build_csr(iu_src, iu_dst, E_IU, NU_, deg, bsum, rp_iu, col_iu, inv_iu, stream);
    build_csr(ub_src, ub_dst, E_UB, NI_, deg, bsum, rp_ub, col_ub, inv_ub, stream);
    build_csr(ii_src, ii_dst, E_II, NI_, deg, bsum, rp_ii, col_ii, inv_ii, stream);

    const int gU = NU_ / 32;  // 6250
    const int gI = NI_ / 32;  // 3125

    // ---- layer 1 (reads only inputs) ----
    item_kernel<64, 128, 128><<<gI, 256, 0, stream>>>(
        x_user, rp_ub, col_ub, inv_ub, W1l_ub, W1r_ub, b1_ub,
        x_item, rp_ii, col_ii, inv_ii, W1l_ii, W1r_ii, b1_ii,
        x_item, xiA, NI_);
    user_kernel<128, 64><<<gU, 256, 0, stream>>>(
        x_item, rp_iu, col_iu, inv_iu, x_user, W1l_iu, W1r_iu, b1_iu, xu, NU_);

    // ---- layers 2-3 ----
    for (int l = 0; l < 2; ++l) {
        const float* cur = (l == 0) ? xiA : xiB;
        float* nxt = (l == 0) ? xiB : xiA;
        const size_t WSZ = 128 * 128;
        const float* Wl_ub = W23l + (size_t)(l * 3 + 0) * WSZ;
        const float* Wr_ub = W23r + (size_t)(l * 3 + 0) * WSZ;
        const float* b_ub = b23 + (size_t)(l * 3 + 0) * 128;
        const float* Wl_iu = W23l + (size_t)(l * 3 + 1) * WSZ;
        const float* Wr_iu = W23r + (size_t)(l * 3 + 1) * WSZ;
        const float* b_iu = b23 + (size_t)(l * 3 + 1) * 128;
        const float* Wl_ii = W23l + (size_t)(l * 3 + 2) * WSZ;
        const float* Wr_ii = W23r + (size_t)(l * 3 + 2) * WSZ;
        const float* b_ii = b23 + (size_t)(l * 3 + 2) * 128;

        // item first (its ub-gather needs the pre-update xu)
        item_kernel<128, 128, 128><<<gI, 256, 0, stream>>>(
            xu, rp_ub, col_ub, inv_ub, Wl_ub, Wr_ub, b_ub,
            cur, rp_ii, col_ii, inv_ii, Wl_ii, Wr_ii, b_ii,
            cur, nxt, NI_);
        // user in-place (gathers from cur, self rows only within own block)
        user_kernel<128, 128><<<gU, 256, 0, stream>>>(
            cur, rp_iu, col_iu, inv_iu, xu, Wl_iu, Wr_iu, b_iu, xu, NU_);
    }

    // ---- final linear: user first (overwrites xiB region), item reads xiA ----
    float* out = (float*)d_out;
    final_kernel<<<gU, 256, 0, stream>>>(xu, Wf_user, bf_user, out, NU_);
    final_kernel<<<gI, 256, 0, stream>>>(xiA, Wf_item, bf_item, out + (size_t)NU_ * 64, NI_);
}

// Round 6
// 2167.461 us; speedup vs baseline: 1.5861x; 1.4291x over previous
//
#include <hip/hip_runtime.h>

constexpr int NU_ = 200000, NI_ = 100000;
constexpr int E_UB = 1000000, E_IU = 1000000, E_II = 500000;
constexpr int SXS = 136;  // LDS row stride (floats) for 128-wide rows, padded

// ================= CSR build =================
__global__ void deg_kernel(const int* __restrict__ dst, int E, int* __restrict__ deg) {
    int i = blockIdx.x * blockDim.x + threadIdx.x;
    if (i < E) atomicAdd(&deg[dst[i]], 1);
}

__global__ void scanA_kernel(const int* __restrict__ deg, int N, int* __restrict__ bsum) {
    __shared__ int s[256];
    int b = blockIdx.x, t = threadIdx.x;
    int base = b * 1024 + t * 4;
    int v = 0;
#pragma unroll
    for (int j = 0; j < 4; ++j) { int i = base + j; if (i < N) v += deg[i]; }
    s[t] = v; __syncthreads();
    for (int off = 1; off < 256; off <<= 1) {
        int x = (t >= off) ? s[t - off] : 0;
        __syncthreads();
        s[t] += x;
        __syncthreads();
    }
    if (t == 255) bsum[b] = s[255];
}

__global__ void scanB_kernel(int* __restrict__ bsum, int nb) {
    __shared__ int s[256];
    int t = threadIdx.x;
    int v = (t < nb) ? bsum[t] : 0;
    s[t] = v; __syncthreads();
    for (int off = 1; off < 256; off <<= 1) {
        int x = (t >= off) ? s[t - off] : 0;
        __syncthreads();
        s[t] += x;
        __syncthreads();
    }
    if (t < nb) bsum[t] = s[t] - v;  // exclusive
}

__global__ void scanC_kernel(const int* __restrict__ deg, int N, const int* __restrict__ boff,
                             int* __restrict__ rp, int E) {
    __shared__ int s[256];
    int b = blockIdx.x, t = threadIdx.x;
    int base = b * 1024 + t * 4;
    int d[4]; int v = 0;
#pragma unroll
    for (int j = 0; j < 4; ++j) { int i = base + j; d[j] = (i < N) ? deg[i] : 0; v += d[j]; }
    s[t] = v; __syncthreads();
    for (int off = 1; off < 256; off <<= 1) {
        int x = (t >= off) ? s[t - off] : 0;
        __syncthreads();
        s[t] += x;
        __syncthreads();
    }
    int ex = boff[b] + s[t] - v;
#pragma unroll
    for (int j = 0; j < 4; ++j) { int i = base + j; if (i < N) rp[i] = ex; ex += d[j]; }
    if (b == 0 && t == 0) rp[N] = E;
}

__global__ void inv_from_deg(const int* __restrict__ deg, float* __restrict__ inv, int N) {
    int i = blockIdx.x * blockDim.x + threadIdx.x;
    if (i < N) inv[i] = 1.0f / fmaxf((float)deg[i], 1.0f);
}

__global__ void fill_kernel(const int* __restrict__ src, const int* __restrict__ dst, int E,
                            const int* __restrict__ rp, int* __restrict__ cur, int* __restrict__ col) {
    int e = blockIdx.x * blockDim.x + threadIdx.x;
    if (e < E) {
        int d = dst[e];
        int p = atomicAdd(&cur[d], 1);
        col[rp[d] + p] = src[e];
    }
}

// ================= fused update building blocks =================
// Block = 256 threads, 32 dst rows.
// Gather: LPR = K/4 lanes per row, each lane owns ONE float4 slice (low regs).
// GEMM mapping: (rg = tid>>5 -> rows rg*4..+4, cq = tid&31 -> cols cq*CPT..).

template<int K>
__device__ inline void gather_avg(const float* __restrict__ xsrc,
                                  const int* __restrict__ rp, const int* __restrict__ col,
                                  const float* __restrict__ inv,
                                  int rowBase, int N, float* sX) {
    constexpr int LPR = K / 4;        // lanes per row (32 for K=128, 16 for K=64)
    constexpr int RPP = 256 / LPR;    // rows per pass
    const int tid = threadIdx.x;
    const int lane = tid % LPR;
    const int rr = tid / LPR;
#pragma unroll
    for (int pass = 0; pass < 32 / RPP; ++pass) {
        const int r = pass * RPP + rr;
        const int node = rowBase + r;
        float4 a = make_float4(0.f, 0.f, 0.f, 0.f);
        if (node < N) {
            int s = rp[node], e = rp[node + 1];
#pragma unroll 1
            for (; s < e; ++s) {
                int c = col[s];
                float4 v = *reinterpret_cast<const float4*>(xsrc + (size_t)c * K + lane * 4);
                a.x += v.x; a.y += v.y; a.z += v.z; a.w += v.w;
            }
            float sc = inv[node];
            a.x *= sc; a.y *= sc; a.z *= sc; a.w *= sc;
        }
        *reinterpret_cast<float4*>(sX + r * SXS + lane * 4) = a;
    }
}

// stage 32 self rows into sX (LPR lanes per row, one float4 each)
template<int K>
__device__ inline void stage_self(const float* __restrict__ x, int rowBase, int N, float* sX) {
    constexpr int LPR = K / 4;
    constexpr int RPP = 256 / LPR;
    const int tid = threadIdx.x;
    const int lane = tid % LPR;
    const int rr = tid / LPR;
#pragma unroll
    for (int pass = 0; pass < 32 / RPP; ++pass) {
        const int r = pass * RPP + rr;
        const int node = rowBase + r;
        float4 v = make_float4(0.f, 0.f, 0.f, 0.f);
        if (node < N) v = *reinterpret_cast<const float4*>(x + (size_t)node * K + lane * 4);
        *reinterpret_cast<float4*>(sX + r * SXS + lane * 4) = v;
    }
}

// acc[4][CPT] += sX[32][K] @ W[K][NCOL]   (W staged in 32-row LDS chunks)
// scalar sX broadcast reads; k-loop unroll bounded to 8 to limit reg pressure.
template<int K, int NCOL>
__device__ inline void gemm_lds(const float* __restrict__ sX, const float* __restrict__ W,
                                float* sW, float* acc) {
    const int tid = threadIdx.x;
    const int rg = tid >> 5;
    const int cq = tid & 31;
    constexpr int CPT = NCOL / 32;
    for (int kc = 0; kc < K; kc += 32) {
        __syncthreads();
        const float4* Wg = reinterpret_cast<const float4*>(W + (size_t)kc * NCOL);
        float4* sW4 = reinterpret_cast<float4*>(sW);
#pragma unroll
        for (int j = 0; j < NCOL / 32; ++j) sW4[tid + j * 256] = Wg[tid + j * 256];
        __syncthreads();
#pragma unroll 8
        for (int k = 0; k < 32; ++k) {
            const float* wr = sW + k * NCOL + cq * CPT;
            float x0 = sX[(rg * 4 + 0) * SXS + kc + k];
            float x1 = sX[(rg * 4 + 1) * SXS + kc + k];
            float x2 = sX[(rg * 4 + 2) * SXS + kc + k];
            float x3 = sX[(rg * 4 + 3) * SXS + kc + k];
#pragma unroll
            for (int j = 0; j < CPT; ++j) {
                float w = wr[j];
                acc[0 * CPT + j] = fmaf(x0, w, acc[0 * CPT + j]);
                acc[1 * CPT + j] = fmaf(x1, w, acc[1 * CPT + j]);
                acc[2 * CPT + j] = fmaf(x2, w, acc[2 * CPT + j]);
                acc[3 * CPT + j] = fmaf(x3, w, acc[3 * CPT + j]);
            }
        }
    }
}

// ================= user update: out = relu(agg@Wl + self@Wr + b) =================
template<int KAGG, int KS>
__global__ __launch_bounds__(256, 3) void user_kernel(
    const float* __restrict__ xagg, const int* __restrict__ rp, const int* __restrict__ col,
    const float* __restrict__ inv, const float* xself,
    const float* __restrict__ Wl, const float* __restrict__ Wr, const float* __restrict__ bias,
    float* out, int N) {
    __shared__ float sX[32 * SXS];
    __shared__ float sW[32 * 128];
    float acc[16];
    const int tid = threadIdx.x;
    const int rg = tid >> 5, cq = tid & 31;
    const int rowBase = blockIdx.x * 32;
#pragma unroll
    for (int i = 0; i < 4; ++i)
#pragma unroll
        for (int j = 0; j < 4; ++j) acc[i * 4 + j] = bias[cq * 4 + j];
    gather_avg<KAGG>(xagg, rp, col, inv, rowBase, N, sX);
    gemm_lds<KAGG, 128>(sX, Wl, sW, acc);
    __syncthreads();
    stage_self<KS>(xself, rowBase, N, sX);
    gemm_lds<KS, 128>(sX, Wr, sW, acc);
#pragma unroll
    for (int i = 0; i < 4; ++i) {
        int row = rowBase + rg * 4 + i;
        if (row < N) {
            float4 v;
            v.x = fmaxf(acc[i * 4 + 0], 0.f);
            v.y = fmaxf(acc[i * 4 + 1], 0.f);
            v.z = fmaxf(acc[i * 4 + 2], 0.f);
            v.w = fmaxf(acc[i * 4 + 3], 0.f);
            *reinterpret_cast<float4*>(out + (size_t)row * 128 + cq * 4) = v;
        }
    }
}

// ====== item update: out = relu(0.5*(aggA@WlA + aggB@WlB + self@WrA + self@WrB + bA + bB)) ======
template<int KA, int KB, int KS>
__global__ __launch_bounds__(256, 3) void item_kernel(
    const float* __restrict__ xsrcA, const int* __restrict__ rpA, const int* __restrict__ colA,
    const float* __restrict__ invA,
    const float* __restrict__ WlA, const float* __restrict__ WrA, const float* __restrict__ bA,
    const float* __restrict__ xsrcB, const int* __restrict__ rpB, const int* __restrict__ colB,
    const float* __restrict__ invB,
    const float* __restrict__ WlB, const float* __restrict__ WrB, const float* __restrict__ bB,
    const float* __restrict__ xself, float* __restrict__ out, int N) {
    __shared__ float sX[32 * SXS];
    __shared__ float sW[32 * 128];
    float acc[16];
    const int tid = threadIdx.x;
    const int rg = tid >> 5, cq = tid & 31;
    const int rowBase = blockIdx.x * 32;
#pragma unroll
    for (int i = 0; i < 4; ++i)
#pragma unroll
        for (int j = 0; j < 4; ++j) acc[i * 4 + j] = bA[cq * 4 + j] + bB[cq * 4 + j];
    gather_avg<KA>(xsrcA, rpA, colA, invA, rowBase, N, sX);
    gemm_lds<KA, 128>(sX, WlA, sW, acc);
    __syncthreads();
    gather_avg<KB>(xsrcB, rpB, colB, invB, rowBase, N, sX);
    gemm_lds<KB, 128>(sX, WlB, sW, acc);
    __syncthreads();
    stage_self<KS>(xself, rowBase, N, sX);
    gemm_lds<KS, 128>(sX, WrA, sW, acc);
    gemm_lds<KS, 128>(sX, WrB, sW, acc);
#pragma unroll
    for (int i = 0; i < 4; ++i) {
        int row = rowBase + rg * 4 + i;
        if (row < N) {
            float4 v;
            v.x = fmaxf(0.5f * acc[i * 4 + 0], 0.f);
            v.y = fmaxf(0.5f * acc[i * 4 + 1], 0.f);
            v.z = fmaxf(0.5f * acc[i * 4 + 2], 0.f);
            v.w = fmaxf(0.5f * acc[i * 4 + 3], 0.f);
            *reinterpret_cast<float4*>(out + (size_t)row * 128 + cq * 4) = v;
        }
    }
}

// ================= final linear 128 -> 64 (no relu) =================
__global__ __launch_bounds__(256, 3) void final_kernel(
    const float* __restrict__ x, const float* __restrict__ W, const float* __restrict__ bias,
    float* __restrict__ out, int N) {
    __shared__ float sX[32 * SXS];
    __shared__ float sW[32 * 64];
    float acc[8];
    const int tid = threadIdx.x;
    const int rg = tid >> 5, cq = tid & 31;
    const int rowBase = blockIdx.x * 32;
#pragma unroll
    for (int i = 0; i < 4; ++i)
#pragma unroll
        for (int j = 0; j < 2; ++j) acc[i * 2 + j] = bias[cq * 2 + j];
    stage_self<128>(x, rowBase, N, sX);
    gemm_lds<128, 64>(sX, W, sW, acc);
#pragma unroll
    for (int i = 0; i < 4; ++i) {
        int row = rowBase + rg * 4 + i;
        if (row < N) {
            float2 v;
            v.x = acc[i * 2 + 0];
            v.y = acc[i * 2 + 1];
            *reinterpret_cast<float2*>(out + (size_t)row * 64 + cq * 2) = v;
        }
    }
}

// ================= host =================
static void build_csr(const int* src, const int* dst, int E, int N,
                      int* deg, int* bsum, int* rp, int* col, float* inv, hipStream_t stream) {
    const int B = 256;
    hipMemsetAsync(deg, 0, (size_t)N * sizeof(int), stream);
    deg_kernel<<<(E + B - 1) / B, B, 0, stream>>>(dst, E, deg);
    int nb = (N + 1023) / 1024;
    scanA_kernel<<<nb, B, 0, stream>>>(deg, N, bsum);
    scanB_kernel<<<1, B, 0, stream>>>(bsum, nb);
    scanC_kernel<<<nb, B, 0, stream>>>(deg, N, bsum, rp, E);
    inv_from_deg<<<(N + B - 1) / B, B, 0, stream>>>(deg, inv, N);
    hipMemsetAsync(deg, 0, (size_t)N * sizeof(int), stream);  // reuse as cursor
    fill_kernel<<<(E + B - 1) / B, B, 0, stream>>>(src, dst, E, rp, deg, col);
}

extern "C" void kernel_launch(void* const* d_in, const int* in_sizes, int n_in,
                              void* d_out, int out_size, void* d_ws, size_t ws_size,
                              hipStream_t stream) {
    const float* x_user = (const float*)d_in[0];
    const float* x_item = (const float*)d_in[1];
    const int* ub_src = (const int*)d_in[2];
    const int* ub_dst = (const int*)d_in[3];
    const int* iu_src = (const int*)d_in[4];
    const int* iu_dst = (const int*)d_in[5];
    const int* ii_src = (const int*)d_in[6];
    const int* ii_dst = (const int*)d_in[7];
    const float* W1l_ub = (const float*)d_in[8];
    const float* W1r_ub = (const float*)d_in[9];
    const float* b1_ub = (const float*)d_in[10];
    const float* W1l_iu = (const float*)d_in[11];
    const float* W1r_iu = (const float*)d_in[12];
    const float* b1_iu = (const float*)d_in[13];
    const float* W1l_ii = (const float*)d_in[14];
    const float* W1r_ii = (const float*)d_in[15];
    const float* b1_ii = (const float*)d_in[16];
    const float* W23l = (const float*)d_in[17];
    const float* W23r = (const float*)d_in[18];
    const float* b23 = (const float*)d_in[19];
    const float* Wf_user = (const float*)d_in[20];
    const float* bf_user = (const float*)d_in[21];
    const float* Wf_item = (const float*)d_in[22];
    const float* bf_item = (const float*)d_in[23];

    // ---- workspace layout (~168 MB) ----
    char* p = (char*)d_ws;
    float* xu = (float*)p;            p += (size_t)NU_ * 128 * sizeof(float);
    float* xiA = (float*)p;           p += (size_t)NI_ * 128 * sizeof(float);
    float* inv_iu = (float*)p;        p += (size_t)NU_ * sizeof(float);
    float* inv_ub = (float*)p;        p += (size_t)NI_ * sizeof(float);
    float* inv_ii = (float*)p;        p += (size_t)NI_ * sizeof(float);
    int* rp_iu = (int*)p;             p += (size_t)(NU_ + 4) * sizeof(int);
    int* rp_ub = (int*)p;             p += (size_t)(NI_ + 4) * sizeof(int);
    int* rp_ii = (int*)p;             p += (size_t)(NI_ + 4) * sizeof(int);
    int* col_iu = (int*)p;            p += (size_t)E_IU * sizeof(int);
    int* col_ub = (int*)p;            p += (size_t)E_UB * sizeof(int);
    int* col_ii = (int*)p;            p += (size_t)E_II * sizeof(int);
    int* deg = (int*)p;               p += (size_t)NU_ * sizeof(int);
    int* bsum = (int*)p;              p += 256 * sizeof(int);
    // xi ping-pong buffer B lives in d_out (dead before final kernels write it)
    float* xiB = (float*)d_out;

    // ---- CSR build (per relation) ----
    build_csr(iu_src, iu_dst, E_IU, NU_, deg, bsum, rp_iu, col_iu, inv_iu, stream);
    build_csr(ub_src, ub_dst, E_UB, NI_, deg, bsum, rp_ub, col_ub, inv_ub, stream);
    build_csr(ii_src, ii_dst, E_II, NI_, deg, bsum, rp_ii, col_ii, inv_ii, stream);

    const int gU = NU_ / 32;  // 6250
    const int gI = NI_ / 32;  // 3125

    // ---- layer 1 (reads only inputs) ----
    item_kernel<64, 128, 128><<<gI, 256, 0, stream>>>(
        x_user, rp_ub, col_ub, inv_ub, W1l_ub, W1r_ub, b1_ub,
        x_item, rp_ii, col_ii, inv_ii, W1l_ii, W1r_ii, b1_ii,
        x_item, xiA, NI_);
    user_kernel<128, 64><<<gU, 256, 0, stream>>>(
        x_item, rp_iu, col_iu, inv_iu, x_user, W1l_iu, W1r_iu, b1_iu, xu, NU_);

    // ---- layers 2-3 ----
    for (int l = 0; l < 2; ++l) {
        const float* cur = (l == 0) ? xiA : xiB;
        float* nxt = (l == 0) ? xiB : xiA;
        const size_t WSZ = 128 * 128;
        const float* Wl_ub = W23l + (size_t)(l * 3 + 0) * WSZ;
        const float* Wr_ub = W23r + (size_t)(l * 3 + 0) * WSZ;
        const float* b_ub = b23 + (size_t)(l * 3 + 0) * 128;
        const float* Wl_iu = W23l + (size_t)(l * 3 + 1) * WSZ;
        const float* Wr_iu = W23r + (size_t)(l * 3 + 1) * WSZ;
        const float* b_iu = b23 + (size_t)(l * 3 + 1) * 128;
        const float* Wl_ii = W23l + (size_t)(l * 3 + 2) * WSZ;
        const float* Wr_ii = W23r + (size_t)(l * 3 + 2) * WSZ;
        const float* b_ii = b23 + (size_t)(l * 3 + 2) * 128;

        // item first (its ub-gather needs the pre-update xu)
        item_kernel<128, 128, 128><<<gI, 256, 0, stream>>>(
            xu, rp_ub, col_ub, inv_ub, Wl_ub, Wr_ub, b_ub,
            cur, rp_ii, col_ii, inv_ii, Wl_ii, Wr_ii, b_ii,
            cur, nxt, NI_);
        // user in-place (gathers from cur, self rows only within own block)
        user_kernel<128, 128><<<gU, 256, 0, stream>>>(
            cur, rp_iu, col_iu, inv_iu, xu, Wl_iu, Wr_iu, b_iu, xu, NU_);
    }

    // ---- final linear: user first (overwrites xiB region), item reads xiA ----
    float* out = (float*)d_out;
    final_kernel<<<gU, 256, 0, stream>>>(xu, Wf_user, bf_user, out, NU_);
    final_kernel<<<gI, 256, 0, stream>>>(xiA, Wf_item, bf_item, out + (size_t)NU_ * 64, NI_);
}

// Round 7
// 1930.862 us; speedup vs baseline: 1.7804x; 1.1225x over previous
//
#include <hip/hip_runtime.h>

typedef unsigned short u16;
typedef __attribute__((ext_vector_type(4))) unsigned short u16x4;
typedef __attribute__((ext_vector_type(4))) short s16x4;
typedef __attribute__((ext_vector_type(8))) short s16x8;
typedef __attribute__((ext_vector_type(16))) float f32x16;

constexpr int NU_ = 200000, NI_ = 100000;
constexpr int E_UB = 1000000, E_IU = 1000000, E_II = 500000;
constexpr int SAP = 132;  // LDS row stride in bf16 elems (264B: 2-way max bank aliasing)

__device__ inline float bf2f(u16 v) { return __uint_as_float(((unsigned)v) << 16); }
__device__ inline u16 f2bf(float f) {
    unsigned u = __float_as_uint(f);
    return (u16)((u + 0x7FFFu + ((u >> 16) & 1u)) >> 16);  // RNE
}

// ================= CSR build (unchanged, works) =================
__global__ void deg_kernel(const int* __restrict__ dst, int E, int* __restrict__ deg) {
    int i = blockIdx.x * blockDim.x + threadIdx.x;
    if (i < E) atomicAdd(&deg[dst[i]], 1);
}

__global__ void scanA_kernel(const int* __restrict__ deg, int N, int* __restrict__ bsum) {
    __shared__ int s[256];
    int b = blockIdx.x, t = threadIdx.x;
    int base = b * 1024 + t * 4;
    int v = 0;
#pragma unroll
    for (int j = 0; j < 4; ++j) { int i = base + j; if (i < N) v += deg[i]; }
    s[t] = v; __syncthreads();
    for (int off = 1; off < 256; off <<= 1) {
        int x = (t >= off) ? s[t - off] : 0;
        __syncthreads();
        s[t] += x;
        __syncthreads();
    }
    if (t == 255) bsum[b] = s[255];
}

__global__ void scanB_kernel(int* __restrict__ bsum, int nb) {
    __shared__ int s[256];
    int t = threadIdx.x;
    int v = (t < nb) ? bsum[t] : 0;
    s[t] = v; __syncthreads();
    for (int off = 1; off < 256; off <<= 1) {
        int x = (t >= off) ? s[t - off] : 0;
        __syncthreads();
        s[t] += x;
        __syncthreads();
    }
    if (t < nb) bsum[t] = s[t] - v;  // exclusive
}

__global__ void scanC_kernel(const int* __restrict__ deg, int N, const int* __restrict__ boff,
                             int* __restrict__ rp, int E) {
    __shared__ int s[256];
    int b = blockIdx.x, t = threadIdx.x;
    int base = b * 1024 + t * 4;
    int d[4]; int v = 0;
#pragma unroll
    for (int j = 0; j < 4; ++j) { int i = base + j; d[j] = (i < N) ? deg[i] : 0; v += d[j]; }
    s[t] = v; __syncthreads();
    for (int off = 1; off < 256; off <<= 1) {
        int x = (t >= off) ? s[t - off] : 0;
        __syncthreads();
        s[t] += x;
        __syncthreads();
    }
    int ex = boff[b] + s[t] - v;
#pragma unroll
    for (int j = 0; j < 4; ++j) { int i = base + j; if (i < N) rp[i] = ex; ex += d[j]; }
    if (b == 0 && t == 0) rp[N] = E;
}

__global__ void inv_from_deg(const int* __restrict__ deg, float* __restrict__ inv, int N) {
    int i = blockIdx.x * blockDim.x + threadIdx.x;
    if (i < N) inv[i] = 1.0f / fmaxf((float)deg[i], 1.0f);
}

__global__ void fill_kernel(const int* __restrict__ src, const int* __restrict__ dst, int E,
                            const int* __restrict__ rp, int* __restrict__ cur, int* __restrict__ col) {
    int e = blockIdx.x * blockDim.x + threadIdx.x;
    if (e < E) {
        int d = dst[e];
        int p = atomicAdd(&cur[d], 1);
        col[rp[d] + p] = src[e];
    }
}

// ================= conversions =================
__global__ void cvt_kernel(const float* __restrict__ in, u16* __restrict__ out, int n4) {
    int i = blockIdx.x * 256 + threadIdx.x;
    if (i < n4) {
        float4 v = reinterpret_cast<const float4*>(in)[i];
        u16x4 o = { f2bf(v.x), f2bf(v.y), f2bf(v.z), f2bf(v.w) };
        reinterpret_cast<u16x4*>(out)[i] = o;
    }
}

// src [K][N] f32 -> dst [N][K] bf16 (transposed)
__global__ void wt_kernel(const float* __restrict__ src, u16* __restrict__ dst, int K, int N) {
    int i = blockIdx.x * 256 + threadIdx.x;
    if (i < K * N) { int k = i / N, n = i - k * N; dst[n * K + k] = f2bf(src[i]); }
}

// batch of nmat 128x128 matrices
__global__ void wt_batch_kernel(const float* __restrict__ src, u16* __restrict__ dst, int nmat) {
    int i = blockIdx.x * 256 + threadIdx.x;
    if (i < nmat * 16384) {
        int m = i >> 14, rem = i & 16383;
        int k = rem >> 7, n = rem & 127;
        dst[(m << 14) + (n << 7) + k] = f2bf(src[i]);
    }
}

// ================= fused MFMA update blocks =================
// Block = 256 threads (4 waves), 64 dst rows, NCOL output cols.
// mfma_f32_32x32x16_bf16: A[m=lane&31][k=4*hi+(j&3)+8*(j>>2)], B symmetric,
// C/D: col=lane&31, row=(r&3)+8*(r>>2)+4*hi  [m74/m101 verified]

// mean-aggregate into sA (bf16, rows padded to SAP)
template<int K>
__device__ inline void gather_avg_bf(const u16* __restrict__ xsrc,
                                     const int* __restrict__ rp, const int* __restrict__ col,
                                     const float* __restrict__ inv,
                                     int rowBase, int N, u16* sA) {
    constexpr int LPR = K / 4;       // lanes per row
    constexpr int RPP = 256 / LPR;   // rows per pass
    const int tid = threadIdx.x;
    const int lane = tid % LPR, rr = tid / LPR;
#pragma unroll
    for (int p = 0; p < 64 / RPP; ++p) {
        const int r = p * RPP + rr;
        const int node = rowBase + r;
        float a0 = 0.f, a1 = 0.f, a2 = 0.f, a3 = 0.f;
        if (node < N) {
            int s = rp[node], e = rp[node + 1];
#pragma unroll 1
            for (; s < e; ++s) {
                int c = col[s];
                u16x4 v = *reinterpret_cast<const u16x4*>(xsrc + (size_t)c * K + lane * 4);
                a0 += bf2f(v.x); a1 += bf2f(v.y); a2 += bf2f(v.z); a3 += bf2f(v.w);
            }
            float sc = inv[node];
            a0 *= sc; a1 *= sc; a2 *= sc; a3 *= sc;
        }
        u16x4 o = { f2bf(a0), f2bf(a1), f2bf(a2), f2bf(a3) };
        *reinterpret_cast<u16x4*>(sA + r * SAP + lane * 4) = o;
    }
}

template<int K>
__device__ inline void stage_self_bf(const u16* __restrict__ x, int rowBase, int N, u16* sA) {
    constexpr int LPR = K / 4;
    constexpr int RPP = 256 / LPR;
    const int tid = threadIdx.x;
    const int lane = tid % LPR, rr = tid / LPR;
#pragma unroll
    for (int p = 0; p < 64 / RPP; ++p) {
        const int r = p * RPP + rr;
        const int node = rowBase + r;
        u16x4 v = { 0, 0, 0, 0 };
        if (node < N) v = *reinterpret_cast<const u16x4*>(x + (size_t)node * K + lane * 4);
        *reinterpret_cast<u16x4*>(sA + r * SAP + lane * 4) = v;
    }
}

// stage transposed weight [NCOL][K] bf16 -> sW [NCOL][SAP]
template<int K, int NCOL>
__device__ inline void stage_w(const u16* __restrict__ Wt, u16* sW) {
    constexpr int CH = K / 4;
    constexpr int TOT = NCOL * CH;
#pragma unroll
    for (int i = threadIdx.x; i < TOT; i += 256) {
        int n = i / CH, c = i - n * CH;
        *reinterpret_cast<u16x4*>(sW + n * SAP + c * 4) =
            *reinterpret_cast<const u16x4*>(Wt + (size_t)n * K + c * 4);
    }
}

template<int K, int NCOL, int TPW>
__device__ inline void gemm_mfma(const u16* sA, const u16* sW, f32x16* acc) {
    constexpr int NB_C = NCOL / 32;
    const int lane = threadIdx.x & 63;
    const int wid = threadIdx.x >> 6;
    const int lm = lane & 31, hi = lane >> 5;
    const int id0 = wid * TPW;
    const int rb = id0 / NB_C;
    const int arow = rb * 32 + lm;
#pragma unroll
    for (int kc = 0; kc < K; kc += 16) {
        const u16* pa = sA + arow * SAP + kc + 4 * hi;
        s16x4 q0 = *reinterpret_cast<const s16x4*>(pa);
        s16x4 q1 = *reinterpret_cast<const s16x4*>(pa + 8);
        s16x8 a = { q0.x, q0.y, q0.z, q0.w, q1.x, q1.y, q1.z, q1.w };
#pragma unroll
        for (int t = 0; t < TPW; ++t) {
            const int cb = (id0 + t) % NB_C;
            const u16* pb = sW + (cb * 32 + lm) * SAP + kc + 4 * hi;
            s16x4 r0 = *reinterpret_cast<const s16x4*>(pb);
            s16x4 r1 = *reinterpret_cast<const s16x4*>(pb + 8);
            s16x8 b = { r0.x, r0.y, r0.z, r0.w, r1.x, r1.y, r1.z, r1.w };
            acc[t] = __builtin_amdgcn_mfma_f32_32x32x16_bf16(a, b, acc[t], 0, 0, 0);
        }
    }
}

// ================= user update: out = relu(agg@Wl + self@Wr + b), bf16 out =================
template<int KA, int KS>
__global__ __launch_bounds__(256, 3) void user_mfma(
    const u16* __restrict__ xagg, const int* __restrict__ rp, const int* __restrict__ col,
    const float* __restrict__ inv, const u16* xself,
    const u16* __restrict__ WlT, const u16* __restrict__ WrT, const float* __restrict__ bias,
    u16* out, int N) {
    __shared__ u16 sA[64 * SAP];
    __shared__ u16 sW[128 * SAP];
    f32x16 acc[2];
    const int lane = threadIdx.x & 63, wid = threadIdx.x >> 6;
    const int lm = lane & 31, hi = lane >> 5;
    const int id0 = wid * 2;
    const int rb = id0 / 4;
    const int rowBase = blockIdx.x * 64;
#pragma unroll
    for (int t = 0; t < 2; ++t) {
        float bv = bias[((id0 + t) % 4) * 32 + lm];
#pragma unroll
        for (int i = 0; i < 16; ++i) acc[t][i] = bv;
    }
    gather_avg_bf<KA>(xagg, rp, col, inv, rowBase, N, sA);
    stage_w<KA, 128>(WlT, sW);
    __syncthreads();
    gemm_mfma<KA, 128, 2>(sA, sW, acc);
    __syncthreads();
    stage_self_bf<KS>(xself, rowBase, N, sA);
    stage_w<KS, 128>(WrT, sW);
    __syncthreads();
    gemm_mfma<KS, 128, 2>(sA, sW, acc);
#pragma unroll
    for (int t = 0; t < 2; ++t) {
        int colv = ((id0 + t) % 4) * 32 + lm;
#pragma unroll
        for (int r = 0; r < 16; ++r) {
            int row = rowBase + rb * 32 + (r & 3) + 8 * (r >> 2) + 4 * hi;
            if (row < N) out[(size_t)row * 128 + colv] = f2bf(fmaxf(acc[t][r], 0.f));
        }
    }
}

// ====== item update: out = relu(0.5*(aggA@WlA + aggB@WlB + self@(WrA+WrB) + bA + bB)) ======
template<int KA, int KB, int KS>
__global__ __launch_bounds__(256, 3) void item_mfma(
    const u16* __restrict__ xsrcA, const int* __restrict__ rpA, const int* __restrict__ colA,
    const float* __restrict__ invA,
    const u16* __restrict__ WlAT, const u16* __restrict__ WrAT, const float* __restrict__ bA,
    const u16* __restrict__ xsrcB, const int* __restrict__ rpB, const int* __restrict__ colB,
    const float* __restrict__ invB,
    const u16* __restrict__ WlBT, const u16* __restrict__ WrBT, const float* __restrict__ bB,
    const u16* __restrict__ xself, u16* __restrict__ out, int N) {
    __shared__ u16 sA[64 * SAP];
    __shared__ u16 sW[128 * SAP];
    f32x16 acc[2];
    const int lane = threadIdx.x & 63, wid = threadIdx.x >> 6;
    const int lm = lane & 31, hi = lane >> 5;
    const int id0 = wid * 2;
    const int rb = id0 / 4;
    const int rowBase = blockIdx.x * 64;
#pragma unroll
    for (int t = 0; t < 2; ++t) {
        int cv = ((id0 + t) % 4) * 32 + lm;
        float bv = bA[cv] + bB[cv];
#pragma unroll
        for (int i = 0; i < 16; ++i) acc[t][i] = bv;
    }
    gather_avg_bf<KA>(xsrcA, rpA, colA, invA, rowBase, N, sA);
    stage_w<KA, 128>(WlAT, sW);
    __syncthreads();
    gemm_mfma<KA, 128, 2>(sA, sW, acc);
    __syncthreads();
    gather_avg_bf<KB>(xsrcB, rpB, colB, invB, rowBase, N, sA);
    stage_w<KB, 128>(WlBT, sW);
    __syncthreads();
    gemm_mfma<KB, 128, 2>(sA, sW, acc);
    __syncthreads();
    stage_self_bf<KS>(xself, rowBase, N, sA);
    stage_w<KS, 128>(WrAT, sW);
    __syncthreads();
    gemm_mfma<KS, 128, 2>(sA, sW, acc);
    __syncthreads();
    stage_w<KS, 128>(WrBT, sW);
    __syncthreads();
    gemm_mfma<KS, 128, 2>(sA, sW, acc);
#pragma unroll
    for (int t = 0; t < 2; ++t) {
        int colv = ((id0 + t) % 4) * 32 + lm;
#pragma unroll
        for (int r = 0; r < 16; ++r) {
            int row = rowBase + rb * 32 + (r & 3) + 8 * (r >> 2) + 4 * hi;
            if (row < N) out[(size_t)row * 128 + colv] = f2bf(fmaxf(0.5f * acc[t][r], 0.f));
        }
    }
}

// ================= final linear 128 -> 64, f32 out =================
__global__ __launch_bounds__(256, 3) void final_mfma(
    const u16* __restrict__ x, const u16* __restrict__ WfT, const float* __restrict__ bias,
    float* __restrict__ out, int N) {
    __shared__ u16 sA[64 * SAP];
    __shared__ u16 sW[64 * SAP];
    f32x16 acc[1];
    const int lane = threadIdx.x & 63, wid = threadIdx.x >> 6;
    const int lm = lane & 31, hi = lane >> 5;
    const int id0 = wid;           // TPW=1, NB_C=2
    const int rb = id0 / 2;
    const int rowBase = blockIdx.x * 64;
    {
        float bv = bias[(id0 % 2) * 32 + lm];
#pragma unroll
        for (int i = 0; i < 16; ++i) acc[0][i] = bv;
    }
    stage_self_bf<128>(x, rowBase, N, sA);
    stage_w<128, 64>(WfT, sW);
    __syncthreads();
    gemm_mfma<128, 64, 1>(sA, sW, acc);
    {
        int colv = (id0 % 2) * 32 + lm;
#pragma unroll
        for (int r = 0; r < 16; ++r) {
            int row = rowBase + rb * 32 + (r & 3) + 8 * (r >> 2) + 4 * hi;
            if (row < N) out[(size_t)row * 64 + colv] = acc[0][r];
        }
    }
}

// ================= host =================
static void build_csr(const int* src, const int* dst, int E, int N,
                      int* deg, int* bsum, int* rp, int* col, float* inv, hipStream_t stream) {
    const int B = 256;
    hipMemsetAsync(deg, 0, (size_t)N * sizeof(int), stream);
    deg_kernel<<<(E + B - 1) / B, B, 0, stream>>>(dst, E, deg);
    int nb = (N + 1023) / 1024;
    scanA_kernel<<<nb, B, 0, stream>>>(deg, N, bsum);
    scanB_kernel<<<1, B, 0, stream>>>(bsum, nb);
    scanC_kernel<<<nb, B, 0, stream>>>(deg, N, bsum, rp, E);
    inv_from_deg<<<(N + B - 1) / B, B, 0, stream>>>(deg, inv, N);
    hipMemsetAsync(deg, 0, (size_t)N * sizeof(int), stream);  // reuse as cursor
    fill_kernel<<<(E + B - 1) / B, B, 0, stream>>>(src, dst, E, rp, deg, col);
}

extern "C" void kernel_launch(void* const* d_in, const int* in_sizes, int n_in,
                              void* d_out, int out_size, void* d_ws, size_t ws_size,
                              hipStream_t stream) {
    const float* x_user = (const float*)d_in[0];
    const float* x_item = (const float*)d_in[1];
    const int* ub_src = (const int*)d_in[2];
    const int* ub_dst = (const int*)d_in[3];
    const int* iu_src = (const int*)d_in[4];
    const int* iu_dst = (const int*)d_in[5];
    const int* ii_src = (const int*)d_in[6];
    const int* ii_dst = (const int*)d_in[7];
    const float* W1l_ub = (const float*)d_in[8];
    const float* W1r_ub = (const float*)d_in[9];
    const float* b1_ub = (const float*)d_in[10];
    const float* W1l_iu = (const float*)d_in[11];
    const float* W1r_iu = (const float*)d_in[12];
    const float* b1_iu = (const float*)d_in[13];
    const float* W1l_ii = (const float*)d_in[14];
    const float* W1r_ii = (const float*)d_in[15];
    const float* b1_ii = (const float*)d_in[16];
    const float* W23l = (const float*)d_in[17];
    const float* W23r = (const float*)d_in[18];
    const float* b23 = (const float*)d_in[19];
    const float* Wf_user = (const float*)d_in[20];
    const float* bf_user = (const float*)d_in[21];
    const float* Wf_item = (const float*)d_in[22];
    const float* bf_item = (const float*)d_in[23];

    // ---- workspace layout (~167.5 MB) ----
    char* p = (char*)d_ws;
    u16* xu_bf  = (u16*)p;  p += (size_t)NU_ * 128 * 2;  // 51.2 MB
    u16* xiA_bf = (u16*)p;  p += (size_t)NI_ * 128 * 2;  // 25.6
    u16* xiB_bf = (u16*)p;  p += (size_t)NI_ * 128 * 2;  // 25.6
    u16* xu0_bf = (u16*)p;  p += (size_t)NU_ * 64 * 2;   // 25.6 (deg/bsum alias here pre-cvt)
    u16* xi0_bf = (u16*)p;  p += (size_t)NI_ * 128 * 2;  // 25.6
    u16* wt     = (u16*)p;  p += (size_t)294912 * 2;     // 0.59
    float* inv_iu = (float*)p; p += (size_t)NU_ * 4;
    float* inv_ub = (float*)p; p += (size_t)NI_ * 4;
    float* inv_ii = (float*)p; p += (size_t)NI_ * 4;
    int* rp_iu = (int*)p;  p += (size_t)(NU_ + 4) * 4;
    int* rp_ub = (int*)p;  p += (size_t)(NI_ + 4) * 4;
    int* rp_ii = (int*)p;  p += (size_t)(NI_ + 4) * 4;
    int* col_iu = (int*)p; p += (size_t)E_IU * 4;
    int* col_ub = (int*)p; p += (size_t)E_UB * 4;
    int* col_ii = (int*)p; p += (size_t)E_II * 4;
    // deg/bsum alias the xu0_bf region (CSR build completes before cvt writes it)
    int* deg = (int*)xu0_bf;
    int* bsum = deg + NU_;

    // weight slot offsets (bf16 elems), each stored transposed [N][K]
    u16* wt_W1l_ub = wt + 0;        // [128][64]
    u16* wt_W1r_ub = wt + 8192;     // [128][128]
    u16* wt_W1l_iu = wt + 24576;
    u16* wt_W1r_iu = wt + 40960;    // [128][64]
    u16* wt_W1l_ii = wt + 49152;
    u16* wt_W1r_ii = wt + 65536;
    u16* wt_W23l   = wt + 81920;    // 6 x [128][128]
    u16* wt_W23r   = wt + 180224;   // 6 x [128][128]
    u16* wt_Wf_u   = wt + 278528;   // [64][128]
    u16* wt_Wf_i   = wt + 286720;   // [64][128]

    // ---- CSR build (uses deg alias; must precede conversions) ----
    build_csr(iu_src, iu_dst, E_IU, NU_, deg, bsum, rp_iu, col_iu, inv_iu, stream);
    build_csr(ub_src, ub_dst, E_UB, NI_, deg, bsum, rp_ub, col_ub, inv_ub, stream);
    build_csr(ii_src, ii_dst, E_II, NI_, deg, bsum, rp_ii, col_ii, inv_ii, stream);

    // ---- conversions ----
    cvt_kernel<<<12500, 256, 0, stream>>>(x_user, xu0_bf, NU_ * 64 / 4);
    cvt_kernel<<<12500, 256, 0, stream>>>(x_item, xi0_bf, NI_ * 128 / 4);
    wt_kernel<<<32, 256, 0, stream>>>(W1l_ub, wt_W1l_ub, 64, 128);
    wt_kernel<<<64, 256, 0, stream>>>(W1r_ub, wt_W1r_ub, 128, 128);
    wt_kernel<<<64, 256, 0, stream>>>(W1l_iu, wt_W1l_iu, 128, 128);
    wt_kernel<<<32, 256, 0, stream>>>(W1r_iu, wt_W1r_iu, 64, 128);
    wt_kernel<<<64, 256, 0, stream>>>(W1l_ii, wt_W1l_ii, 128, 128);
    wt_kernel<<<64, 256, 0, stream>>>(W1r_ii, wt_W1r_ii, 128, 128);
    wt_batch_kernel<<<384, 256, 0, stream>>>(W23l, wt_W23l, 6);
    wt_batch_kernel<<<384, 256, 0, stream>>>(W23r, wt_W23r, 6);
    wt_kernel<<<32, 256, 0, stream>>>(Wf_user, wt_Wf_u, 128, 64);
    wt_kernel<<<32, 256, 0, stream>>>(Wf_item, wt_Wf_i, 128, 64);

    const int gU = NU_ / 64;             // 3125
    const int gI = (NI_ + 63) / 64;      // 1563

    // ---- layer 1 ----
    item_mfma<64, 128, 128><<<gI, 256, 0, stream>>>(
        xu0_bf, rp_ub, col_ub, inv_ub, wt_W1l_ub, wt_W1r_ub, b1_ub,
        xi0_bf, rp_ii, col_ii, inv_ii, wt_W1l_ii, wt_W1r_ii, b1_ii,
        xi0_bf, xiA_bf, NI_);
    user_mfma<128, 64><<<gU, 256, 0, stream>>>(
        xi0_bf, rp_iu, col_iu, inv_iu, xu0_bf, wt_W1l_iu, wt_W1r_iu, b1_iu, xu_bf, NU_);

    // ---- layers 2-3 ----
    for (int l = 0; l < 2; ++l) {
        const u16* cur = (l == 0) ? xiA_bf : xiB_bf;
        u16* nxt = (l == 0) ? xiB_bf : xiA_bf;
        const u16* wl_ub = wt_W23l + (size_t)(l * 3 + 0) * 16384;
        const u16* wr_ub = wt_W23r + (size_t)(l * 3 + 0) * 16384;
        const u16* wl_iu = wt_W23l + (size_t)(l * 3 + 1) * 16384;
        const u16* wr_iu = wt_W23r + (size_t)(l * 3 + 1) * 16384;
        const u16* wl_ii = wt_W23l + (size_t)(l * 3 + 2) * 16384;
        const u16* wr_ii = wt_W23r + (size_t)(l * 3 + 2) * 16384;
        const float* b_ub = b23 + (size_t)(l * 3 + 0) * 128;
        const float* b_iu = b23 + (size_t)(l * 3 + 1) * 128;
        const float* b_ii = b23 + (size_t)(l * 3 + 2) * 128;

        // item first (ub-gather needs pre-update xu)
        item_mfma<128, 128, 128><<<gI, 256, 0, stream>>>(
            xu_bf, rp_ub, col_ub, inv_ub, wl_ub, wr_ub, b_ub,
            cur, rp_ii, col_ii, inv_ii, wl_ii, wr_ii, b_ii,
            cur, nxt, NI_);
        user_mfma<128, 128><<<gU, 256, 0, stream>>>(
            cur, rp_iu, col_iu, inv_iu, xu_bf, wl_iu, wr_iu, b_iu, xu_bf, NU_);
    }

    // ---- finals (layer-3 item output is xiA_bf) ----
    float* out = (float*)d_out;
    final_mfma<<<gU, 256, 0, stream>>>(xu_bf, wt_Wf_u, bf_user, out, NU_);
    final_mfma<<<gI, 256, 0, stream>>>(xiA_bf, wt_Wf_i, bf_item, out + (size_t)NU_ * 64, NI_);
}

// Round 9
// 1647.492 us; speedup vs baseline: 2.0867x; 1.1720x over previous
//
#include <hip/hip_runtime.h>

typedef unsigned short u16;
typedef __attribute__((ext_vector_type(4))) unsigned short u16x4;
typedef __attribute__((ext_vector_type(4))) short s16x4;
typedef __attribute__((ext_vector_type(8))) short s16x8;
typedef __attribute__((ext_vector_type(16))) float f32x16;

constexpr int NU_ = 200000, NI_ = 100000;
constexpr int E_UB = 1000000, E_IU = 1000000, E_II = 500000;

__device__ inline float bf2f(u16 v) { return __uint_as_float(((unsigned)v) << 16); }
__device__ inline u16 f2bf(float f) {
    unsigned u = __float_as_uint(f);
    return (u16)((u + 0x7FFFu + ((u >> 16) & 1u)) >> 16);  // RNE
}

// ================= CSR build =================
__global__ void deg_kernel(const int* __restrict__ dst, int E, int* __restrict__ deg) {
    int i = blockIdx.x * blockDim.x + threadIdx.x;
    if (i < E) atomicAdd(&deg[dst[i]], 1);
}

__global__ void scanA_kernel(const int* __restrict__ deg, int N, int* __restrict__ bsum) {
    __shared__ int s[256];
    int b = blockIdx.x, t = threadIdx.x;
    int base = b * 1024 + t * 4;
    int v = 0;
#pragma unroll
    for (int j = 0; j < 4; ++j) { int i = base + j; if (i < N) v += deg[i]; }
    s[t] = v; __syncthreads();
    for (int off = 1; off < 256; off <<= 1) {
        int x = (t >= off) ? s[t - off] : 0;
        __syncthreads();
        s[t] += x;
        __syncthreads();
    }
    if (t == 255) bsum[b] = s[255];
}

__global__ void scanB_kernel(int* __restrict__ bsum, int nb) {
    __shared__ int s[256];
    int t = threadIdx.x;
    int v = (t < nb) ? bsum[t] : 0;
    s[t] = v; __syncthreads();
    for (int off = 1; off < 256; off <<= 1) {
        int x = (t >= off) ? s[t - off] : 0;
        __syncthreads();
        s[t] += x;
        __syncthreads();
    }
    if (t < nb) bsum[t] = s[t] - v;  // exclusive
}

__global__ void scanC_kernel(const int* __restrict__ deg, int N, const int* __restrict__ boff,
                             int* __restrict__ rp, int E) {
    __shared__ int s[256];
    int b = blockIdx.x, t = threadIdx.x;
    int base = b * 1024 + t * 4;
    int d[4]; int v = 0;
#pragma unroll
    for (int j = 0; j < 4; ++j) { int i = base + j; d[j] = (i < N) ? deg[i] : 0; v += d[j]; }
    s[t] = v; __syncthreads();
    for (int off = 1; off < 256; off <<= 1) {
        int x = (t >= off) ? s[t - off] : 0;
        __syncthreads();
        s[t] += x;
        __syncthreads();
    }
    int ex = boff[b] + s[t] - v;
#pragma unroll
    for (int j = 0; j < 4; ++j) { int i = base + j; if (i < N) rp[i] = ex; ex += d[j]; }
    if (b == 0 && t == 0) rp[N] = E;
}

__global__ void inv_from_deg(const int* __restrict__ deg, float* __restrict__ inv, int N) {
    int i = blockIdx.x * blockDim.x + threadIdx.x;
    if (i < N) inv[i] = 1.0f / fmaxf((float)deg[i], 1.0f);
}

__global__ void fill_kernel(const int* __restrict__ src, const int* __restrict__ dst, int E,
                            const int* __restrict__ rp, int* __restrict__ cur, int* __restrict__ col) {
    int e = blockIdx.x * blockDim.x + threadIdx.x;
    if (e < E) {
        int d = dst[e];
        int p = atomicAdd(&cur[d], 1);
        col[rp[d] + p] = src[e];
    }
}

// ================= conversions =================
__global__ void cvt_kernel(const float* __restrict__ in, u16* __restrict__ out, int n4) {
    int i = blockIdx.x * 256 + threadIdx.x;
    if (i < n4) {
        float4 v = reinterpret_cast<const float4*>(in)[i];
        u16x4 o = { f2bf(v.x), f2bf(v.y), f2bf(v.z), f2bf(v.w) };
        reinterpret_cast<u16x4*>(out)[i] = o;
    }
}

// src [K][N] f32 -> dst [N][K] bf16 (transposed)
__global__ void wt_kernel(const float* __restrict__ src, u16* __restrict__ dst, int K, int N) {
    int i = blockIdx.x * 256 + threadIdx.x;
    if (i < K * N) { int k = i / N, n = i - k * N; dst[n * K + k] = f2bf(src[i]); }
}

__global__ void wt_batch_kernel(const float* __restrict__ src, u16* __restrict__ dst, int nmat) {
    int i = blockIdx.x * 256 + threadIdx.x;
    if (i < nmat * 16384) {
        int m = i >> 14, rem = i & 16383;
        int k = rem >> 7, n = rem & 127;
        dst[(m << 14) + (n << 7) + k] = f2bf(src[i]);
    }
}

// ================= standalone gather: agg[node] = mean of src rows =================
template<int K, bool F32SRC>
__global__ __launch_bounds__(256, 8) void gather_kernel(
    const void* __restrict__ xsrc, const int* __restrict__ rp, const int* __restrict__ col,
    const float* __restrict__ inv, u16* __restrict__ agg, int N) {
    constexpr int LPR = K / 4;
    long long gt = (long long)blockIdx.x * 256 + threadIdx.x;
    int node = (int)(gt / LPR);
    int lane = (int)(gt % LPR);
    if (node >= N) return;
    float a0 = 0.f, a1 = 0.f, a2 = 0.f, a3 = 0.f;
    int s = rp[node], e = rp[node + 1];
    for (; s + 2 <= e; s += 2) {
        int c0 = col[s], c1 = col[s + 1];
        if constexpr (F32SRC) {
            float4 v0 = reinterpret_cast<const float4*>(xsrc)[(size_t)c0 * LPR + lane];
            float4 v1 = reinterpret_cast<const float4*>(xsrc)[(size_t)c1 * LPR + lane];
            a0 += v0.x + v1.x; a1 += v0.y + v1.y; a2 += v0.z + v1.z; a3 += v0.w + v1.w;
        } else {
            u16x4 v0 = reinterpret_cast<const u16x4*>(xsrc)[(size_t)c0 * LPR + lane];
            u16x4 v1 = reinterpret_cast<const u16x4*>(xsrc)[(size_t)c1 * LPR + lane];
            a0 += bf2f(v0.x) + bf2f(v1.x); a1 += bf2f(v0.y) + bf2f(v1.y);
            a2 += bf2f(v0.z) + bf2f(v1.z); a3 += bf2f(v0.w) + bf2f(v1.w);
        }
    }
    if (s < e) {
        int c = col[s];
        if constexpr (F32SRC) {
            float4 v = reinterpret_cast<const float4*>(xsrc)[(size_t)c * LPR + lane];
            a0 += v.x; a1 += v.y; a2 += v.z; a3 += v.w;
        } else {
            u16x4 v = reinterpret_cast<const u16x4*>(xsrc)[(size_t)c * LPR + lane];
            a0 += bf2f(v.x); a1 += bf2f(v.y); a2 += bf2f(v.z); a3 += bf2f(v.w);
        }
    }
    float sc = inv[node];
    u16x4 o = { f2bf(a0 * sc), f2bf(a1 * sc), f2bf(a2 * sc), f2bf(a3 * sc) };
    reinterpret_cast<u16x4*>(agg)[(size_t)node * LPR + lane] = o;
}

// ================= dense MFMA GEMM from global (no LDS) =================
// Block 256 = 4 waves, 64 rows x NCOL cols. mfma_f32_32x32x16_bf16; C/D:
// col=lane&31, row=(r&3)+8*(r>>2)+4*(lane>>5)  [verified round 7]
template<int K, int NCOL, int TPW, bool A_F32>
__device__ inline void gemm_g(const void* __restrict__ A, const u16* __restrict__ Wt,
                              int rowBase, f32x16* acc) {
    constexpr int NB_C = NCOL / 32;
    const int lane = threadIdx.x & 63, wid = threadIdx.x >> 6;
    const int lm = lane & 31, hi = lane >> 5;
    const int id0 = wid * TPW;
    const int rb = id0 / NB_C;
    const int arow = rowBase + rb * 32 + lm;
#pragma unroll 4
    for (int kc = 0; kc < K; kc += 16) {
        s16x8 a;
        if constexpr (A_F32) {
            const float* pa = (const float*)A + (size_t)arow * K + kc + 4 * hi;
            float4 f0 = *reinterpret_cast<const float4*>(pa);
            float4 f1 = *reinterpret_cast<const float4*>(pa + 8);
            a = s16x8{ (short)f2bf(f0.x), (short)f2bf(f0.y), (short)f2bf(f0.z), (short)f2bf(f0.w),
                       (short)f2bf(f1.x), (short)f2bf(f1.y), (short)f2bf(f1.z), (short)f2bf(f1.w) };
        } else {
            const u16* pa = (const u16*)A + (size_t)arow * K + kc + 4 * hi;
            s16x4 q0 = *reinterpret_cast<const s16x4*>(pa);
            s16x4 q1 = *reinterpret_cast<const s16x4*>(pa + 8);
            a = s16x8{ q0.x, q0.y, q0.z, q0.w, q1.x, q1.y, q1.z, q1.w };
        }
#pragma unroll
        for (int t = 0; t < TPW; ++t) {
            const int cb = (id0 + t) % NB_C;
            const u16* pb = Wt + (size_t)(cb * 32 + lm) * K + kc + 4 * hi;
            s16x4 r0 = *reinterpret_cast<const s16x4*>(pb);
            s16x4 r1 = *reinterpret_cast<const s16x4*>(pb + 8);
            s16x8 b = s16x8{ r0.x, r0.y, r0.z, r0.w, r1.x, r1.y, r1.z, r1.w };
            acc[t] = __builtin_amdgcn_mfma_f32_32x32x16_bf16(a, b, acc[t], 0, 0, 0);
        }
    }
}

// item: out = relu(0.5*(aggA@WlA + aggB@WlB + self@WrA + self@WrB + bA + bB))
template<int KA, int KB, int KS, bool SELF_F32>
__global__ __launch_bounds__(256, 4) void item_dense(
    const u16* __restrict__ aggA, const u16* __restrict__ WlAT, const float* __restrict__ bA,
    const u16* __restrict__ aggB, const u16* __restrict__ WlBT, const float* __restrict__ bB,
    const u16* __restrict__ WrAT, const u16* __restrict__ WrBT,
    const void* __restrict__ xself, u16* __restrict__ out, int N) {
    f32x16 acc[2];
    const int lane = threadIdx.x & 63, wid = threadIdx.x >> 6;
    const int lm = lane & 31, hi = lane >> 5;
    const int id0 = wid * 2;
    const int rb = id0 / 4;
    const int rowBase = min(blockIdx.x * 64, N - 64);
#pragma unroll
    for (int t = 0; t < 2; ++t) {
        int cv = ((id0 + t) % 4) * 32 + lm;
        float bv = bA[cv] + bB[cv];
#pragma unroll
        for (int i = 0; i < 16; ++i) acc[t][i] = bv;
    }
    gemm_g<KA, 128, 2, false>(aggA, WlAT, rowBase, acc);
    gemm_g<KB, 128, 2, false>(aggB, WlBT, rowBase, acc);
    gemm_g<KS, 128, 2, SELF_F32>(xself, WrAT, rowBase, acc);
    gemm_g<KS, 128, 2, SELF_F32>(xself, WrBT, rowBase, acc);
    __syncthreads();  // all waves done reading before any (potentially aliased) writes
#pragma unroll
    for (int t = 0; t < 2; ++t) {
        int colv = ((id0 + t) % 4) * 32 + lm;
#pragma unroll
        for (int r = 0; r < 16; ++r) {
            int row = rowBase + rb * 32 + (r & 3) + 8 * (r >> 2) + 4 * hi;
            out[(size_t)row * 128 + colv] = f2bf(fmaxf(0.5f * acc[t][r], 0.f));
        }
    }
}

// user: out = relu(agg@Wl + self@Wr + b); out may alias xself (in-place, block-local rows)
template<int KA, int KS, bool SELF_F32>
__global__ __launch_bounds__(256, 4) void user_dense(
    const u16* __restrict__ agg, const u16* __restrict__ WlT, const float* __restrict__ bias,
    const u16* __restrict__ WrT, const void* __restrict__ xself,
    u16* __restrict__ out, int N) {
    f32x16 acc[2];
    const int lane = threadIdx.x & 63, wid = threadIdx.x >> 6;
    const int lm = lane & 31, hi = lane >> 5;
    const int id0 = wid * 2;
    const int rb = id0 / 4;
    const int rowBase = min(blockIdx.x * 64, N - 64);
#pragma unroll
    for (int t = 0; t < 2; ++t) {
        float bv = bias[((id0 + t) % 4) * 32 + lm];
#pragma unroll
        for (int i = 0; i < 16; ++i) acc[t][i] = bv;
    }
    gemm_g<KA, 128, 2, false>(agg, WlT, rowBase, acc);
    gemm_g<KS, 128, 2, SELF_F32>(xself, WrT, rowBase, acc);
    // RACE FIX (round 8 bug): in-place update — wave i must not write rows
    // that wave j is still reading from global as its self-term A operand.
    __syncthreads();
#pragma unroll
    for (int t = 0; t < 2; ++t) {
        int colv = ((id0 + t) % 4) * 32 + lm;
#pragma unroll
        for (int r = 0; r < 16; ++r) {
            int row = rowBase + rb * 32 + (r & 3) + 8 * (r >> 2) + 4 * hi;
            out[(size_t)row * 128 + colv] = f2bf(fmaxf(acc[t][r], 0.f));
        }
    }
}

// final 128->64 linear, f32 out
__global__ __launch_bounds__(256, 4) void final_dense(
    const u16* __restrict__ x, const u16* __restrict__ WfT, const float* __restrict__ bias,
    float* __restrict__ out, int N) {
    f32x16 acc[1];
    const int lane = threadIdx.x & 63, wid = threadIdx.x >> 6;
    const int lm = lane & 31, hi = lane >> 5;
    const int rb = wid / 2;
    const int rowBase = min(blockIdx.x * 64, N - 64);
    {
        float bv = bias[(wid % 2) * 32 + lm];
#pragma unroll
        for (int i = 0; i < 16; ++i) acc[0][i] = bv;
    }
    gemm_g<128, 64, 1, false>(x, WfT, rowBase, acc);
    {
        int colv = (wid % 2) * 32 + lm;
#pragma unroll
        for (int r = 0; r < 16; ++r) {
            int row = rowBase + rb * 32 + (r & 3) + 8 * (r >> 2) + 4 * hi;
            out[(size_t)row * 64 + colv] = acc[0][r];
        }
    }
}

// ================= host =================
static void build_csr(const int* src, const int* dst, int E, int N,
                      int* deg, int* bsum, int* rp, int* col, float* inv, hipStream_t stream) {
    const int B = 256;
    hipMemsetAsync(deg, 0, (size_t)N * sizeof(int), stream);
    deg_kernel<<<(E + B - 1) / B, B, 0, stream>>>(dst, E, deg);
    int nb = (N + 1023) / 1024;
    scanA_kernel<<<nb, B, 0, stream>>>(deg, N, bsum);
    scanB_kernel<<<1, B, 0, stream>>>(bsum, nb);
    scanC_kernel<<<nb, B, 0, stream>>>(deg, N, bsum, rp, E);
    inv_from_deg<<<(N + B - 1) / B, B, 0, stream>>>(deg, inv, N);
    hipMemsetAsync(deg, 0, (size_t)N * sizeof(int), stream);
    fill_kernel<<<(E + B - 1) / B, B, 0, stream>>>(src, dst, E, rp, deg, col);
}

extern "C" void kernel_launch(void* const* d_in, const int* in_sizes, int n_in,
                              void* d_out, int out_size, void* d_ws, size_t ws_size,
                              hipStream_t stream) {
    const float* x_user = (const float*)d_in[0];
    const float* x_item = (const float*)d_in[1];
    const int* ub_src = (const int*)d_in[2];
    const int* ub_dst = (const int*)d_in[3];
    const int* iu_src = (const int*)d_in[4];
    const int* iu_dst = (const int*)d_in[5];
    const int* ii_src = (const int*)d_in[6];
    const int* ii_dst = (const int*)d_in[7];
    const float* W1l_ub = (const float*)d_in[8];
    const float* W1r_ub = (const float*)d_in[9];
    const float* b1_ub = (const float*)d_in[10];
    const float* W1l_iu = (const float*)d_in[11];
    const float* W1r_iu = (const float*)d_in[12];
    const float* b1_iu = (const float*)d_in[13];
    const float* W1l_ii = (const float*)d_in[14];
    const float* W1r_ii = (const float*)d_in[15];
    const float* b1_ii = (const float*)d_in[16];
    const float* W23l = (const float*)d_in[17];
    const float* W23r = (const float*)d_in[18];
    const float* b23 = (const float*)d_in[19];
    const float* Wf_user = (const float*)d_in[20];
    const float* bf_user = (const float*)d_in[21];
    const float* Wf_item = (const float*)d_in[22];
    const float* bf_item = (const float*)d_in[23];

    // ---- workspace (~167 MB) ----
    char* p = (char*)d_ws;
    u16* xu_bf  = (u16*)p;  p += (size_t)NU_ * 128 * 2;   // 51.2 MB
    u16* xiA_bf = (u16*)p;  p += (size_t)NI_ * 128 * 2;   // 25.6
    u16* xi0_bf = (u16*)p;  p += (size_t)NI_ * 128 * 2;   // 25.6 (x_item bf16)
    u16* agg_ub = (u16*)p;  p += (size_t)NI_ * 128 * 2;   // 25.6 (deg/bsum alias pre-gather)
    u16* agg_ii = (u16*)p;  p += (size_t)NI_ * 128 * 2;   // 25.6
    u16* wt     = (u16*)p;  p += (size_t)294912 * 2;      // 0.59
    float* inv_iu = (float*)p; p += (size_t)NU_ * 4;
    float* inv_ub = (float*)p; p += (size_t)NI_ * 4;
    float* inv_ii = (float*)p; p += (size_t)NI_ * 4;
    int* rp_iu = (int*)p;  p += (size_t)(NU_ + 4) * 4;
    int* rp_ub = (int*)p;  p += (size_t)(NI_ + 4) * 4;
    int* rp_ii = (int*)p;  p += (size_t)(NI_ + 4) * 4;
    int* col_iu = (int*)p; p += (size_t)E_IU * 4;
    int* col_ub = (int*)p; p += (size_t)E_UB * 4;
    int* col_ii = (int*)p; p += (size_t)E_II * 4;
    // deg/bsum alias agg_ub region (CSR build completes before gathers write it)
    int* deg = (int*)agg_ub;
    int* bsum = deg + NU_;
    // d_out hosts agg_iu [NU][128] bf16 (51.2 MB) + xiB [NI][128] bf16 (25.6 MB) = 76.8 MB.
    // Both dead before the final_dense kernels write d_out.
    u16* agg_iu = (u16*)d_out;
    u16* xiB_bf = (u16*)((char*)d_out + (size_t)NU_ * 128 * 2);

    // weight slots (bf16, transposed [N][K])
    u16* wt_W1l_ub = wt + 0;        // [128][64]
    u16* wt_W1r_ub = wt + 8192;     // [128][128]
    u16* wt_W1l_iu = wt + 24576;    // [128][128]
    u16* wt_W1r_iu = wt + 40960;    // [128][64]
    u16* wt_W1l_ii = wt + 49152;    // [128][128]
    u16* wt_W1r_ii = wt + 65536;    // [128][128]
    u16* wt_W23l   = wt + 81920;    // 6 x [128][128]
    u16* wt_W23r   = wt + 180224;   // 6 x [128][128]
    u16* wt_Wf_u   = wt + 278528;   // [64][128]
    u16* wt_Wf_i   = wt + 286720;   // [64][128]

    // ---- CSR build (deg alias in agg_ub; precedes gathers) ----
    build_csr(iu_src, iu_dst, E_IU, NU_, deg, bsum, rp_iu, col_iu, inv_iu, stream);
    build_csr(ub_src, ub_dst, E_UB, NI_, deg, bsum, rp_ub, col_ub, inv_ub, stream);
    build_csr(ii_src, ii_dst, E_II, NI_, deg, bsum, rp_ii, col_ii, inv_ii, stream);

    // ---- conversions ----
    cvt_kernel<<<(NI_ * 32 + 255) / 256, 256, 0, stream>>>(x_item, xi0_bf, NI_ * 32);
    wt_kernel<<<32, 256, 0, stream>>>(W1l_ub, wt_W1l_ub, 64, 128);
    wt_kernel<<<64, 256, 0, stream>>>(W1r_ub, wt_W1r_ub, 128, 128);
    wt_kernel<<<64, 256, 0, stream>>>(W1l_iu, wt_W1l_iu, 128, 128);
    wt_kernel<<<32, 256, 0, stream>>>(W1r_iu, wt_W1r_iu, 64, 128);
    wt_kernel<<<64, 256, 0, stream>>>(W1l_ii, wt_W1l_ii, 128, 128);
    wt_kernel<<<64, 256, 0, stream>>>(W1r_ii, wt_W1r_ii, 128, 128);
    wt_batch_kernel<<<384, 256, 0, stream>>>(W23l, wt_W23l, 6);
    wt_batch_kernel<<<384, 256, 0, stream>>>(W23r, wt_W23r, 6);
    wt_kernel<<<32, 256, 0, stream>>>(Wf_user, wt_Wf_u, 128, 64);
    wt_kernel<<<32, 256, 0, stream>>>(Wf_item, wt_Wf_i, 128, 64);

    const int gU = NU_ / 64;         // 3125 (exact)
    const int gI = (NI_ + 63) / 64;  // 1563 (overlap trick for tail)
    const int gg128I = (NI_ * 32 + 255) / 256;  // gather grids
    const int gg128U = (NU_ * 32 + 255) / 256;
    const int gg64I  = (NI_ * 16 + 255) / 256;

    // ---- layer 1 ----
    gather_kernel<64, true><<<gg64I, 256, 0, stream>>>(x_user, rp_ub, col_ub, inv_ub, agg_ub, NI_);
    gather_kernel<128, false><<<gg128I, 256, 0, stream>>>(xi0_bf, rp_ii, col_ii, inv_ii, agg_ii, NI_);
    gather_kernel<128, false><<<gg128U, 256, 0, stream>>>(xi0_bf, rp_iu, col_iu, inv_iu, agg_iu, NU_);
    item_dense<64, 128, 128, true><<<gI, 256, 0, stream>>>(
        agg_ub, wt_W1l_ub, b1_ub, agg_ii, wt_W1l_ii, b1_ii,
        wt_W1r_ub, wt_W1r_ii, x_item, xiA_bf, NI_);
    user_dense<128, 64, true><<<gU, 256, 0, stream>>>(
        agg_iu, wt_W1l_iu, b1_iu, wt_W1r_iu, x_user, xu_bf, NU_);

    // ---- layers 2-3 ----
    for (int l = 0; l < 2; ++l) {
        const u16* cur = (l == 0) ? xiA_bf : xiB_bf;
        u16* nxt = (l == 0) ? xiB_bf : xiA_bf;
        const u16* wl_ub = wt_W23l + (size_t)(l * 3 + 0) * 16384;
        const u16* wr_ub = wt_W23r + (size_t)(l * 3 + 0) * 16384;
        const u16* wl_iu = wt_W23l + (size_t)(l * 3 + 1) * 16384;
        const u16* wr_iu = wt_W23r + (size_t)(l * 3 + 1) * 16384;
        const u16* wl_ii = wt_W23l + (size_t)(l * 3 + 2) * 16384;
        const u16* wr_ii = wt_W23r + (size_t)(l * 3 + 2) * 16384;
        const float* b_ub = b23 + (size_t)(l * 3 + 0) * 128;
        const float* b_iu = b23 + (size_t)(l * 3 + 1) * 128;
        const float* b_ii = b23 + (size_t)(l * 3 + 2) * 128;

        gather_kernel<128, false><<<gg128I, 256, 0, stream>>>(xu_bf, rp_ub, col_ub, inv_ub, agg_ub, NI_);
        gather_kernel<128, false><<<gg128I, 256, 0, stream>>>(cur, rp_ii, col_ii, inv_ii, agg_ii, NI_);
        gather_kernel<128, false><<<gg128U, 256, 0, stream>>>(cur, rp_iu, col_iu, inv_iu, agg_iu, NU_);
        item_dense<128, 128, 128, false><<<gI, 256, 0, stream>>>(
            agg_ub, wl_ub, b_ub, agg_ii, wl_ii, b_ii,
            wr_ub, wr_ii, cur, nxt, NI_);
        user_dense<128, 128, false><<<gU, 256, 0, stream>>>(
            agg_iu, wl_iu, b_iu, wr_iu, xu_bf, xu_bf, NU_);
    }

    // ---- finals (layer-3 item output = xiA_bf); these overwrite agg_iu/xiB (dead) ----
    float* out = (float*)d_out;
    final_dense<<<gU, 256, 0, stream>>>(xu_bf, wt_Wf_u, bf_user, out, NU_);
    final_dense<<<gI, 256, 0, stream>>>(xiA_bf, wt_Wf_i, bf_item, out + (size_t)NU_ * 64, NI_);
}

// Round 10
// 1238.237 us; speedup vs baseline: 2.7763x; 1.3305x over previous
//
#include <hip/hip_runtime.h>

typedef unsigned short u16;
typedef __attribute__((ext_vector_type(4))) unsigned short u16x4;
typedef __attribute__((ext_vector_type(4))) short s16x4;
typedef __attribute__((ext_vector_type(8))) short s16x8;
typedef __attribute__((ext_vector_type(16))) float f32x16;

constexpr int NU_ = 200000, NI_ = 100000;
constexpr int E_UB = 1000000, E_IU = 1000000, E_II = 500000;
constexpr int SAP = 132;  // LDS row stride (bf16 elems)

__device__ inline float bf2f(u16 v) { return __uint_as_float(((unsigned)v) << 16); }
__device__ inline u16 f2bf(float f) {
    unsigned u = __float_as_uint(f);
    return (u16)((u + 0x7FFFu + ((u >> 16) & 1u)) >> 16);  // RNE
}

// ================= CSR build =================
__global__ void deg_kernel(const int* __restrict__ dst, int E, int* __restrict__ deg) {
    int i = blockIdx.x * blockDim.x + threadIdx.x;
    if (i < E) atomicAdd(&deg[dst[i]], 1);
}

__global__ void scanA_kernel(const int* __restrict__ deg, int N, int* __restrict__ bsum) {
    __shared__ int s[256];
    int b = blockIdx.x, t = threadIdx.x;
    int base = b * 1024 + t * 4;
    int v = 0;
#pragma unroll
    for (int j = 0; j < 4; ++j) { int i = base + j; if (i < N) v += deg[i]; }
    s[t] = v; __syncthreads();
    for (int off = 1; off < 256; off <<= 1) {
        int x = (t >= off) ? s[t - off] : 0;
        __syncthreads();
        s[t] += x;
        __syncthreads();
    }
    if (t == 255) bsum[b] = s[255];
}

__global__ void scanB_kernel(int* __restrict__ bsum, int nb) {
    __shared__ int s[256];
    int t = threadIdx.x;
    int v = (t < nb) ? bsum[t] : 0;
    s[t] = v; __syncthreads();
    for (int off = 1; off < 256; off <<= 1) {
        int x = (t >= off) ? s[t - off] : 0;
        __syncthreads();
        s[t] += x;
        __syncthreads();
    }
    if (t < nb) bsum[t] = s[t] - v;  // exclusive
}

__global__ void scanC_kernel(const int* __restrict__ deg, int N, const int* __restrict__ boff,
                             int* __restrict__ rp, int E) {
    __shared__ int s[256];
    int b = blockIdx.x, t = threadIdx.x;
    int base = b * 1024 + t * 4;
    int d[4]; int v = 0;
#pragma unroll
    for (int j = 0; j < 4; ++j) { int i = base + j; d[j] = (i < N) ? deg[i] : 0; v += d[j]; }
    s[t] = v; __syncthreads();
    for (int off = 1; off < 256; off <<= 1) {
        int x = (t >= off) ? s[t - off] : 0;
        __syncthreads();
        s[t] += x;
        __syncthreads();
    }
    int ex = boff[b] + s[t] - v;
#pragma unroll
    for (int j = 0; j < 4; ++j) { int i = base + j; if (i < N) rp[i] = ex; ex += d[j]; }
    if (b == 0 && t == 0) rp[N] = E;
}

__global__ void inv_from_deg(const int* __restrict__ deg, float* __restrict__ inv, int N) {
    int i = blockIdx.x * blockDim.x + threadIdx.x;
    if (i < N) inv[i] = 1.0f / fmaxf((float)deg[i], 1.0f);
}

__global__ void fill_kernel(const int* __restrict__ src, const int* __restrict__ dst, int E,
                            const int* __restrict__ rp, int* __restrict__ cur, int* __restrict__ col) {
    int e = blockIdx.x * blockDim.x + threadIdx.x;
    if (e < E) {
        int d = dst[e];
        int p = atomicAdd(&cur[d], 1);
        col[rp[d] + p] = src[e];
    }
}

// ================= conversions =================
__global__ void cvt_kernel(const float* __restrict__ in, u16* __restrict__ out, int n4) {
    int i = blockIdx.x * 256 + threadIdx.x;
    if (i < n4) {
        float4 v = reinterpret_cast<const float4*>(in)[i];
        u16x4 o = { f2bf(v.x), f2bf(v.y), f2bf(v.z), f2bf(v.w) };
        reinterpret_cast<u16x4*>(out)[i] = o;
    }
}

// src [K][N] f32 -> dst [N][K] bf16 (transposed)
__global__ void wt_kernel(const float* __restrict__ src, u16* __restrict__ dst, int K, int N) {
    int i = blockIdx.x * 256 + threadIdx.x;
    if (i < K * N) { int k = i / N, n = i - k * N; dst[n * K + k] = f2bf(src[i]); }
}

__global__ void wt_batch_kernel(const float* __restrict__ src, u16* __restrict__ dst, int nmat) {
    int i = blockIdx.x * 256 + threadIdx.x;
    if (i < nmat * 16384) {
        int m = i >> 14, rem = i & 16383;
        int k = rem >> 7, n = rem & 127;
        dst[(m << 14) + (n << 7) + k] = f2bf(src[i]);
    }
}

// ================= standalone gather (round 9, verified) =================
template<int K, bool F32SRC>
__global__ __launch_bounds__(256, 8) void gather_kernel(
    const void* __restrict__ xsrc, const int* __restrict__ rp, const int* __restrict__ col,
    const float* __restrict__ inv, u16* __restrict__ agg, int N) {
    constexpr int LPR = K / 4;
    long long gt = (long long)blockIdx.x * 256 + threadIdx.x;
    int node = (int)(gt / LPR);
    int lane = (int)(gt % LPR);
    if (node >= N) return;
    float a0 = 0.f, a1 = 0.f, a2 = 0.f, a3 = 0.f;
    int s = rp[node], e = rp[node + 1];
    for (; s + 2 <= e; s += 2) {
        int c0 = col[s], c1 = col[s + 1];
        if constexpr (F32SRC) {
            float4 v0 = reinterpret_cast<const float4*>(xsrc)[(size_t)c0 * LPR + lane];
            float4 v1 = reinterpret_cast<const float4*>(xsrc)[(size_t)c1 * LPR + lane];
            a0 += v0.x + v1.x; a1 += v0.y + v1.y; a2 += v0.z + v1.z; a3 += v0.w + v1.w;
        } else {
            u16x4 v0 = reinterpret_cast<const u16x4*>(xsrc)[(size_t)c0 * LPR + lane];
            u16x4 v1 = reinterpret_cast<const u16x4*>(xsrc)[(size_t)c1 * LPR + lane];
            a0 += bf2f(v0.x) + bf2f(v1.x); a1 += bf2f(v0.y) + bf2f(v1.y);
            a2 += bf2f(v0.z) + bf2f(v1.z); a3 += bf2f(v0.w) + bf2f(v1.w);
        }
    }
    if (s < e) {
        int c = col[s];
        if constexpr (F32SRC) {
            float4 v = reinterpret_cast<const float4*>(xsrc)[(size_t)c * LPR + lane];
            a0 += v.x; a1 += v.y; a2 += v.z; a3 += v.w;
        } else {
            u16x4 v = reinterpret_cast<const u16x4*>(xsrc)[(size_t)c * LPR + lane];
            a0 += bf2f(v.x); a1 += bf2f(v.y); a2 += bf2f(v.z); a3 += bf2f(v.w);
        }
    }
    float sc = inv[node];
    u16x4 o = { f2bf(a0 * sc), f2bf(a1 * sc), f2bf(a2 * sc), f2bf(a3 * sc) };
    reinterpret_cast<u16x4*>(agg)[(size_t)node * LPR + lane] = o;
}

// ================= LDS-staged MFMA GEMM (round 7, verified) =================
// Block 256 = 4 waves, 64 rows. mfma_f32_32x32x16_bf16.
// C/D: col=lane&31, row=(r&3)+8*(r>>2)+4*(lane>>5).

// stage 64 contiguous rows (bf16 or f32 src) into sA[64][SAP]
template<int K, bool F32SRC>
__device__ inline void stage_rows(const void* __restrict__ x, int rowBase, int N, u16* sA) {
    constexpr int LPR = K / 4;
    constexpr int RPP = 256 / LPR;
    const int tid = threadIdx.x;
    const int lane = tid % LPR, rr = tid / LPR;
#pragma unroll
    for (int p = 0; p < 64 / RPP; ++p) {
        const int r = p * RPP + rr;
        const int node = rowBase + r;
        u16x4 o = { 0, 0, 0, 0 };
        if (node < N) {
            if constexpr (F32SRC) {
                float4 v = reinterpret_cast<const float4*>(x)[(size_t)node * LPR + lane];
                o = u16x4{ f2bf(v.x), f2bf(v.y), f2bf(v.z), f2bf(v.w) };
            } else {
                o = reinterpret_cast<const u16x4*>(x)[(size_t)node * LPR + lane];
            }
        }
        *reinterpret_cast<u16x4*>(sA + r * SAP + lane * 4) = o;
    }
}

// stage transposed weight [NCOL][K] bf16 -> sW [NCOL][SAP]
template<int K, int NCOL>
__device__ inline void stage_w(const u16* __restrict__ Wt, u16* sW) {
    constexpr int CH = K / 4;
    constexpr int TOT = NCOL * CH;
#pragma unroll
    for (int i = threadIdx.x; i < TOT; i += 256) {
        int n = i / CH, c = i - n * CH;
        *reinterpret_cast<u16x4*>(sW + n * SAP + c * 4) =
            *reinterpret_cast<const u16x4*>(Wt + (size_t)n * K + c * 4);
    }
}

template<int K, int NCOL, int TPW>
__device__ inline void gemm_mfma(const u16* sA, const u16* sW, f32x16* acc) {
    constexpr int NB_C = NCOL / 32;
    const int lane = threadIdx.x & 63;
    const int wid = threadIdx.x >> 6;
    const int lm = lane & 31, hi = lane >> 5;
    const int id0 = wid * TPW;
    const int rb = id0 / NB_C;
    const int arow = rb * 32 + lm;
#pragma unroll
    for (int kc = 0; kc < K; kc += 16) {
        const u16* pa = sA + arow * SAP + kc + 4 * hi;
        s16x4 q0 = *reinterpret_cast<const s16x4*>(pa);
        s16x4 q1 = *reinterpret_cast<const s16x4*>(pa + 8);
        s16x8 a = { q0.x, q0.y, q0.z, q0.w, q1.x, q1.y, q1.z, q1.w };
#pragma unroll
        for (int t = 0; t < TPW; ++t) {
            const int cb = (id0 + t) % NB_C;
            const u16* pb = sW + (cb * 32 + lm) * SAP + kc + 4 * hi;
            s16x4 r0 = *reinterpret_cast<const s16x4*>(pb);
            s16x4 r1 = *reinterpret_cast<const s16x4*>(pb + 8);
            s16x8 b = { r0.x, r0.y, r0.z, r0.w, r1.x, r1.y, r1.z, r1.w };
            acc[t] = __builtin_amdgcn_mfma_f32_32x32x16_bf16(a, b, acc[t], 0, 0, 0);
        }
    }
}

// user: out = relu(agg@Wl + self@Wr + b); out may alias xself (self staged behind barrier)
template<int KA, int KS, bool SELF_F32>
__global__ __launch_bounds__(256, 3) void user_lds(
    const u16* __restrict__ agg, const u16* __restrict__ WlT, const float* __restrict__ bias,
    const u16* __restrict__ WrT, const void* xself, u16* out, int N) {
    __shared__ u16 sA[64 * SAP];
    __shared__ u16 sW[128 * SAP];
    f32x16 acc[2];
    const int lane = threadIdx.x & 63, wid = threadIdx.x >> 6;
    const int lm = lane & 31, hi = lane >> 5;
    const int id0 = wid * 2;
    const int rb = id0 / 4;
    const int rowBase = blockIdx.x * 64;
#pragma unroll
    for (int t = 0; t < 2; ++t) {
        float bv = bias[((id0 + t) % 4) * 32 + lm];
#pragma unroll
        for (int i = 0; i < 16; ++i) acc[t][i] = bv;
    }
    stage_rows<KA, false>(agg, rowBase, N, sA);
    stage_w<KA, 128>(WlT, sW);
    __syncthreads();
    gemm_mfma<KA, 128, 2>(sA, sW, acc);
    __syncthreads();
    stage_rows<KS, SELF_F32>(xself, rowBase, N, sA);
    stage_w<KS, 128>(WrT, sW);
    __syncthreads();  // all self reads done before any global writes (in-place safety)
    gemm_mfma<KS, 128, 2>(sA, sW, acc);
#pragma unroll
    for (int t = 0; t < 2; ++t) {
        int colv = ((id0 + t) % 4) * 32 + lm;
#pragma unroll
        for (int r = 0; r < 16; ++r) {
            int row = rowBase + rb * 32 + (r & 3) + 8 * (r >> 2) + 4 * hi;
            if (row < N) out[(size_t)row * 128 + colv] = f2bf(fmaxf(acc[t][r], 0.f));
        }
    }
}

// item: out = relu(0.5*(aggA@WlA + aggB@WlB + self@WrA + self@WrB + bA + bB))
template<int KA, int KB, int KS, bool SELF_F32>
__global__ __launch_bounds__(256, 3) void item_lds(
    const u16* __restrict__ aggA, const u16* __restrict__ WlAT, const float* __restrict__ bA,
    const u16* __restrict__ aggB, const u16* __restrict__ WlBT, const float* __restrict__ bB,
    const u16* __restrict__ WrAT, const u16* __restrict__ WrBT,
    const void* __restrict__ xself, u16* __restrict__ out, int N) {
    __shared__ u16 sA[64 * SAP];
    __shared__ u16 sW[128 * SAP];
    f32x16 acc[2];
    const int lane = threadIdx.x & 63, wid = threadIdx.x >> 6;
    const int lm = lane & 31, hi = lane >> 5;
    const int id0 = wid * 2;
    const int rb = id0 / 4;
    const int rowBase = blockIdx.x * 64;
#pragma unroll
    for (int t = 0; t < 2; ++t) {
        int cv = ((id0 + t) % 4) * 32 + lm;
        float bv = bA[cv] + bB[cv];
#pragma unroll
        for (int i = 0; i < 16; ++i) acc[t][i] = bv;
    }
    stage_rows<KA, false>(aggA, rowBase, N, sA);
    stage_w<KA, 128>(WlAT, sW);
    __syncthreads();
    gemm_mfma<KA, 128, 2>(sA, sW, acc);
    __syncthreads();
    stage_rows<KB, false>(aggB, rowBase, N, sA);
    stage_w<KB, 128>(WlBT, sW);
    __syncthreads();
    gemm_mfma<KB, 128, 2>(sA, sW, acc);
    __syncthreads();
    stage_rows<KS, SELF_F32>(xself, rowBase, N, sA);
    stage_w<KS, 128>(WrAT, sW);
    __syncthreads();
    gemm_mfma<KS, 128, 2>(sA, sW, acc);
    __syncthreads();
    stage_w<KS, 128>(WrBT, sW);
    __syncthreads();
    gemm_mfma<KS, 128, 2>(sA, sW, acc);
#pragma unroll
    for (int t = 0; t < 2; ++t) {
        int colv = ((id0 + t) % 4) * 32 + lm;
#pragma unroll
        for (int r = 0; r < 16; ++r) {
            int row = rowBase + rb * 32 + (r & 3) + 8 * (r >> 2) + 4 * hi;
            if (row < N) out[(size_t)row * 128 + colv] = f2bf(fmaxf(0.5f * acc[t][r], 0.f));
        }
    }
}

// final 128->64 linear, f32 out
__global__ __launch_bounds__(256, 3) void final_lds(
    const u16* __restrict__ x, const u16* __restrict__ WfT, const float* __restrict__ bias,
    float* __restrict__ out, int N) {
    __shared__ u16 sA[64 * SAP];
    __shared__ u16 sW[64 * SAP];
    f32x16 acc[1];
    const int lane = threadIdx.x & 63, wid = threadIdx.x >> 6;
    const int lm = lane & 31, hi = lane >> 5;
    const int rb = wid / 2;
    const int rowBase = blockIdx.x * 64;
    {
        float bv = bias[(wid % 2) * 32 + lm];
#pragma unroll
        for (int i = 0; i < 16; ++i) acc[0][i] = bv;
    }
    stage_rows<128, false>(x, rowBase, N, sA);
    stage_w<128, 64>(WfT, sW);
    __syncthreads();
    gemm_mfma<128, 64, 1>(sA, sW, acc);
    {
        int colv = (wid % 2) * 32 + lm;
#pragma unroll
        for (int r = 0; r < 16; ++r) {
            int row = rowBase + rb * 32 + (r & 3) + 8 * (r >> 2) + 4 * hi;
            if (row < N) out[(size_t)row * 64 + colv] = acc[0][r];
        }
    }
}

// ================= host =================
static void build_csr(const int* src, const int* dst, int E, int N,
                      int* deg, int* bsum, int* rp, int* col, float* inv, hipStream_t stream) {
    const int B = 256;
    hipMemsetAsync(deg, 0, (size_t)N * sizeof(int), stream);
    deg_kernel<<<(E + B - 1) / B, B, 0, stream>>>(dst, E, deg);
    int nb = (N + 1023) / 1024;
    scanA_kernel<<<nb, B, 0, stream>>>(deg, N, bsum);
    scanB_kernel<<<1, B, 0, stream>>>(bsum, nb);
    scanC_kernel<<<nb, B, 0, stream>>>(deg, N, bsum, rp, E);
    inv_from_deg<<<(N + B - 1) / B, B, 0, stream>>>(deg, inv, N);
    hipMemsetAsync(deg, 0, (size_t)N * sizeof(int), stream);
    fill_kernel<<<(E + B - 1) / B, B, 0, stream>>>(src, dst, E, rp, deg, col);
}

extern "C" void kernel_launch(void* const* d_in, const int* in_sizes, int n_in,
                              void* d_out, int out_size, void* d_ws, size_t ws_size,
                              hipStream_t stream) {
    const float* x_user = (const float*)d_in[0];
    const float* x_item = (const float*)d_in[1];
    const int* ub_src = (const int*)d_in[2];
    const int* ub_dst = (const int*)d_in[3];
    const int* iu_src = (const int*)d_in[4];
    const int* iu_dst = (const int*)d_in[5];
    const int* ii_src = (const int*)d_in[6];
    const int* ii_dst = (const int*)d_in[7];
    const float* W1l_ub = (const float*)d_in[8];
    const float* W1r_ub = (const float*)d_in[9];
    const float* b1_ub = (const float*)d_in[10];
    const float* W1l_iu = (const float*)d_in[11];
    const float* W1r_iu = (const float*)d_in[12];
    const float* b1_iu = (const float*)d_in[13];
    const float* W1l_ii = (const float*)d_in[14];
    const float* W1r_ii = (const float*)d_in[15];
    const float* b1_ii = (const float*)d_in[16];
    const float* W23l = (const float*)d_in[17];
    const float* W23r = (const float*)d_in[18];
    const float* b23 = (const float*)d_in[19];
    const float* Wf_user = (const float*)d_in[20];
    const float* bf_user = (const float*)d_in[21];
    const float* Wf_item = (const float*)d_in[22];
    const float* bf_item = (const float*)d_in[23];

    // ---- workspace (~167 MB) ----
    char* p = (char*)d_ws;
    u16* xu_bf  = (u16*)p;  p += (size_t)NU_ * 128 * 2;   // 51.2 MB
    u16* xiA_bf = (u16*)p;  p += (size_t)NI_ * 128 * 2;   // 25.6
    u16* xi0_bf = (u16*)p;  p += (size_t)NI_ * 128 * 2;   // 25.6 (x_item bf16)
    u16* agg_ub = (u16*)p;  p += (size_t)NI_ * 128 * 2;   // 25.6 (deg/bsum alias pre-gather)
    u16* agg_ii = (u16*)p;  p += (size_t)NI_ * 128 * 2;   // 25.6
    u16* wt     = (u16*)p;  p += (size_t)294912 * 2;      // 0.59
    float* inv_iu = (float*)p; p += (size_t)NU_ * 4;
    float* inv_ub = (float*)p; p += (size_t)NI_ * 4;
    float* inv_ii = (float*)p; p += (size_t)NI_ * 4;
    int* rp_iu = (int*)p;  p += (size_t)(NU_ + 4) * 4;
    int* rp_ub = (int*)p;  p += (size_t)(NI_ + 4) * 4;
    int* rp_ii = (int*)p;  p += (size_t)(NI_ + 4) * 4;
    int* col_iu = (int*)p; p += (size_t)E_IU * 4;
    int* col_ub = (int*)p; p += (size_t)E_UB * 4;
    int* col_ii = (int*)p; p += (size_t)E_II * 4;
    // deg/bsum alias agg_ub region (CSR build completes before gathers write it)
    int* deg = (int*)agg_ub;
    int* bsum = deg + NU_;
    // d_out hosts agg_iu [NU][128] bf16 + xiB [NI][128] bf16; both dead before finals write.
    u16* agg_iu = (u16*)d_out;
    u16* xiB_bf = (u16*)((char*)d_out + (size_t)NU_ * 128 * 2);

    // weight slots (bf16, transposed [N][K])
    u16* wt_W1l_ub = wt + 0;        // [128][64]
    u16* wt_W1r_ub = wt + 8192;     // [128][128]
    u16* wt_W1l_iu = wt + 24576;    // [128][128]
    u16* wt_W1r_iu = wt + 40960;    // [128][64]
    u16* wt_W1l_ii = wt + 49152;    // [128][128]
    u16* wt_W1r_ii = wt + 65536;    // [128][128]
    u16* wt_W23l   = wt + 81920;    // 6 x [128][128]
    u16* wt_W23r   = wt + 180224;   // 6 x [128][128]
    u16* wt_Wf_u   = wt + 278528;   // [64][128]
    u16* wt_Wf_i   = wt + 286720;   // [64][128]

    // ---- CSR build ----
    build_csr(iu_src, iu_dst, E_IU, NU_, deg, bsum, rp_iu, col_iu, inv_iu, stream);
    build_csr(ub_src, ub_dst, E_UB, NI_, deg, bsum, rp_ub, col_ub, inv_ub, stream);
    build_csr(ii_src, ii_dst, E_II, NI_, deg, bsum, rp_ii, col_ii, inv_ii, stream);

    // ---- conversions ----
    cvt_kernel<<<(NI_ * 32 + 255) / 256, 256, 0, stream>>>(x_item, xi0_bf, NI_ * 32);
    wt_kernel<<<32, 256, 0, stream>>>(W1l_ub, wt_W1l_ub, 64, 128);
    wt_kernel<<<64, 256, 0, stream>>>(W1r_ub, wt_W1r_ub, 128, 128);
    wt_kernel<<<64, 256, 0, stream>>>(W1l_iu, wt_W1l_iu, 128, 128);
    wt_kernel<<<32, 256, 0, stream>>>(W1r_iu, wt_W1r_iu, 64, 128);
    wt_kernel<<<64, 256, 0, stream>>>(W1l_ii, wt_W1l_ii, 128, 128);
    wt_kernel<<<64, 256, 0, stream>>>(W1r_ii, wt_W1r_ii, 128, 128);
    wt_batch_kernel<<<384, 256, 0, stream>>>(W23l, wt_W23l, 6);
    wt_batch_kernel<<<384, 256, 0, stream>>>(W23r, wt_W23r, 6);
    wt_kernel<<<32, 256, 0, stream>>>(Wf_user, wt_Wf_u, 128, 64);
    wt_kernel<<<32, 256, 0, stream>>>(Wf_item, wt_Wf_i, 128, 64);

    const int gU = NU_ / 64;         // 3125 (exact)
    const int gI = (NI_ + 63) / 64;  // 1563 (guarded tail)
    const int gg128I = (NI_ * 32 + 255) / 256;
    const int gg128U = (NU_ * 32 + 255) / 256;
    const int gg64I  = (NI_ * 16 + 255) / 256;

    // ---- layer 1 ----
    gather_kernel<64, true><<<gg64I, 256, 0, stream>>>(x_user, rp_ub, col_ub, inv_ub, agg_ub, NI_);
    gather_kernel<128, false><<<gg128I, 256, 0, stream>>>(xi0_bf, rp_ii, col_ii, inv_ii, agg_ii, NI_);
    gather_kernel<128, false><<<gg128U, 256, 0, stream>>>(xi0_bf, rp_iu, col_iu, inv_iu, agg_iu, NU_);
    item_lds<64, 128, 128, true><<<gI, 256, 0, stream>>>(
        agg_ub, wt_W1l_ub, b1_ub, agg_ii, wt_W1l_ii, b1_ii,
        wt_W1r_ub, wt_W1r_ii, x_item, xiA_bf, NI_);
    user_lds<128, 64, true><<<gU, 256, 0, stream>>>(
        agg_iu, wt_W1l_iu, b1_iu, wt_W1r_iu, x_user, xu_bf, NU_);

    // ---- layers 2-3 ----
    for (int l = 0; l < 2; ++l) {
        const u16* cur = (l == 0) ? xiA_bf : xiB_bf;
        u16* nxt = (l == 0) ? xiB_bf : xiA_bf;
        const u16* wl_ub = wt_W23l + (size_t)(l * 3 + 0) * 16384;
        const u16* wr_ub = wt_W23r + (size_t)(l * 3 + 0) * 16384;
        const u16* wl_iu = wt_W23l + (size_t)(l * 3 + 1) * 16384;
        const u16* wr_iu = wt_W23r + (size_t)(l * 3 + 1) * 16384;
        const u16* wl_ii = wt_W23l + (size_t)(l * 3 + 2) * 16384;
        const u16* wr_ii = wt_W23r + (size_t)(l * 3 + 2) * 16384;
        const float* b_ub = b23 + (size_t)(l * 3 + 0) * 128;
        const float* b_iu = b23 + (size_t)(l * 3 + 1) * 128;
        const float* b_ii = b23 + (size_t)(l * 3 + 2) * 128;

        gather_kernel<128, false><<<gg128I, 256, 0, stream>>>(xu_bf, rp_ub, col_ub, inv_ub, agg_ub, NI_);
        gather_kernel<128, false><<<gg128I, 256, 0, stream>>>(cur, rp_ii, col_ii, inv_ii, agg_ii, NI_);
        gather_kernel<128, false><<<gg128U, 256, 0, stream>>>(cur, rp_iu, col_iu, inv_iu, agg_iu, NU_);
        item_lds<128, 128, 128, false><<<gI, 256, 0, stream>>>(
            agg_ub, wl_ub, b_ub, agg_ii, wl_ii, b_ii,
            wr_ub, wr_ii, cur, nxt, NI_);
        user_lds<128, 128, false><<<gU, 256, 0, stream>>>(
            agg_iu, wl_iu, b_iu, wr_iu, xu_bf, xu_bf, NU_);
    }

    // ---- finals (layer-3 item output = xiA_bf); overwrite agg_iu/xiB (dead) ----
    float* out = (float*)d_out;
    final_lds<<<gU, 256, 0, stream>>>(xu_bf, wt_Wf_u, bf_user, out, NU_);
    final_lds<<<gI, 256, 0, stream>>>(xiA_bf, wt_Wf_i, bf_item, out + (size_t)NU_ * 64, NI_);
}

// Round 11
// 1175.401 us; speedup vs baseline: 2.9248x; 1.0535x over previous
//
#include <hip/hip_runtime.h>

typedef unsigned short u16;
typedef __attribute__((ext_vector_type(4))) unsigned short u16x4;
typedef __attribute__((ext_vector_type(4))) short s16x4;
typedef __attribute__((ext_vector_type(8))) short s16x8;
typedef __attribute__((ext_vector_type(16))) float f32x16;

constexpr int NU_ = 200000, NI_ = 100000;
constexpr int E_UB = 1000000, E_IU = 1000000, E_II = 500000;
constexpr int SAP = 132;  // LDS row stride (bf16 elems): 264B => max 2-way bank aliasing

__device__ inline float bf2f(u16 v) { return __uint_as_float(((unsigned)v) << 16); }
__device__ inline u16 f2bf(float f) {
    unsigned u = __float_as_uint(f);
    return (u16)((u + 0x7FFFu + ((u >> 16) & 1u)) >> 16);  // RNE
}

// ================= CSR build =================
__global__ void deg_kernel(const int* __restrict__ dst, int E, int* __restrict__ deg) {
    int i = blockIdx.x * blockDim.x + threadIdx.x;
    if (i < E) atomicAdd(&deg[dst[i]], 1);
}

__global__ void scanA_kernel(const int* __restrict__ deg, int N, int* __restrict__ bsum) {
    __shared__ int s[256];
    int b = blockIdx.x, t = threadIdx.x;
    int base = b * 1024 + t * 4;
    int v = 0;
#pragma unroll
    for (int j = 0; j < 4; ++j) { int i = base + j; if (i < N) v += deg[i]; }
    s[t] = v; __syncthreads();
    for (int off = 1; off < 256; off <<= 1) {
        int x = (t >= off) ? s[t - off] : 0;
        __syncthreads();
        s[t] += x;
        __syncthreads();
    }
    if (t == 255) bsum[b] = s[255];
}

__global__ void scanB_kernel(int* __restrict__ bsum, int nb) {
    __shared__ int s[256];
    int t = threadIdx.x;
    int v = (t < nb) ? bsum[t] : 0;
    s[t] = v; __syncthreads();
    for (int off = 1; off < 256; off <<= 1) {
        int x = (t >= off) ? s[t - off] : 0;
        __syncthreads();
        s[t] += x;
        __syncthreads();
    }
    if (t < nb) bsum[t] = s[t] - v;  // exclusive
}

__global__ void scanC_kernel(const int* __restrict__ deg, int N, const int* __restrict__ boff,
                             int* __restrict__ rp, int E) {
    __shared__ int s[256];
    int b = blockIdx.x, t = threadIdx.x;
    int base = b * 1024 + t * 4;
    int d[4]; int v = 0;
#pragma unroll
    for (int j = 0; j < 4; ++j) { int i = base + j; d[j] = (i < N) ? deg[i] : 0; v += d[j]; }
    s[t] = v; __syncthreads();
    for (int off = 1; off < 256; off <<= 1) {
        int x = (t >= off) ? s[t - off] : 0;
        __syncthreads();
        s[t] += x;
        __syncthreads();
    }
    int ex = boff[b] + s[t] - v;
#pragma unroll
    for (int j = 0; j < 4; ++j) { int i = base + j; if (i < N) rp[i] = ex; ex += d[j]; }
    if (b == 0 && t == 0) rp[N] = E;
}

__global__ void inv_from_deg(const int* __restrict__ deg, float* __restrict__ inv, int N) {
    int i = blockIdx.x * blockDim.x + threadIdx.x;
    if (i < N) inv[i] = 1.0f / fmaxf((float)deg[i], 1.0f);
}

__global__ void fill_kernel(const int* __restrict__ src, const int* __restrict__ dst, int E,
                            const int* __restrict__ rp, int* __restrict__ cur, int* __restrict__ col) {
    int e = blockIdx.x * blockDim.x + threadIdx.x;
    if (e < E) {
        int d = dst[e];
        int p = atomicAdd(&cur[d], 1);
        col[rp[d] + p] = src[e];
    }
}

// ================= conversions =================
__global__ void cvt_kernel(const float* __restrict__ in, u16* __restrict__ out, int n4) {
    int i = blockIdx.x * 256 + threadIdx.x;
    if (i < n4) {
        float4 v = reinterpret_cast<const float4*>(in)[i];
        u16x4 o = { f2bf(v.x), f2bf(v.y), f2bf(v.z), f2bf(v.w) };
        reinterpret_cast<u16x4*>(out)[i] = o;
    }
}

// src [K][N] f32 -> dst [N][K] bf16 (transposed)
__global__ void wt_kernel(const float* __restrict__ src, u16* __restrict__ dst, int K, int N) {
    int i = blockIdx.x * 256 + threadIdx.x;
    if (i < K * N) { int k = i / N, n = i - k * N; dst[n * K + k] = f2bf(src[i]); }
}

__global__ void wt_batch_kernel(const float* __restrict__ src, u16* __restrict__ dst, int nmat) {
    int i = blockIdx.x * 256 + threadIdx.x;
    if (i < nmat * 16384) {
        int m = i >> 14, rem = i & 16383;
        int k = rem >> 7, n = rem & 127;
        dst[(m << 14) + (n << 7) + k] = f2bf(src[i]);
    }
}

// dst[n][k] = bf16(A[k][n] + B[k][n])  (128x128)
__global__ void wt_sum_kernel(const float* __restrict__ A, const float* __restrict__ B,
                              u16* __restrict__ dst) {
    int i = blockIdx.x * 256 + threadIdx.x;
    if (i < 16384) { int k = i >> 7, n = i & 127; dst[n * 128 + k] = f2bf(A[i] + B[i]); }
}

// ================= standalone gather (unroll x4) =================
template<int K, bool F32SRC>
__global__ __launch_bounds__(256, 8) void gather_kernel(
    const void* __restrict__ xsrc, const int* __restrict__ rp, const int* __restrict__ col,
    const float* __restrict__ inv, u16* __restrict__ agg, int N) {
    constexpr int LPR = K / 4;
    long long gt = (long long)blockIdx.x * 256 + threadIdx.x;
    int node = (int)(gt / LPR);
    int lane = (int)(gt % LPR);
    if (node >= N) return;
    float a0 = 0.f, a1 = 0.f, a2 = 0.f, a3 = 0.f;
    int s = rp[node], e = rp[node + 1];
    for (; s + 4 <= e; s += 4) {
        int c0 = col[s], c1 = col[s + 1], c2 = col[s + 2], c3 = col[s + 3];
        if constexpr (F32SRC) {
            float4 v0 = reinterpret_cast<const float4*>(xsrc)[(size_t)c0 * LPR + lane];
            float4 v1 = reinterpret_cast<const float4*>(xsrc)[(size_t)c1 * LPR + lane];
            float4 v2 = reinterpret_cast<const float4*>(xsrc)[(size_t)c2 * LPR + lane];
            float4 v3 = reinterpret_cast<const float4*>(xsrc)[(size_t)c3 * LPR + lane];
            a0 += (v0.x + v1.x) + (v2.x + v3.x);
            a1 += (v0.y + v1.y) + (v2.y + v3.y);
            a2 += (v0.z + v1.z) + (v2.z + v3.z);
            a3 += (v0.w + v1.w) + (v2.w + v3.w);
        } else {
            u16x4 v0 = reinterpret_cast<const u16x4*>(xsrc)[(size_t)c0 * LPR + lane];
            u16x4 v1 = reinterpret_cast<const u16x4*>(xsrc)[(size_t)c1 * LPR + lane];
            u16x4 v2 = reinterpret_cast<const u16x4*>(xsrc)[(size_t)c2 * LPR + lane];
            u16x4 v3 = reinterpret_cast<const u16x4*>(xsrc)[(size_t)c3 * LPR + lane];
            a0 += (bf2f(v0.x) + bf2f(v1.x)) + (bf2f(v2.x) + bf2f(v3.x));
            a1 += (bf2f(v0.y) + bf2f(v1.y)) + (bf2f(v2.y) + bf2f(v3.y));
            a2 += (bf2f(v0.z) + bf2f(v1.z)) + (bf2f(v2.z) + bf2f(v3.z));
            a3 += (bf2f(v0.w) + bf2f(v1.w)) + (bf2f(v2.w) + bf2f(v3.w));
        }
    }
    for (; s < e; ++s) {
        int c = col[s];
        if constexpr (F32SRC) {
            float4 v = reinterpret_cast<const float4*>(xsrc)[(size_t)c * LPR + lane];
            a0 += v.x; a1 += v.y; a2 += v.z; a3 += v.w;
        } else {
            u16x4 v = reinterpret_cast<const u16x4*>(xsrc)[(size_t)c * LPR + lane];
            a0 += bf2f(v.x); a1 += bf2f(v.y); a2 += bf2f(v.z); a3 += bf2f(v.w);
        }
    }
    float sc = inv[node];
    u16x4 o = { f2bf(a0 * sc), f2bf(a1 * sc), f2bf(a2 * sc), f2bf(a3 * sc) };
    reinterpret_cast<u16x4*>(agg)[(size_t)node * LPR + lane] = o;
}

// ================= MFMA update: B from LDS, A from global =================
// Block 256 = 4 waves, 64 rows. mfma_f32_32x32x16_bf16.
// C/D: col=lane&31, row=(r&3)+8*(r>>2)+4*(lane>>5)  [verified rounds 7-10]

// stage transposed weight [NCOL][K] bf16 -> sW [NCOL][SAP]
template<int K, int NCOL>
__device__ inline void stage_w(const u16* __restrict__ Wt, u16* sW) {
    constexpr int CH = K / 4;
    constexpr int TOT = NCOL * CH;
#pragma unroll
    for (int i = threadIdx.x; i < TOT; i += 256) {
        int n = i / CH, c = i - n * CH;
        *reinterpret_cast<u16x4*>(sW + n * SAP + c * 4) =
            *reinterpret_cast<const u16x4*>(Wt + (size_t)n * K + c * 4);
    }
}

template<int K, int NCOL, int TPW, bool A_F32>
__device__ inline void gemm_pass(const void* __restrict__ A, int rowBase, int N,
                                 const u16* sW, f32x16* acc) {
    constexpr int NB_C = NCOL / 32;
    const int lane = threadIdx.x & 63, wid = threadIdx.x >> 6;
    const int lm = lane & 31, hi = lane >> 5;
    const int id0 = wid * TPW;
    const int rb = id0 / NB_C;
    const int arow = min(rowBase + rb * 32 + lm, N - 1);  // tail clamp (stores guarded)
#pragma unroll 4
    for (int kc = 0; kc < K; kc += 16) {
        s16x8 a;
        if constexpr (A_F32) {
            const float* pa = (const float*)A + (size_t)arow * K + kc + 4 * hi;
            float4 f0 = *reinterpret_cast<const float4*>(pa);
            float4 f1 = *reinterpret_cast<const float4*>(pa + 8);
            a = s16x8{ (short)f2bf(f0.x), (short)f2bf(f0.y), (short)f2bf(f0.z), (short)f2bf(f0.w),
                       (short)f2bf(f1.x), (short)f2bf(f1.y), (short)f2bf(f1.z), (short)f2bf(f1.w) };
        } else {
            const u16* pa = (const u16*)A + (size_t)arow * K + kc + 4 * hi;
            s16x4 q0 = *reinterpret_cast<const s16x4*>(pa);
            s16x4 q1 = *reinterpret_cast<const s16x4*>(pa + 8);
            a = s16x8{ q0.x, q0.y, q0.z, q0.w, q1.x, q1.y, q1.z, q1.w };
        }
#pragma unroll
        for (int t = 0; t < TPW; ++t) {
            const int cb = (id0 + t) % NB_C;
            const u16* pb = sW + (cb * 32 + lm) * SAP + kc + 4 * hi;
            s16x4 r0 = *reinterpret_cast<const s16x4*>(pb);
            s16x4 r1 = *reinterpret_cast<const s16x4*>(pb + 8);
            s16x8 b = { r0.x, r0.y, r0.z, r0.w, r1.x, r1.y, r1.z, r1.w };
            acc[t] = __builtin_amdgcn_mfma_f32_32x32x16_bf16(a, b, acc[t], 0, 0, 0);
        }
    }
}

// item: out = relu(0.5*(aggA@WlA + aggB@WlB + self@Wsum + bA + bB)); out != inputs
template<int KA, int KB, int KS>
__global__ __launch_bounds__(256, 4) void item_upd(
    const u16* __restrict__ aggA, const u16* __restrict__ WlAT, const float* __restrict__ bA,
    const u16* __restrict__ aggB, const u16* __restrict__ WlBT, const float* __restrict__ bB,
    const u16* __restrict__ WsumT, const u16* __restrict__ xself,
    u16* __restrict__ out, int N) {
    __shared__ u16 sW[128 * SAP];
    f32x16 acc[2];
    const int lane = threadIdx.x & 63, wid = threadIdx.x >> 6;
    const int lm = lane & 31, hi = lane >> 5;
    const int id0 = wid * 2;
    const int rb = id0 / 4;
    const int rowBase = blockIdx.x * 64;
#pragma unroll
    for (int t = 0; t < 2; ++t) {
        int cv = ((id0 + t) % 4) * 32 + lm;
        float bv = bA[cv] + bB[cv];
#pragma unroll
        for (int i = 0; i < 16; ++i) acc[t][i] = bv;
    }
    stage_w<KA, 128>(WlAT, sW);
    __syncthreads();
    gemm_pass<KA, 128, 2, false>(aggA, rowBase, N, sW, acc);
    __syncthreads();
    stage_w<KB, 128>(WlBT, sW);
    __syncthreads();
    gemm_pass<KB, 128, 2, false>(aggB, rowBase, N, sW, acc);
    __syncthreads();
    stage_w<KS, 128>(WsumT, sW);
    __syncthreads();
    gemm_pass<KS, 128, 2, false>(xself, rowBase, N, sW, acc);
#pragma unroll
    for (int t = 0; t < 2; ++t) {
        int colv = ((id0 + t) % 4) * 32 + lm;
#pragma unroll
        for (int r = 0; r < 16; ++r) {
            int row = rowBase + rb * 32 + (r & 3) + 8 * (r >> 2) + 4 * hi;
            if (row < N) out[(size_t)row * 128 + colv] = f2bf(fmaxf(0.5f * acc[t][r], 0.f));
        }
    }
}

// user: out = relu(agg@Wl + self@Wr + b); out may alias xself (barrier before writes)
template<int KA, int KS, bool SELF_F32>
__global__ __launch_bounds__(256, 4) void user_upd(
    const u16* __restrict__ agg, const u16* __restrict__ WlT, const float* __restrict__ bias,
    const u16* __restrict__ WrT, const void* xself, u16* out, int N) {
    __shared__ u16 sW[128 * SAP];
    f32x16 acc[2];
    const int lane = threadIdx.x & 63, wid = threadIdx.x >> 6;
    const int lm = lane & 31, hi = lane >> 5;
    const int id0 = wid * 2;
    const int rb = id0 / 4;
    const int rowBase = blockIdx.x * 64;
#pragma unroll
    for (int t = 0; t < 2; ++t) {
        float bv = bias[((id0 + t) % 4) * 32 + lm];
#pragma unroll
        for (int i = 0; i < 16; ++i) acc[t][i] = bv;
    }
    stage_w<KA, 128>(WlT, sW);
    __syncthreads();
    gemm_pass<KA, 128, 2, false>(agg, rowBase, N, sW, acc);
    __syncthreads();
    stage_w<KS, 128>(WrT, sW);
    __syncthreads();
    gemm_pass<KS, 128, 2, SELF_F32>(xself, rowBase, N, sW, acc);
    // in-place safety: every wave's global reads of self rows complete before any write
    __syncthreads();
#pragma unroll
    for (int t = 0; t < 2; ++t) {
        int colv = ((id0 + t) % 4) * 32 + lm;
#pragma unroll
        for (int r = 0; r < 16; ++r) {
            int row = rowBase + rb * 32 + (r & 3) + 8 * (r >> 2) + 4 * hi;
            if (row < N) out[(size_t)row * 128 + colv] = f2bf(fmaxf(acc[t][r], 0.f));
        }
    }
}

// final 128->64 linear, f32 out (out-of-place)
__global__ __launch_bounds__(256, 4) void final_upd(
    const u16* __restrict__ x, const u16* __restrict__ WfT, const float* __restrict__ bias,
    float* __restrict__ out, int N) {
    __shared__ u16 sW[64 * SAP];
    f32x16 acc[1];
    const int lane = threadIdx.x & 63, wid = threadIdx.x >> 6;
    const int lm = lane & 31, hi = lane >> 5;
    const int rb = wid / 2;
    const int rowBase = blockIdx.x * 64;
    {
        float bv = bias[(wid % 2) * 32 + lm];
#pragma unroll
        for (int i = 0; i < 16; ++i) acc[0][i] = bv;
    }
    stage_w<128, 64>(WfT, sW);
    __syncthreads();
    gemm_pass<128, 64, 1, false>(x, rowBase, N, sW, acc);
    {
        int colv = (wid % 2) * 32 + lm;
#pragma unroll
        for (int r = 0; r < 16; ++r) {
            int row = rowBase + rb * 32 + (r & 3) + 8 * (r >> 2) + 4 * hi;
            if (row < N) out[(size_t)row * 64 + colv] = acc[0][r];
        }
    }
}

// ================= host =================
static void build_csr(const int* src, const int* dst, int E, int N,
                      int* deg, int* bsum, int* rp, int* col, float* inv, hipStream_t stream) {
    const int B = 256;
    hipMemsetAsync(deg, 0, (size_t)N * sizeof(int), stream);
    deg_kernel<<<(E + B - 1) / B, B, 0, stream>>>(dst, E, deg);
    int nb = (N + 1023) / 1024;
    scanA_kernel<<<nb, B, 0, stream>>>(deg, N, bsum);
    scanB_kernel<<<1, B, 0, stream>>>(bsum, nb);
    scanC_kernel<<<nb, B, 0, stream>>>(deg, N, bsum, rp, E);
    inv_from_deg<<<(N + B - 1) / B, B, 0, stream>>>(deg, inv, N);
    hipMemsetAsync(deg, 0, (size_t)N * sizeof(int), stream);
    fill_kernel<<<(E + B - 1) / B, B, 0, stream>>>(src, dst, E, rp, deg, col);
}

extern "C" void kernel_launch(void* const* d_in, const int* in_sizes, int n_in,
                              void* d_out, int out_size, void* d_ws, size_t ws_size,
                              hipStream_t stream) {
    const float* x_user = (const float*)d_in[0];
    const float* x_item = (const float*)d_in[1];
    const int* ub_src = (const int*)d_in[2];
    const int* ub_dst = (const int*)d_in[3];
    const int* iu_src = (const int*)d_in[4];
    const int* iu_dst = (const int*)d_in[5];
    const int* ii_src = (const int*)d_in[6];
    const int* ii_dst = (const int*)d_in[7];
    const float* W1l_ub = (const float*)d_in[8];
    const float* W1r_ub = (const float*)d_in[9];
    const float* b1_ub = (const float*)d_in[10];
    const float* W1l_iu = (const float*)d_in[11];
    const float* W1r_iu = (const float*)d_in[12];
    const float* b1_iu = (const float*)d_in[13];
    const float* W1l_ii = (const float*)d_in[14];
    const float* W1r_ii = (const float*)d_in[15];
    const float* b1_ii = (const float*)d_in[16];
    const float* W23l = (const float*)d_in[17];
    const float* W23r = (const float*)d_in[18];
    const float* b23 = (const float*)d_in[19];
    const float* Wf_user = (const float*)d_in[20];
    const float* bf_user = (const float*)d_in[21];
    const float* Wf_item = (const float*)d_in[22];
    const float* bf_item = (const float*)d_in[23];

    // ---- workspace (~168 MB + optional 25.6 MB) ----
    char* p = (char*)d_ws;
    u16* xu_bf  = (u16*)p;  p += (size_t)NU_ * 128 * 2;   // 51.2 MB
    u16* xiA_bf = (u16*)p;  p += (size_t)NI_ * 128 * 2;   // 25.6
    u16* xi0_bf = (u16*)p;  p += (size_t)NI_ * 128 * 2;   // 25.6 (x_item bf16)
    u16* agg_ub = (u16*)p;  p += (size_t)NI_ * 128 * 2;   // 25.6 (deg/bsum alias pre-gather)
    u16* agg_ii = (u16*)p;  p += (size_t)NI_ * 128 * 2;   // 25.6
    u16* wt     = (u16*)p;  p += (size_t)344064 * 2;      // 0.69 (incl. 3 wsum slots)
    float* inv_iu = (float*)p; p += (size_t)NU_ * 4;
    float* inv_ub = (float*)p; p += (size_t)NI_ * 4;
    float* inv_ii = (float*)p; p += (size_t)NI_ * 4;
    int* rp_iu = (int*)p;  p += (size_t)(NU_ + 4) * 4;
    int* rp_ub = (int*)p;  p += (size_t)(NI_ + 4) * 4;
    int* rp_ii = (int*)p;  p += (size_t)(NI_ + 4) * 4;
    int* col_iu = (int*)p; p += (size_t)E_IU * 4;
    int* col_ub = (int*)p; p += (size_t)E_UB * 4;
    int* col_ii = (int*)p; p += (size_t)E_II * 4;
    // optional bf16 copy of x_user (used only if workspace is big enough)
    u16* xu0b = nullptr;
    {
        size_t used = (size_t)(p - (char*)d_ws);
        if (used + (size_t)NU_ * 64 * 2 <= ws_size) { xu0b = (u16*)p; }
    }
    // deg/bsum alias agg_ub region (CSR build completes before gathers write it)
    int* deg = (int*)agg_ub;
    int* bsum = deg + NU_;
    // d_out hosts agg_iu [NU][128] bf16 + xiB [NI][128] bf16; both dead before finals write.
    u16* agg_iu = (u16*)d_out;
    u16* xiB_bf = (u16*)((char*)d_out + (size_t)NU_ * 128 * 2);

    // weight slots (bf16, transposed [N][K])
    u16* wt_W1l_ub = wt + 0;        // [128][64]
    u16* wt_W1l_iu = wt + 24576;    // [128][128]
    u16* wt_W1r_iu = wt + 40960;    // [128][64]
    u16* wt_W1l_ii = wt + 49152;    // [128][128]
    u16* wt_W23l   = wt + 81920;    // 6 x [128][128]
    u16* wt_W23r   = wt + 180224;   // 6 x [128][128]
    u16* wt_Wf_u   = wt + 278528;   // [64][128]
    u16* wt_Wf_i   = wt + 286720;   // [64][128]
    u16* wt_Wsum   = wt + 294912;   // 3 x [128][128] presummed self weights (item)

    // ---- CSR build ----
    build_csr(iu_src, iu_dst, E_IU, NU_, deg, bsum, rp_iu, col_iu, inv_iu, stream);
    build_csr(ub_src, ub_dst, E_UB, NI_, deg, bsum, rp_ub, col_ub, inv_ub, stream);
    build_csr(ii_src, ii_dst, E_II, NI_, deg, bsum, rp_ii, col_ii, inv_ii, stream);

    // ---- conversions ----
    cvt_kernel<<<(NI_ * 32 + 255) / 256, 256, 0, stream>>>(x_item, xi0_bf, NI_ * 32);
    if (xu0b) cvt_kernel<<<(NU_ * 16 + 255) / 256, 256, 0, stream>>>(x_user, xu0b, NU_ * 16);
    wt_kernel<<<32, 256, 0, stream>>>(W1l_ub, wt_W1l_ub, 64, 128);
    wt_kernel<<<64, 256, 0, stream>>>(W1l_iu, wt_W1l_iu, 128, 128);
    wt_kernel<<<32, 256, 0, stream>>>(W1r_iu, wt_W1r_iu, 64, 128);
    wt_kernel<<<64, 256, 0, stream>>>(W1l_ii, wt_W1l_ii, 128, 128);
    wt_batch_kernel<<<384, 256, 0, stream>>>(W23l, wt_W23l, 6);
    wt_batch_kernel<<<384, 256, 0, stream>>>(W23r, wt_W23r, 6);
    wt_kernel<<<32, 256, 0, stream>>>(Wf_user, wt_Wf_u, 128, 64);
    wt_kernel<<<32, 256, 0, stream>>>(Wf_item, wt_Wf_i, 128, 64);
    // presummed item self weights: layer1 = W1r_ub + W1r_ii; layers 2-3 = W23r[l,0] + W23r[l,2]
    wt_sum_kernel<<<64, 256, 0, stream>>>(W1r_ub, W1r_ii, wt_Wsum + 0);
    wt_sum_kernel<<<64, 256, 0, stream>>>(W23r + 0 * 16384, W23r + 2 * 16384, wt_Wsum + 16384);
    wt_sum_kernel<<<64, 256, 0, stream>>>(W23r + 3 * 16384, W23r + 5 * 16384, wt_Wsum + 32768);

    const int gU = NU_ / 64;         // 3125 (exact)
    const int gI = (NI_ + 63) / 64;  // 1563 (tail clamped/guarded)
    const int gg128I = (NI_ * 32 + 255) / 256;
    const int gg128U = (NU_ * 32 + 255) / 256;
    const int gg64I  = (NI_ * 16 + 255) / 256;

    // ---- layer 1 ----
    if (xu0b)
        gather_kernel<64, false><<<gg64I, 256, 0, stream>>>(xu0b, rp_ub, col_ub, inv_ub, agg_ub, NI_);
    else
        gather_kernel<64, true><<<gg64I, 256, 0, stream>>>(x_user, rp_ub, col_ub, inv_ub, agg_ub, NI_);
    gather_kernel<128, false><<<gg128I, 256, 0, stream>>>(xi0_bf, rp_ii, col_ii, inv_ii, agg_ii, NI_);
    gather_kernel<128, false><<<gg128U, 256, 0, stream>>>(xi0_bf, rp_iu, col_iu, inv_iu, agg_iu, NU_);
    item_upd<64, 128, 128><<<gI, 256, 0, stream>>>(
        agg_ub, wt_W1l_ub, b1_ub, agg_ii, wt_W1l_ii, b1_ii,
        wt_Wsum + 0, xi0_bf, xiA_bf, NI_);
    if (xu0b)
        user_upd<128, 64, false><<<gU, 256, 0, stream>>>(
            agg_iu, wt_W1l_iu, b1_iu, wt_W1r_iu, xu0b, xu_bf, NU_);
    else
        user_upd<128, 64, true><<<gU, 256, 0, stream>>>(
            agg_iu, wt_W1l_iu, b1_iu, wt_W1r_iu, x_user, xu_bf, NU_);

    // ---- layers 2-3 ----
    for (int l = 0; l < 2; ++l) {
        const u16* cur = (l == 0) ? xiA_bf : xiB_bf;
        u16* nxt = (l == 0) ? xiB_bf : xiA_bf;
        const u16* wl_ub = wt_W23l + (size_t)(l * 3 + 0) * 16384;
        const u16* wl_iu = wt_W23l + (size_t)(l * 3 + 1) * 16384;
        const u16* wr_iu = wt_W23r + (size_t)(l * 3 + 1) * 16384;
        const u16* wl_ii = wt_W23l + (size_t)(l * 3 + 2) * 16384;
        const u16* wsum = wt_Wsum + (size_t)(l + 1) * 16384;
        const float* b_ub = b23 + (size_t)(l * 3 + 0) * 128;
        const float* b_iu = b23 + (size_t)(l * 3 + 1) * 128;
        const float* b_ii = b23 + (size_t)(l * 3 + 2) * 128;

        gather_kernel<128, false><<<gg128I, 256, 0, stream>>>(xu_bf, rp_ub, col_ub, inv_ub, agg_ub, NI_);
        gather_kernel<128, false><<<gg128I, 256, 0, stream>>>(cur, rp_ii, col_ii, inv_ii, agg_ii, NI_);
        gather_kernel<128, false><<<gg128U, 256, 0, stream>>>(cur, rp_iu, col_iu, inv_iu, agg_iu, NU_);
        item_upd<128, 128, 128><<<gI, 256, 0, stream>>>(
            agg_ub, wl_ub, b_ub, agg_ii, wl_ii, b_ii,
            wsum, cur, nxt, NI_);
        user_upd<128, 128, false><<<gU, 256, 0, stream>>>(
            agg_iu, wl_iu, b_iu, wr_iu, xu_bf, xu_bf, NU_);
    }

    // ---- finals (layer-3 item output = xiA_bf); overwrite agg_iu/xiB (dead) ----
    float* out = (float*)d_out;
    final_upd<<<gU, 256, 0, stream>>>(xu_bf, wt_Wf_u, bf_user, out, NU_);
    final_upd<<<gI, 256, 0, stream>>>(xiA_bf, wt_Wf_i, bf_item, out + (size_t)NU_ * 64, NI_);
}

// Round 12
// 1116.966 us; speedup vs baseline: 3.0778x; 1.0523x over previous
//
#include <hip/hip_runtime.h>

typedef unsigned short u16;
typedef __attribute__((ext_vector_type(4))) unsigned short u16x4;
typedef __attribute__((ext_vector_type(8))) unsigned short u16x8;
typedef __attribute__((ext_vector_type(4))) short s16x4;
typedef __attribute__((ext_vector_type(8))) short s16x8;
typedef __attribute__((ext_vector_type(16))) float f32x16;

constexpr int NU_ = 200000, NI_ = 100000;
constexpr int E_UB = 1000000, E_IU = 1000000, E_II = 500000;
constexpr int SAP = 132;  // LDS row stride (bf16 elems): 264B => max 2-way bank aliasing

__device__ inline float bf2f(u16 v) { return __uint_as_float(((unsigned)v) << 16); }
__device__ inline u16 f2bf(float f) {
    unsigned u = __float_as_uint(f);
    return (u16)((u + 0x7FFFu + ((u >> 16) & 1u)) >> 16);  // RNE
}

// ================= CSR build =================
__global__ void deg_kernel(const int* __restrict__ dst, int E, int* __restrict__ deg) {
    int i = blockIdx.x * blockDim.x + threadIdx.x;
    if (i < E) atomicAdd(&deg[dst[i]], 1);
}

__global__ void scanA_kernel(const int* __restrict__ deg, int N, int* __restrict__ bsum) {
    __shared__ int s[256];
    int b = blockIdx.x, t = threadIdx.x;
    int base = b * 1024 + t * 4;
    int v = 0;
#pragma unroll
    for (int j = 0; j < 4; ++j) { int i = base + j; if (i < N) v += deg[i]; }
    s[t] = v; __syncthreads();
    for (int off = 1; off < 256; off <<= 1) {
        int x = (t >= off) ? s[t - off] : 0;
        __syncthreads();
        s[t] += x;
        __syncthreads();
    }
    if (t == 255) bsum[b] = s[255];
}

__global__ void scanB_kernel(int* __restrict__ bsum, int nb) {
    __shared__ int s[256];
    int t = threadIdx.x;
    int v = (t < nb) ? bsum[t] : 0;
    s[t] = v; __syncthreads();
    for (int off = 1; off < 256; off <<= 1) {
        int x = (t >= off) ? s[t - off] : 0;
        __syncthreads();
        s[t] += x;
        __syncthreads();
    }
    if (t < nb) bsum[t] = s[t] - v;  // exclusive
}

__global__ void scanC_kernel(const int* __restrict__ deg, int N, const int* __restrict__ boff,
                             int* __restrict__ rp, int E) {
    __shared__ int s[256];
    int b = blockIdx.x, t = threadIdx.x;
    int base = b * 1024 + t * 4;
    int d[4]; int v = 0;
#pragma unroll
    for (int j = 0; j < 4; ++j) { int i = base + j; d[j] = (i < N) ? deg[i] : 0; v += d[j]; }
    s[t] = v; __syncthreads();
    for (int off = 1; off < 256; off <<= 1) {
        int x = (t >= off) ? s[t - off] : 0;
        __syncthreads();
        s[t] += x;
        __syncthreads();
    }
    int ex = boff[b] + s[t] - v;
#pragma unroll
    for (int j = 0; j < 4; ++j) { int i = base + j; if (i < N) rp[i] = ex; ex += d[j]; }
    if (b == 0 && t == 0) rp[N] = E;
}

__global__ void inv_from_deg(const int* __restrict__ deg, float* __restrict__ inv, int N) {
    int i = blockIdx.x * blockDim.x + threadIdx.x;
    if (i < N) inv[i] = 1.0f / fmaxf((float)deg[i], 1.0f);
}

__global__ void fill_kernel(const int* __restrict__ src, const int* __restrict__ dst, int E,
                            const int* __restrict__ rp, int* __restrict__ cur, int* __restrict__ col) {
    int e = blockIdx.x * blockDim.x + threadIdx.x;
    if (e < E) {
        int d = dst[e];
        int p = atomicAdd(&cur[d], 1);
        col[rp[d] + p] = src[e];
    }
}

// ================= conversions =================
__global__ void cvt_kernel(const float* __restrict__ in, u16* __restrict__ out, int n4) {
    int i = blockIdx.x * 256 + threadIdx.x;
    if (i < n4) {
        float4 v = reinterpret_cast<const float4*>(in)[i];
        u16x4 o = { f2bf(v.x), f2bf(v.y), f2bf(v.z), f2bf(v.w) };
        reinterpret_cast<u16x4*>(out)[i] = o;
    }
}

// src [K][N] f32 -> dst [N][K] bf16 (transposed)
__global__ void wt_kernel(const float* __restrict__ src, u16* __restrict__ dst, int K, int N) {
    int i = blockIdx.x * 256 + threadIdx.x;
    if (i < K * N) { int k = i / N, n = i - k * N; dst[n * K + k] = f2bf(src[i]); }
}

__global__ void wt_batch_kernel(const float* __restrict__ src, u16* __restrict__ dst, int nmat) {
    int i = blockIdx.x * 256 + threadIdx.x;
    if (i < nmat * 16384) {
        int m = i >> 14, rem = i & 16383;
        int k = rem >> 7, n = rem & 127;
        dst[(m << 14) + (n << 7) + k] = f2bf(src[i]);
    }
}

// dst[n][k] = bf16(A[k][n] + B[k][n])  (128x128)
__global__ void wt_sum_kernel(const float* __restrict__ A, const float* __restrict__ B,
                              u16* __restrict__ dst) {
    int i = blockIdx.x * 256 + threadIdx.x;
    if (i < 16384) { int k = i >> 7, n = i & 127; dst[n * 128 + k] = f2bf(A[i] + B[i]); }
}

// ================= standalone gather: 16B loads per lane =================
// bf16 src: LPR = K/8 lanes/row (u16x8 = 16B); f32 src: LPR = K/4 (float4 = 16B).
template<int K, bool F32SRC>
__global__ __launch_bounds__(256, 8) void gather_kernel(
    const void* __restrict__ xsrc, const int* __restrict__ rp, const int* __restrict__ col,
    const float* __restrict__ inv, u16* __restrict__ agg, int N) {
    constexpr int LPR = F32SRC ? (K / 4) : (K / 8);
    long long gt = (long long)blockIdx.x * 256 + threadIdx.x;
    int node = (int)(gt / LPR);
    int lane = (int)(gt % LPR);
    if (node >= N) return;
    int s = rp[node], e = rp[node + 1];
    float sc = inv[node];
    if constexpr (F32SRC) {
        float a0 = 0.f, a1 = 0.f, a2 = 0.f, a3 = 0.f;
        for (; s + 4 <= e; s += 4) {
            int c0 = col[s], c1 = col[s + 1], c2 = col[s + 2], c3 = col[s + 3];
            float4 v0 = reinterpret_cast<const float4*>(xsrc)[(size_t)c0 * LPR + lane];
            float4 v1 = reinterpret_cast<const float4*>(xsrc)[(size_t)c1 * LPR + lane];
            float4 v2 = reinterpret_cast<const float4*>(xsrc)[(size_t)c2 * LPR + lane];
            float4 v3 = reinterpret_cast<const float4*>(xsrc)[(size_t)c3 * LPR + lane];
            a0 += (v0.x + v1.x) + (v2.x + v3.x);
            a1 += (v0.y + v1.y) + (v2.y + v3.y);
            a2 += (v0.z + v1.z) + (v2.z + v3.z);
            a3 += (v0.w + v1.w) + (v2.w + v3.w);
        }
        for (; s < e; ++s) {
            int c = col[s];
            float4 v = reinterpret_cast<const float4*>(xsrc)[(size_t)c * LPR + lane];
            a0 += v.x; a1 += v.y; a2 += v.z; a3 += v.w;
        }
        u16x4 o = { f2bf(a0 * sc), f2bf(a1 * sc), f2bf(a2 * sc), f2bf(a3 * sc) };
        reinterpret_cast<u16x4*>(agg)[(size_t)node * LPR + lane] = o;
    } else {
        float a[8];
#pragma unroll
        for (int j = 0; j < 8; ++j) a[j] = 0.f;
        for (; s + 4 <= e; s += 4) {
            int c0 = col[s], c1 = col[s + 1], c2 = col[s + 2], c3 = col[s + 3];
            u16x8 v0 = reinterpret_cast<const u16x8*>(xsrc)[(size_t)c0 * LPR + lane];
            u16x8 v1 = reinterpret_cast<const u16x8*>(xsrc)[(size_t)c1 * LPR + lane];
            u16x8 v2 = reinterpret_cast<const u16x8*>(xsrc)[(size_t)c2 * LPR + lane];
            u16x8 v3 = reinterpret_cast<const u16x8*>(xsrc)[(size_t)c3 * LPR + lane];
#pragma unroll
            for (int j = 0; j < 8; ++j)
                a[j] += (bf2f(v0[j]) + bf2f(v1[j])) + (bf2f(v2[j]) + bf2f(v3[j]));
        }
        for (; s < e; ++s) {
            int c = col[s];
            u16x8 v = reinterpret_cast<const u16x8*>(xsrc)[(size_t)c * LPR + lane];
#pragma unroll
            for (int j = 0; j < 8; ++j) a[j] += bf2f(v[j]);
        }
        u16x8 o;
#pragma unroll
        for (int j = 0; j < 8; ++j) o[j] = f2bf(a[j] * sc);
        reinterpret_cast<u16x8*>(agg)[(size_t)node * LPR + lane] = o;
    }
}

// ================= MFMA update: B from LDS, A from global (round 11, verified) =================
// Block 256 = 4 waves, 64 rows. mfma_f32_32x32x16_bf16.
// C/D: col=lane&31, row=(r&3)+8*(r>>2)+4*(lane>>5)

template<int K, int NCOL>
__device__ inline void stage_w(const u16* __restrict__ Wt, u16* sW) {
    constexpr int CH = K / 4;
    constexpr int TOT = NCOL * CH;
#pragma unroll
    for (int i = threadIdx.x; i < TOT; i += 256) {
        int n = i / CH, c = i - n * CH;
        *reinterpret_cast<u16x4*>(sW + n * SAP + c * 4) =
            *reinterpret_cast<const u16x4*>(Wt + (size_t)n * K + c * 4);
    }
}

template<int K, int NCOL, int TPW, bool A_F32>
__device__ inline void gemm_pass(const void* __restrict__ A, int rowBase, int N,
                                 const u16* sW, f32x16* acc) {
    constexpr int NB_C = NCOL / 32;
    const int lane = threadIdx.x & 63, wid = threadIdx.x >> 6;
    const int lm = lane & 31, hi = lane >> 5;
    const int id0 = wid * TPW;
    const int rb = id0 / NB_C;
    const int arow = min(rowBase + rb * 32 + lm, N - 1);  // tail clamp (stores guarded)
#pragma unroll 4
    for (int kc = 0; kc < K; kc += 16) {
        s16x8 a;
        if constexpr (A_F32) {
            const float* pa = (const float*)A + (size_t)arow * K + kc + 4 * hi;
            float4 f0 = *reinterpret_cast<const float4*>(pa);
            float4 f1 = *reinterpret_cast<const float4*>(pa + 8);
            a = s16x8{ (short)f2bf(f0.x), (short)f2bf(f0.y), (short)f2bf(f0.z), (short)f2bf(f0.w),
                       (short)f2bf(f1.x), (short)f2bf(f1.y), (short)f2bf(f1.z), (short)f2bf(f1.w) };
        } else {
            const u16* pa = (const u16*)A + (size_t)arow * K + kc + 4 * hi;
            s16x4 q0 = *reinterpret_cast<const s16x4*>(pa);
            s16x4 q1 = *reinterpret_cast<const s16x4*>(pa + 8);
            a = s16x8{ q0.x, q0.y, q0.z, q0.w, q1.x, q1.y, q1.z, q1.w };
        }
#pragma unroll
        for (int t = 0; t < TPW; ++t) {
            const int cb = (id0 + t) % NB_C;
            const u16* pb = sW + (cb * 32 + lm) * SAP + kc + 4 * hi;
            s16x4 r0 = *reinterpret_cast<const s16x4*>(pb);
            s16x4 r1 = *reinterpret_cast<const s16x4*>(pb + 8);
            s16x8 b = { r0.x, r0.y, r0.z, r0.w, r1.x, r1.y, r1.z, r1.w };
            acc[t] = __builtin_amdgcn_mfma_f32_32x32x16_bf16(a, b, acc[t], 0, 0, 0);
        }
    }
}

// item: out = relu(0.5*(aggA@WlA + aggB@WlB + self@Wsum + bA + bB)); out != inputs
template<int KA, int KB, int KS>
__global__ __launch_bounds__(256, 4) void item_upd(
    const u16* __restrict__ aggA, const u16* __restrict__ WlAT, const float* __restrict__ bA,
    const u16* __restrict__ aggB, const u16* __restrict__ WlBT, const float* __restrict__ bB,
    const u16* __restrict__ WsumT, const u16* __restrict__ xself,
    u16* __restrict__ out, int N) {
    __shared__ u16 sW[128 * SAP];
    f32x16 acc[2];
    const int lane = threadIdx.x & 63, wid = threadIdx.x >> 6;
    const int lm = lane & 31, hi = lane >> 5;
    const int id0 = wid * 2;
    const int rb = id0 / 4;
    const int rowBase = blockIdx.x * 64;
#pragma unroll
    for (int t = 0; t < 2; ++t) {
        int cv = ((id0 + t) % 4) * 32 + lm;
        float bv = bA[cv] + bB[cv];
#pragma unroll
        for (int i = 0; i < 16; ++i) acc[t][i] = bv;
    }
    stage_w<KA, 128>(WlAT, sW);
    __syncthreads();
    gemm_pass<KA, 128, 2, false>(aggA, rowBase, N, sW, acc);
    __syncthreads();
    stage_w<KB, 128>(WlBT, sW);
    __syncthreads();
    gemm_pass<KB, 128, 2, false>(aggB, rowBase, N, sW, acc);
    __syncthreads();
    stage_w<KS, 128>(WsumT, sW);
    __syncthreads();
    gemm_pass<KS, 128, 2, false>(xself, rowBase, N, sW, acc);
#pragma unroll
    for (int t = 0; t < 2; ++t) {
        int colv = ((id0 + t) % 4) * 32 + lm;
#pragma unroll
        for (int r = 0; r < 16; ++r) {
            int row = rowBase + rb * 32 + (r & 3) + 8 * (r >> 2) + 4 * hi;
            if (row < N) out[(size_t)row * 128 + colv] = f2bf(fmaxf(0.5f * acc[t][r], 0.f));
        }
    }
}

// user: out = relu(agg@Wl + self@Wr + b); out may alias xself (barrier before writes)
template<int KA, int KS, bool SELF_F32>
__global__ __launch_bounds__(256, 4) void user_upd(
    const u16* __restrict__ agg, const u16* __restrict__ WlT, const float* __restrict__ bias,
    const u16* __restrict__ WrT, const void* xself, u16* out, int N) {
    __shared__ u16 sW[128 * SAP];
    f32x16 acc[2];
    const int lane = threadIdx.x & 63, wid = threadIdx.x >> 6;
    const int lm = lane & 31, hi = lane >> 5;
    const int id0 = wid * 2;
    const int rb = id0 / 4;
    const int rowBase = blockIdx.x * 64;
#pragma unroll
    for (int t = 0; t < 2; ++t) {
        float bv = bias[((id0 + t) % 4) * 32 + lm];
#pragma unroll
        for (int i = 0; i < 16; ++i) acc[t][i] = bv;
    }
    stage_w<KA, 128>(WlT, sW);
    __syncthreads();
    gemm_pass<KA, 128, 2, false>(agg, rowBase, N, sW, acc);
    __syncthreads();
    stage_w<KS, 128>(WrT, sW);
    __syncthreads();
    gemm_pass<KS, 128, 2, SELF_F32>(xself, rowBase, N, sW, acc);
    // in-place safety: every wave's global reads of self rows complete before any write
    __syncthreads();
#pragma unroll
    for (int t = 0; t < 2; ++t) {
        int colv = ((id0 + t) % 4) * 32 + lm;
#pragma unroll
        for (int r = 0; r < 16; ++r) {
            int row = rowBase + rb * 32 + (r & 3) + 8 * (r >> 2) + 4 * hi;
            if (row < N) out[(size_t)row * 128 + colv] = f2bf(fmaxf(acc[t][r], 0.f));
        }
    }
}

// final 128->64 linear, f32 out (out-of-place)
__global__ __launch_bounds__(256, 4) void final_upd(
    const u16* __restrict__ x, const u16* __restrict__ WfT, const float* __restrict__ bias,
    float* __restrict__ out, int N) {
    __shared__ u16 sW[64 * SAP];
    f32x16 acc[1];
    const int lane = threadIdx.x & 63, wid = threadIdx.x >> 6;
    const int lm = lane & 31, hi = lane >> 5;
    const int rb = wid / 2;
    const int rowBase = blockIdx.x * 64;
    {
        float bv = bias[(wid % 2) * 32 + lm];
#pragma unroll
        for (int i = 0; i < 16; ++i) acc[0][i] = bv;
    }
    stage_w<128, 64>(WfT, sW);
    __syncthreads();
    gemm_pass<128, 64, 1, false>(x, rowBase, N, sW, acc);
    {
        int colv = (wid % 2) * 32 + lm;
#pragma unroll
        for (int r = 0; r < 16; ++r) {
            int row = rowBase + rb * 32 + (r & 3) + 8 * (r >> 2) + 4 * hi;
            if (row < N) out[(size_t)row * 64 + colv] = acc[0][r];
        }
    }
}

// ================= host =================
static void build_csr(const int* src, const int* dst, int E, int N,
                      int* deg, int* bsum, int* rp, int* col, float* inv, hipStream_t stream) {
    const int B = 256;
    hipMemsetAsync(deg, 0, (size_t)N * sizeof(int), stream);
    deg_kernel<<<(E + B - 1) / B, B, 0, stream>>>(dst, E, deg);
    int nb = (N + 1023) / 1024;
    scanA_kernel<<<nb, B, 0, stream>>>(deg, N, bsum);
    scanB_kernel<<<1, B, 0, stream>>>(bsum, nb);
    scanC_kernel<<<nb, B, 0, stream>>>(deg, N, bsum, rp, E);
    inv_from_deg<<<(N + B - 1) / B, B, 0, stream>>>(deg, inv, N);
    hipMemsetAsync(deg, 0, (size_t)N * sizeof(int), stream);
    fill_kernel<<<(E + B - 1) / B, B, 0, stream>>>(src, dst, E, rp, deg, col);
}

extern "C" void kernel_launch(void* const* d_in, const int* in_sizes, int n_in,
                              void* d_out, int out_size, void* d_ws, size_t ws_size,
                              hipStream_t stream) {
    const float* x_user = (const float*)d_in[0];
    const float* x_item = (const float*)d_in[1];
    const int* ub_src = (const int*)d_in[2];
    const int* ub_dst = (const int*)d_in[3];
    const int* iu_src = (const int*)d_in[4];
    const int* iu_dst = (const int*)d_in[5];
    const int* ii_src = (const int*)d_in[6];
    const int* ii_dst = (const int*)d_in[7];
    const float* W1l_ub = (const float*)d_in[8];
    const float* W1r_ub = (const float*)d_in[9];
    const float* b1_ub = (const float*)d_in[10];
    const float* W1l_iu = (const float*)d_in[11];
    const float* W1r_iu = (const float*)d_in[12];
    const float* b1_iu = (const float*)d_in[13];
    const float* W1l_ii = (const float*)d_in[14];
    const float* W1r_ii = (const float*)d_in[15];
    const float* b1_ii = (const float*)d_in[16];
    const float* W23l = (const float*)d_in[17];
    const float* W23r = (const float*)d_in[18];
    const float* b23 = (const float*)d_in[19];
    const float* Wf_user = (const float*)d_in[20];
    const float* bf_user = (const float*)d_in[21];
    const float* Wf_item = (const float*)d_in[22];
    const float* bf_item = (const float*)d_in[23];

    // ---- workspace (~168 MB + optional 25.6 MB) ----
    char* p = (char*)d_ws;
    u16* xu_bf  = (u16*)p;  p += (size_t)NU_ * 128 * 2;   // 51.2 MB
    u16* xiA_bf = (u16*)p;  p += (size_t)NI_ * 128 * 2;   // 25.6
    u16* xi0_bf = (u16*)p;  p += (size_t)NI_ * 128 * 2;   // 25.6 (x_item bf16)
    u16* agg_ub = (u16*)p;  p += (size_t)NI_ * 128 * 2;   // 25.6 (deg/bsum alias pre-gather)
    u16* agg_ii = (u16*)p;  p += (size_t)NI_ * 128 * 2;   // 25.6
    u16* wt     = (u16*)p;  p += (size_t)344064 * 2;      // 0.69 (incl. 3 wsum slots)
    float* inv_iu = (float*)p; p += (size_t)NU_ * 4;
    float* inv_ub = (float*)p; p += (size_t)NI_ * 4;
    float* inv_ii = (float*)p; p += (size_t)NI_ * 4;
    int* rp_iu = (int*)p;  p += (size_t)(NU_ + 4) * 4;
    int* rp_ub = (int*)p;  p += (size_t)(NI_ + 4) * 4;
    int* rp_ii = (int*)p;  p += (size_t)(NI_ + 4) * 4;
    int* col_iu = (int*)p; p += (size_t)E_IU * 4;
    int* col_ub = (int*)p; p += (size_t)E_UB * 4;
    int* col_ii = (int*)p; p += (size_t)E_II * 4;
    // optional bf16 copy of x_user (used only if workspace is big enough)
    u16* xu0b = nullptr;
    {
        size_t used = (size_t)(p - (char*)d_ws);
        if (used + (size_t)NU_ * 64 * 2 <= ws_size) { xu0b = (u16*)p; }
    }
    // deg/bsum alias agg_ub region (CSR build completes before gathers write it)
    int* deg = (int*)agg_ub;
    int* bsum = deg + NU_;
    // d_out hosts agg_iu [NU][128] bf16 + xiB [NI][128] bf16; both dead before finals write.
    u16* agg_iu = (u16*)d_out;
    u16* xiB_bf = (u16*)((char*)d_out + (size_t)NU_ * 128 * 2);

    // weight slots (bf16, transposed [N][K])
    u16* wt_W1l_ub = wt + 0;        // [128][64]
    u16* wt_W1l_iu = wt + 24576;    // [128][128]
    u16* wt_W1r_iu = wt + 40960;    // [128][64]
    u16* wt_W1l_ii = wt + 49152;    // [128][128]
    u16* wt_W23l   = wt + 81920;    // 6 x [128][128]
    u16* wt_W23r   = wt + 180224;   // 6 x [128][128]
    u16* wt_Wf_u   = wt + 278528;   // [64][128]
    u16* wt_Wf_i   = wt + 286720;   // [64][128]
    u16* wt_Wsum   = wt + 294912;   // 3 x [128][128] presummed self weights (item)

    // ---- CSR build ----
    build_csr(iu_src, iu_dst, E_IU, NU_, deg, bsum, rp_iu, col_iu, inv_iu, stream);
    build_csr(ub_src, ub_dst, E_UB, NI_, deg, bsum, rp_ub, col_ub, inv_ub, stream);
    build_csr(ii_src, ii_dst, E_II, NI_, deg, bsum, rp_ii, col_ii, inv_ii, stream);

    // ---- conversions ----
    cvt_kernel<<<(NI_ * 32 + 255) / 256, 256, 0, stream>>>(x_item, xi0_bf, NI_ * 32);
    if (xu0b) cvt_kernel<<<(NU_ * 16 + 255) / 256, 256, 0, stream>>>(x_user, xu0b, NU_ * 16);
    wt_kernel<<<32, 256, 0, stream>>>(W1l_ub, wt_W1l_ub, 64, 128);
    wt_kernel<<<64, 256, 0, stream>>>(W1l_iu, wt_W1l_iu, 128, 128);
    wt_kernel<<<32, 256, 0, stream>>>(W1r_iu, wt_W1r_iu, 64, 128);
    wt_kernel<<<64, 256, 0, stream>>>(W1l_ii, wt_W1l_ii, 128, 128);
    wt_batch_kernel<<<384, 256, 0, stream>>>(W23l, wt_W23l, 6);
    wt_batch_kernel<<<384, 256, 0, stream>>>(W23r, wt_W23r, 6);
    wt_kernel<<<32, 256, 0, stream>>>(Wf_user, wt_Wf_u, 128, 64);
    wt_kernel<<<32, 256, 0, stream>>>(Wf_item, wt_Wf_i, 128, 64);
    // presummed item self weights: layer1 = W1r_ub + W1r_ii; layers 2-3 = W23r[l,0] + W23r[l,2]
    wt_sum_kernel<<<64, 256, 0, stream>>>(W1r_ub, W1r_ii, wt_Wsum + 0);
    wt_sum_kernel<<<64, 256, 0, stream>>>(W23r + 0 * 16384, W23r + 2 * 16384, wt_Wsum + 16384);
    wt_sum_kernel<<<64, 256, 0, stream>>>(W23r + 3 * 16384, W23r + 5 * 16384, wt_Wsum + 32768);

    const int gU = NU_ / 64;         // 3125 (exact)
    const int gI = (NI_ + 63) / 64;  // 1563 (tail clamped/guarded)
    // gather grids: threads = N * LPR
    const int ggI_b128 = (NI_ * 16 + 255) / 256;   // bf16 K=128: LPR=16
    const int ggU_b128 = (NU_ * 16 + 255) / 256;
    const int ggI_b64  = (NI_ * 8 + 255) / 256;    // bf16 K=64: LPR=8
    const int ggI_f64  = (NI_ * 16 + 255) / 256;   // f32 K=64: LPR=16

    // ---- layer 1 ----
    if (xu0b)
        gather_kernel<64, false><<<ggI_b64, 256, 0, stream>>>(xu0b, rp_ub, col_ub, inv_ub, agg_ub, NI_);
    else
        gather_kernel<64, true><<<ggI_f64, 256, 0, stream>>>(x_user, rp_ub, col_ub, inv_ub, agg_ub, NI_);
    gather_kernel<128, false><<<ggI_b128, 256, 0, stream>>>(xi0_bf, rp_ii, col_ii, inv_ii, agg_ii, NI_);
    gather_kernel<128, false><<<ggU_b128, 256, 0, stream>>>(xi0_bf, rp_iu, col_iu, inv_iu, agg_iu, NU_);
    item_upd<64, 128, 128><<<gI, 256, 0, stream>>>(
        agg_ub, wt_W1l_ub, b1_ub, agg_ii, wt_W1l_ii, b1_ii,
        wt_Wsum + 0, xi0_bf, xiA_bf, NI_);
    if (xu0b)
        user_upd<128, 64, false><<<gU, 256, 0, stream>>>(
            agg_iu, wt_W1l_iu, b1_iu, wt_W1r_iu, xu0b, xu_bf, NU_);
    else
        user_upd<128, 64, true><<<gU, 256, 0, stream>>>(
            agg_iu, wt_W1l_iu, b1_iu, wt_W1r_iu, x_user, xu_bf, NU_);

    // ---- layers 2-3 ----
    for (int l = 0; l < 2; ++l) {
        const u16* cur = (l == 0) ? xiA_bf : xiB_bf;
        u16* nxt = (l == 0) ? xiB_bf : xiA_bf;
        const u16* wl_ub = wt_W23l + (size_t)(l * 3 + 0) * 16384;
        const u16* wl_iu = wt_W23l + (size_t)(l * 3 + 1) * 16384;
        const u16* wr_iu = wt_W23r + (size_t)(l * 3 + 1) * 16384;
        const u16* wl_ii = wt_W23l + (size_t)(l * 3 + 2) * 16384;
        const u16* wsum = wt_Wsum + (size_t)(l + 1) * 16384;
        const float* b_ub = b23 + (size_t)(l * 3 + 0) * 128;
        const float* b_iu = b23 + (size_t)(l * 3 + 1) * 128;
        const float* b_ii = b23 + (size_t)(l * 3 + 2) * 128;

        gather_kernel<128, false><<<ggI_b128, 256, 0, stream>>>(xu_bf, rp_ub, col_ub, inv_ub, agg_ub, NI_);
        gather_kernel<128, false><<<ggI_b128, 256, 0, stream>>>(cur, rp_ii, col_ii, inv_ii, agg_ii, NI_);
        gather_kernel<128, false><<<ggU_b128, 256, 0, stream>>>(cur, rp_iu, col_iu, inv_iu, agg_iu, NU_);
        item_upd<128, 128, 128><<<gI, 256, 0, stream>>>(
            agg_ub, wl_ub, b_ub, agg_ii, wl_ii, b_ii,
            wsum, cur, nxt, NI_);
        user_upd<128, 128, false><<<gU, 256, 0, stream>>>(
            agg_iu, wl_iu, b_iu, wr_iu, xu_bf, xu_bf, NU_);
    }

    // ---- finals (layer-3 item output = xiA_bf); overwrite agg_iu/xiB (dead) ----
    float* out = (float*)d_out;
    final_upd<<<gU, 256, 0, stream>>>(xu_bf, wt_Wf_u, bf_user, out, NU_);
    final_upd<<<gI, 256, 0, stream>>>(xiA_bf, wt_Wf_i, bf_item, out + (size_t)NU_ * 64, NI_);
}

// Round 13
// 1061.634 us; speedup vs baseline: 3.2382x; 1.0521x over previous
//
#include <hip/hip_runtime.h>

typedef unsigned short u16;
typedef __attribute__((ext_vector_type(4))) unsigned short u16x4;
typedef __attribute__((ext_vector_type(8))) unsigned short u16x8;
typedef __attribute__((ext_vector_type(4))) short s16x4;
typedef __attribute__((ext_vector_type(8))) short s16x8;
typedef __attribute__((ext_vector_type(16))) float f32x16;

constexpr int NU_ = 200000, NI_ = 100000;
constexpr int E_UB = 1000000, E_IU = 1000000, E_II = 500000;
constexpr int SAP = 132;  // LDS row stride for final_upd's staged weights

__device__ inline float bf2f(u16 v) { return __uint_as_float(((unsigned)v) << 16); }
__device__ inline u16 f2bf(float f) {
    unsigned u = __float_as_uint(f);
    return (u16)((u + 0x7FFFu + ((u >> 16) & 1u)) >> 16);  // RNE
}

// ================= CSR build =================
__global__ void deg_kernel(const int* __restrict__ dst, int E, int* __restrict__ deg) {
    int i = blockIdx.x * blockDim.x + threadIdx.x;
    if (i < E) atomicAdd(&deg[dst[i]], 1);
}

__global__ void scanA_kernel(const int* __restrict__ deg, int N, int* __restrict__ bsum) {
    __shared__ int s[256];
    int b = blockIdx.x, t = threadIdx.x;
    int base = b * 1024 + t * 4;
    int v = 0;
#pragma unroll
    for (int j = 0; j < 4; ++j) { int i = base + j; if (i < N) v += deg[i]; }
    s[t] = v; __syncthreads();
    for (int off = 1; off < 256; off <<= 1) {
        int x = (t >= off) ? s[t - off] : 0;
        __syncthreads();
        s[t] += x;
        __syncthreads();
    }
    if (t == 255) bsum[b] = s[255];
}

__global__ void scanB_kernel(int* __restrict__ bsum, int nb) {
    __shared__ int s[256];
    int t = threadIdx.x;
    int v = (t < nb) ? bsum[t] : 0;
    s[t] = v; __syncthreads();
    for (int off = 1; off < 256; off <<= 1) {
        int x = (t >= off) ? s[t - off] : 0;
        __syncthreads();
        s[t] += x;
        __syncthreads();
    }
    if (t < nb) bsum[t] = s[t] - v;  // exclusive
}

__global__ void scanC_kernel(const int* __restrict__ deg, int N, const int* __restrict__ boff,
                             int* __restrict__ rp, int E) {
    __shared__ int s[256];
    int b = blockIdx.x, t = threadIdx.x;
    int base = b * 1024 + t * 4;
    int d[4]; int v = 0;
#pragma unroll
    for (int j = 0; j < 4; ++j) { int i = base + j; d[j] = (i < N) ? deg[i] : 0; v += d[j]; }
    s[t] = v; __syncthreads();
    for (int off = 1; off < 256; off <<= 1) {
        int x = (t >= off) ? s[t - off] : 0;
        __syncthreads();
        s[t] += x;
        __syncthreads();
    }
    int ex = boff[b] + s[t] - v;
#pragma unroll
    for (int j = 0; j < 4; ++j) { int i = base + j; if (i < N) rp[i] = ex; ex += d[j]; }
    if (b == 0 && t == 0) rp[N] = E;
}

__global__ void inv_from_deg(const int* __restrict__ deg, float* __restrict__ inv, int N) {
    int i = blockIdx.x * blockDim.x + threadIdx.x;
    if (i < N) inv[i] = 1.0f / fmaxf((float)deg[i], 1.0f);
}

__global__ void fill_kernel(const int* __restrict__ src, const int* __restrict__ dst, int E,
                            const int* __restrict__ rp, int* __restrict__ cur, int* __restrict__ col) {
    int e = blockIdx.x * blockDim.x + threadIdx.x;
    if (e < E) {
        int d = dst[e];
        int p = atomicAdd(&cur[d], 1);
        col[rp[d] + p] = src[e];
    }
}

// ================= conversions =================
__global__ void cvt_kernel(const float* __restrict__ in, u16* __restrict__ out, int n4) {
    int i = blockIdx.x * 256 + threadIdx.x;
    if (i < n4) {
        float4 v = reinterpret_cast<const float4*>(in)[i];
        u16x4 o = { f2bf(v.x), f2bf(v.y), f2bf(v.z), f2bf(v.w) };
        reinterpret_cast<u16x4*>(out)[i] = o;
    }
}

// src [K][N] f32 -> dst [N][K] bf16 (transposed)
__global__ void wt_kernel(const float* __restrict__ src, u16* __restrict__ dst, int K, int N) {
    int i = blockIdx.x * 256 + threadIdx.x;
    if (i < K * N) { int k = i / N, n = i - k * N; dst[n * K + k] = f2bf(src[i]); }
}

__global__ void wt_batch_kernel(const float* __restrict__ src, u16* __restrict__ dst, int nmat) {
    int i = blockIdx.x * 256 + threadIdx.x;
    if (i < nmat * 16384) {
        int m = i >> 14, rem = i & 16383;
        int k = rem >> 7, n = rem & 127;
        dst[(m << 14) + (n << 7) + k] = f2bf(src[i]);
    }
}

// dst[n][k] = bf16(A[k][n] + B[k][n])  (128x128)
__global__ void wt_sum_kernel(const float* __restrict__ A, const float* __restrict__ B,
                              u16* __restrict__ dst) {
    int i = blockIdx.x * 256 + threadIdx.x;
    if (i < 16384) { int k = i >> 7, n = i & 127; dst[n * 128 + k] = f2bf(A[i] + B[i]); }
}

// ================= standalone gather: 16B loads per lane (round 12, verified) =================
template<int K, bool F32SRC>
__global__ __launch_bounds__(256, 8) void gather_kernel(
    const void* __restrict__ xsrc, const int* __restrict__ rp, const int* __restrict__ col,
    const float* __restrict__ inv, u16* __restrict__ agg, int N) {
    constexpr int LPR = F32SRC ? (K / 4) : (K / 8);
    long long gt = (long long)blockIdx.x * 256 + threadIdx.x;
    int node = (int)(gt / LPR);
    int lane = (int)(gt % LPR);
    if (node >= N) return;
    int s = rp[node], e = rp[node + 1];
    float sc = inv[node];
    if constexpr (F32SRC) {
        float a0 = 0.f, a1 = 0.f, a2 = 0.f, a3 = 0.f;
        for (; s + 4 <= e; s += 4) {
            int c0 = col[s], c1 = col[s + 1], c2 = col[s + 2], c3 = col[s + 3];
            float4 v0 = reinterpret_cast<const float4*>(xsrc)[(size_t)c0 * LPR + lane];
            float4 v1 = reinterpret_cast<const float4*>(xsrc)[(size_t)c1 * LPR + lane];
            float4 v2 = reinterpret_cast<const float4*>(xsrc)[(size_t)c2 * LPR + lane];
            float4 v3 = reinterpret_cast<const float4*>(xsrc)[(size_t)c3 * LPR + lane];
            a0 += (v0.x + v1.x) + (v2.x + v3.x);
            a1 += (v0.y + v1.y) + (v2.y + v3.y);
            a2 += (v0.z + v1.z) + (v2.z + v3.z);
            a3 += (v0.w + v1.w) + (v2.w + v3.w);
        }
        for (; s < e; ++s) {
            int c = col[s];
            float4 v = reinterpret_cast<const float4*>(xsrc)[(size_t)c * LPR + lane];
            a0 += v.x; a1 += v.y; a2 += v.z; a3 += v.w;
        }
        u16x4 o = { f2bf(a0 * sc), f2bf(a1 * sc), f2bf(a2 * sc), f2bf(a3 * sc) };
        reinterpret_cast<u16x4*>(agg)[(size_t)node * LPR + lane] = o;
    } else {
        float a[8];
#pragma unroll
        for (int j = 0; j < 8; ++j) a[j] = 0.f;
        for (; s + 4 <= e; s += 4) {
            int c0 = col[s], c1 = col[s + 1], c2 = col[s + 2], c3 = col[s + 3];
            u16x8 v0 = reinterpret_cast<const u16x8*>(xsrc)[(size_t)c0 * LPR + lane];
            u16x8 v1 = reinterpret_cast<const u16x8*>(xsrc)[(size_t)c1 * LPR + lane];
            u16x8 v2 = reinterpret_cast<const u16x8*>(xsrc)[(size_t)c2 * LPR + lane];
            u16x8 v3 = reinterpret_cast<const u16x8*>(xsrc)[(size_t)c3 * LPR + lane];
#pragma unroll
            for (int j = 0; j < 8; ++j)
                a[j] += (bf2f(v0[j]) + bf2f(v1[j])) + (bf2f(v2[j]) + bf2f(v3[j]));
        }
        for (; s < e; ++s) {
            int c = col[s];
            u16x8 v = reinterpret_cast<const u16x8*>(xsrc)[(size_t)c * LPR + lane];
#pragma unroll
            for (int j = 0; j < 8; ++j) a[j] += bf2f(v[j]);
        }
        u16x8 o;
#pragma unroll
        for (int j = 0; j < 8; ++j) o[j] = f2bf(a[j] * sc);
        reinterpret_cast<u16x8*>(agg)[(size_t)node * LPR + lane] = o;
    }
}

// ================= 512-thread merged MFMA update =================
// Block = 8 waves, 128 rows x 128 cols. Both weight matrices resident in LDS
// (2 x [128 rows][128 u16] = 64 KB), 8B-granule XOR swizzle (g ^= n&SWZ) for
// conflict-free ds_reads. Wave wid: rb = wid>>1 (row block), cb0=(wid&1)*2.
// mfma_f32_32x32x16_bf16; C/D: col=lane&31, row=(r&3)+8*(r>>2)+4*(lane>>5).

__device__ inline s16x8 afrag_bf(const u16* __restrict__ A, int stride, int row, int e) {
    const u16* pa = A + (size_t)row * stride + e;
    s16x4 q0 = *reinterpret_cast<const s16x4*>(pa);
    s16x4 q1 = *reinterpret_cast<const s16x4*>(pa + 8);
    return s16x8{ q0.x, q0.y, q0.z, q0.w, q1.x, q1.y, q1.z, q1.w };
}

__device__ inline s16x8 afrag_f32(const float* __restrict__ A, int stride, int row, int e) {
    const float* pa = A + (size_t)row * stride + e;
    float4 f0 = *reinterpret_cast<const float4*>(pa);
    float4 f1 = *reinterpret_cast<const float4*>(pa + 8);
    return s16x8{ (short)f2bf(f0.x), (short)f2bf(f0.y), (short)f2bf(f0.z), (short)f2bf(f0.w),
                  (short)f2bf(f1.x), (short)f2bf(f1.y), (short)f2bf(f1.z), (short)f2bf(f1.w) };
}

// stage transposed weight [128 n-rows][K] -> LDS slot [128][128 u16], granule-swizzled
template<int K, int SWZ>
__device__ inline void stage_w_swz(const u16* __restrict__ Wt, u16* sW) {
    constexpr int CH = K / 4;           // 8B granules per row
    constexpr int TOT = 128 * CH;
#pragma unroll
    for (int i = threadIdx.x; i < TOT; i += 512) {
        int n = i / CH, g = i - n * CH;
        int gs = g ^ (n & SWZ);
        *reinterpret_cast<u16x4*>(sW + n * 128 + gs * 4) =
            *reinterpret_cast<const u16x4*>(Wt + (size_t)n * K + g * 4);
    }
}

template<int SWZ>
__device__ inline s16x8 bfrag(const u16* sW, int n, int e) {
    const u16* row = sW + n * 128;
    int m = n & SWZ;
    int g0 = ((e >> 2) ^ m) << 2;
    int g1 = (((e >> 2) + 2) ^ m) << 2;
    s16x4 r0 = *reinterpret_cast<const s16x4*>(row + g0);
    s16x4 r1 = *reinterpret_cast<const s16x4*>(row + g1);
    return s16x8{ r0.x, r0.y, r0.z, r0.w, r1.x, r1.y, r1.z, r1.w };
}

// user: out = relu(agg@Wl + self@Wr + b); out may alias xself (barrier before writes)
template<int KA, int KS, bool SELF_F32>
__global__ __launch_bounds__(512, 4) void user_upd512(
    const u16* __restrict__ agg, const u16* __restrict__ WlT, const float* __restrict__ bias,
    const u16* __restrict__ WrT, const void* xself, u16* out, int N) {
    __shared__ u16 sW[2 * 128 * 128];  // 64 KB
    u16* sW0 = sW;
    u16* sW1 = sW + 128 * 128;
    constexpr int SWA = 31;
    constexpr int SWS = (KS == 128) ? 31 : 15;
    f32x16 acc[2];
    const int lane = threadIdx.x & 63, wid = threadIdx.x >> 6;
    const int lm = lane & 31, hi = lane >> 5;
    const int rb = wid >> 1, cb0 = (wid & 1) * 2;
    const int rowBase = blockIdx.x * 128;
    const int arow = min(rowBase + rb * 32 + lm, N - 1);
#pragma unroll
    for (int t = 0; t < 2; ++t) {
        float bv = bias[(cb0 + t) * 32 + lm];
#pragma unroll
        for (int i = 0; i < 16; ++i) acc[t][i] = bv;
    }
    stage_w_swz<KA, SWA>(WlT, sW0);
    stage_w_swz<KS, SWS>(WrT, sW1);
    __syncthreads();
#pragma unroll 4
    for (int kc = 0; kc < KA; kc += 16) {
        const int e = kc + 4 * hi;
        s16x8 aA = afrag_bf(agg, KA, arow, e);
        s16x8 aS;
        if (kc < KS) {
            if constexpr (SELF_F32) aS = afrag_f32((const float*)xself, KS, arow, e);
            else aS = afrag_bf((const u16*)xself, KS, arow, e);
        }
#pragma unroll
        for (int t = 0; t < 2; ++t) {
            const int n = (cb0 + t) * 32 + lm;
            acc[t] = __builtin_amdgcn_mfma_f32_32x32x16_bf16(aA, bfrag<SWA>(sW0, n, e), acc[t], 0, 0, 0);
            if (kc < KS)
                acc[t] = __builtin_amdgcn_mfma_f32_32x32x16_bf16(aS, bfrag<SWS>(sW1, n, e), acc[t], 0, 0, 0);
        }
    }
    __syncthreads();  // in-place safety: all self reads done before any writes
#pragma unroll
    for (int t = 0; t < 2; ++t) {
        int colv = (cb0 + t) * 32 + lm;
#pragma unroll
        for (int r = 0; r < 16; ++r) {
            int row = rowBase + rb * 32 + (r & 3) + 8 * (r >> 2) + 4 * hi;
            if (row < N) out[(size_t)row * 128 + colv] = f2bf(fmaxf(acc[t][r], 0.f));
        }
    }
}

// item: out = relu(0.5*(aggA@WlA + aggB@WlB + self@Wsum + bA + bB)); out != inputs
template<int KA, int KB, int KS>
__global__ __launch_bounds__(512, 4) void item_upd512(
    const u16* __restrict__ aggA, const u16* __restrict__ WlAT, const float* __restrict__ bA,
    const u16* __restrict__ aggB, const u16* __restrict__ WlBT, const float* __restrict__ bB,
    const u16* __restrict__ WsumT, const u16* __restrict__ xself,
    u16* __restrict__ out, int N) {
    __shared__ u16 sW[2 * 128 * 128];  // 64 KB
    u16* sW0 = sW;
    u16* sW1 = sW + 128 * 128;
    constexpr int SWA = (KA == 128) ? 31 : 15;
    constexpr int SWB = 31;
    constexpr int SWS = 31;
    f32x16 acc[2];
    const int lane = threadIdx.x & 63, wid = threadIdx.x >> 6;
    const int lm = lane & 31, hi = lane >> 5;
    const int rb = wid >> 1, cb0 = (wid & 1) * 2;
    const int rowBase = blockIdx.x * 128;
    const int arow = min(rowBase + rb * 32 + lm, N - 1);
#pragma unroll
    for (int t = 0; t < 2; ++t) {
        int cv = (cb0 + t) * 32 + lm;
        float bv = bA[cv] + bB[cv];
#pragma unroll
        for (int i = 0; i < 16; ++i) acc[t][i] = bv;
    }
    stage_w_swz<KA, SWA>(WlAT, sW0);
    stage_w_swz<KB, SWB>(WlBT, sW1);
    __syncthreads();
#pragma unroll 4
    for (int kc = 0; kc < KB; kc += 16) {
        const int e = kc + 4 * hi;
        s16x8 aB = afrag_bf(aggB, KB, arow, e);
        s16x8 aA;
        if (kc < KA) aA = afrag_bf(aggA, KA, arow, e);
#pragma unroll
        for (int t = 0; t < 2; ++t) {
            const int n = (cb0 + t) * 32 + lm;
            acc[t] = __builtin_amdgcn_mfma_f32_32x32x16_bf16(aB, bfrag<SWB>(sW1, n, e), acc[t], 0, 0, 0);
            if (kc < KA)
                acc[t] = __builtin_amdgcn_mfma_f32_32x32x16_bf16(aA, bfrag<SWA>(sW0, n, e), acc[t], 0, 0, 0);
        }
    }
    __syncthreads();  // all reads of sW0 done
    stage_w_swz<KS, SWS>(WsumT, sW0);
    __syncthreads();
#pragma unroll 4
    for (int kc = 0; kc < KS; kc += 16) {
        const int e = kc + 4 * hi;
        s16x8 aS = afrag_bf(xself, KS, arow, e);
#pragma unroll
        for (int t = 0; t < 2; ++t) {
            const int n = (cb0 + t) * 32 + lm;
            acc[t] = __builtin_amdgcn_mfma_f32_32x32x16_bf16(aS, bfrag<SWS>(sW0, n, e), acc[t], 0, 0, 0);
        }
    }
#pragma unroll
    for (int t = 0; t < 2; ++t) {
        int colv = (cb0 + t) * 32 + lm;
#pragma unroll
        for (int r = 0; r < 16; ++r) {
            int row = rowBase + rb * 32 + (r & 3) + 8 * (r >> 2) + 4 * hi;
            if (row < N) out[(size_t)row * 128 + colv] = f2bf(fmaxf(0.5f * acc[t][r], 0.f));
        }
    }
}

// ================= final 128->64 linear, f32 out (round 11/12, verified) =================
template<int K, int NCOL>
__device__ inline void stage_w_sap(const u16* __restrict__ Wt, u16* sW) {
    constexpr int CH = K / 4;
    constexpr int TOT = NCOL * CH;
#pragma unroll
    for (int i = threadIdx.x; i < TOT; i += 256) {
        int n = i / CH, c = i - n * CH;
        *reinterpret_cast<u16x4*>(sW + n * SAP + c * 4) =
            *reinterpret_cast<const u16x4*>(Wt + (size_t)n * K + c * 4);
    }
}

__global__ __launch_bounds__(256, 4) void final_upd(
    const u16* __restrict__ x, const u16* __restrict__ WfT, const float* __restrict__ bias,
    float* __restrict__ out, int N) {
    __shared__ u16 sW[64 * SAP];
    f32x16 acc[1];
    const int lane = threadIdx.x & 63, wid = threadIdx.x >> 6;
    const int lm = lane & 31, hi = lane >> 5;
    const int rb = wid / 2;
    const int rowBase = blockIdx.x * 64;
    const int arow = min(rowBase + rb * 32 + lm, N - 1);
    {
        float bv = bias[(wid % 2) * 32 + lm];
#pragma unroll
        for (int i = 0; i < 16; ++i) acc[0][i] = bv;
    }
    stage_w_sap<128, 64>(WfT, sW);
    __syncthreads();
    const int cb = wid % 2;
#pragma unroll 4
    for (int kc = 0; kc < 128; kc += 16) {
        const int e = kc + 4 * hi;
        s16x8 a = afrag_bf(x, 128, arow, e);
        const u16* pb = sW + (cb * 32 + lm) * SAP + e;
        s16x4 r0 = *reinterpret_cast<const s16x4*>(pb);
        s16x4 r1 = *reinterpret_cast<const s16x4*>(pb + 8);
        s16x8 b = { r0.x, r0.y, r0.z, r0.w, r1.x, r1.y, r1.z, r1.w };
        acc[0] = __builtin_amdgcn_mfma_f32_32x32x16_bf16(a, b, acc[0], 0, 0, 0);
    }
    {
        int colv = cb * 32 + lm;
#pragma unroll
        for (int r = 0; r < 16; ++r) {
            int row = rowBase + rb * 32 + (r & 3) + 8 * (r >> 2) + 4 * hi;
            if (row < N) out[(size_t)row * 64 + colv] = acc[0][r];
        }
    }
}

// ================= host =================
static void build_csr(const int* src, const int* dst, int E, int N,
                      int* deg, int* bsum, int* rp, int* col, float* inv, hipStream_t stream) {
    const int B = 256;
    hipMemsetAsync(deg, 0, (size_t)N * sizeof(int), stream);
    deg_kernel<<<(E + B - 1) / B, B, 0, stream>>>(dst, E, deg);
    int nb = (N + 1023) / 1024;
    scanA_kernel<<<nb, B, 0, stream>>>(deg, N, bsum);
    scanB_kernel<<<1, B, 0, stream>>>(bsum, nb);
    scanC_kernel<<<nb, B, 0, stream>>>(deg, N, bsum, rp, E);
    inv_from_deg<<<(N + B - 1) / B, B, 0, stream>>>(deg, inv, N);
    hipMemsetAsync(deg, 0, (size_t)N * sizeof(int), stream);
    fill_kernel<<<(E + B - 1) / B, B, 0, stream>>>(src, dst, E, rp, deg, col);
}

extern "C" void kernel_launch(void* const* d_in, const int* in_sizes, int n_in,
                              void* d_out, int out_size, void* d_ws, size_t ws_size,
                              hipStream_t stream) {
    const float* x_user = (const float*)d_in[0];
    const float* x_item = (const float*)d_in[1];
    const int* ub_src = (const int*)d_in[2];
    const int* ub_dst = (const int*)d_in[3];
    const int* iu_src = (const int*)d_in[4];
    const int* iu_dst = (const int*)d_in[5];
    const int* ii_src = (const int*)d_in[6];
    const int* ii_dst = (const int*)d_in[7];
    const float* W1l_ub = (const float*)d_in[8];
    const float* W1r_ub = (const float*)d_in[9];
    const float* b1_ub = (const float*)d_in[10];
    const float* W1l_iu = (const float*)d_in[11];
    const float* W1r_iu = (const float*)d_in[12];
    const float* b1_iu = (const float*)d_in[13];
    const float* W1l_ii = (const float*)d_in[14];
    const float* W1r_ii = (const float*)d_in[15];
    const float* b1_ii = (const float*)d_in[16];
    const float* W23l = (const float*)d_in[17];
    const float* W23r = (const float*)d_in[18];
    const float* b23 = (const float*)d_in[19];
    const float* Wf_user = (const float*)d_in[20];
    const float* bf_user = (const float*)d_in[21];
    const float* Wf_item = (const float*)d_in[22];
    const float* bf_item = (const float*)d_in[23];

    // ---- workspace (~168 MB + optional 25.6 MB) ----
    char* p = (char*)d_ws;
    u16* xu_bf  = (u16*)p;  p += (size_t)NU_ * 128 * 2;   // 51.2 MB
    u16* xiA_bf = (u16*)p;  p += (size_t)NI_ * 128 * 2;   // 25.6
    u16* xi0_bf = (u16*)p;  p += (size_t)NI_ * 128 * 2;   // 25.6 (x_item bf16)
    u16* agg_ub = (u16*)p;  p += (size_t)NI_ * 128 * 2;   // 25.6 (deg/bsum alias pre-gather)
    u16* agg_ii = (u16*)p;  p += (size_t)NI_ * 128 * 2;   // 25.6
    u16* wt     = (u16*)p;  p += (size_t)344064 * 2;      // 0.69 (incl. 3 wsum slots)
    float* inv_iu = (float*)p; p += (size_t)NU_ * 4;
    float* inv_ub = (float*)p; p += (size_t)NI_ * 4;
    float* inv_ii = (float*)p; p += (size_t)NI_ * 4;
    int* rp_iu = (int*)p;  p += (size_t)(NU_ + 4) * 4;
    int* rp_ub = (int*)p;  p += (size_t)(NI_ + 4) * 4;
    int* rp_ii = (int*)p;  p += (size_t)(NI_ + 4) * 4;
    int* col_iu = (int*)p; p += (size_t)E_IU * 4;
    int* col_ub = (int*)p; p += (size_t)E_UB * 4;
    int* col_ii = (int*)p; p += (size_t)E_II * 4;
    // optional bf16 copy of x_user (used only if workspace is big enough)
    u16* xu0b = nullptr;
    {
        size_t used = (size_t)(p - (char*)d_ws);
        if (used + (size_t)NU_ * 64 * 2 <= ws_size) { xu0b = (u16*)p; }
    }
    // deg/bsum alias agg_ub region (CSR build completes before gathers write it)
    int* deg = (int*)agg_ub;
    int* bsum = deg + NU_;
    // d_out hosts agg_iu [NU][128] bf16 + xiB [NI][128] bf16; both dead before finals write.
    u16* agg_iu = (u16*)d_out;
    u16* xiB_bf = (u16*)((char*)d_out + (size_t)NU_ * 128 * 2);

    // weight slots (bf16, transposed [N][K])
    u16* wt_W1l_ub = wt + 0;        // [128][64]
    u16* wt_W1l_iu = wt + 24576;    // [128][128]
    u16* wt_W1r_iu = wt + 40960;    // [128][64]
    u16* wt_W1l_ii = wt + 49152;    // [128][128]
    u16* wt_W23l   = wt + 81920;    // 6 x [128][128]
    u16* wt_W23r   = wt + 180224;   // 6 x [128][128]
    u16* wt_Wf_u   = wt + 278528;   // [64][128]
    u16* wt_Wf_i   = wt + 286720;   // [64][128]
    u16* wt_Wsum   = wt + 294912;   // 3 x [128][128] presummed self weights (item)

    // ---- CSR build ----
    build_csr(iu_src, iu_dst, E_IU, NU_, deg, bsum, rp_iu, col_iu, inv_iu, stream);
    build_csr(ub_src, ub_dst, E_UB, NI_, deg, bsum, rp_ub, col_ub, inv_ub, stream);
    build_csr(ii_src, ii_dst, E_II, NI_, deg, bsum, rp_ii, col_ii, inv_ii, stream);

    // ---- conversions ----
    cvt_kernel<<<(NI_ * 32 + 255) / 256, 256, 0, stream>>>(x_item, xi0_bf, NI_ * 32);
    if (xu0b) cvt_kernel<<<(NU_ * 16 + 255) / 256, 256, 0, stream>>>(x_user, xu0b, NU_ * 16);
    wt_kernel<<<32, 256, 0, stream>>>(W1l_ub, wt_W1l_ub, 64, 128);
    wt_kernel<<<64, 256, 0, stream>>>(W1l_iu, wt_W1l_iu, 128, 128);
    wt_kernel<<<32, 256, 0, stream>>>(W1r_iu, wt_W1r_iu, 64, 128);
    wt_kernel<<<64, 256, 0, stream>>>(W1l_ii, wt_W1l_ii, 128, 128);
    wt_batch_kernel<<<384, 256, 0, stream>>>(W23l, wt_W23l, 6);
    wt_batch_kernel<<<384, 256, 0, stream>>>(W23r, wt_W23r, 6);
    wt_kernel<<<32, 256, 0, stream>>>(Wf_user, wt_Wf_u, 128, 64);
    wt_kernel<<<32, 256, 0, stream>>>(Wf_item, wt_Wf_i, 128, 64);
    // presummed item self weights: layer1 = W1r_ub + W1r_ii; layers 2-3 = W23r[l,0] + W23r[l,2]
    wt_sum_kernel<<<64, 256, 0, stream>>>(W1r_ub, W1r_ii, wt_Wsum + 0);
    wt_sum_kernel<<<64, 256, 0, stream>>>(W23r + 0 * 16384, W23r + 2 * 16384, wt_Wsum + 16384);
    wt_sum_kernel<<<64, 256, 0, stream>>>(W23r + 3 * 16384, W23r + 5 * 16384, wt_Wsum + 32768);

    const int gU2 = (NU_ + 127) / 128;  // 1563
    const int gI2 = (NI_ + 127) / 128;  // 782
    const int gUf = (NU_ + 63) / 64;    // finals
    const int gIf = (NI_ + 63) / 64;
    // gather grids: threads = N * LPR
    const int ggI_b128 = (NI_ * 16 + 255) / 256;   // bf16 K=128: LPR=16
    const int ggU_b128 = (NU_ * 16 + 255) / 256;
    const int ggI_b64  = (NI_ * 8 + 255) / 256;    // bf16 K=64: LPR=8
    const int ggI_f64  = (NI_ * 16 + 255) / 256;   // f32 K=64: LPR=16

    // ---- layer 1 ----
    if (xu0b)
        gather_kernel<64, false><<<ggI_b64, 256, 0, stream>>>(xu0b, rp_ub, col_ub, inv_ub, agg_ub, NI_);
    else
        gather_kernel<64, true><<<ggI_f64, 256, 0, stream>>>(x_user, rp_ub, col_ub, inv_ub, agg_ub, NI_);
    gather_kernel<128, false><<<ggI_b128, 256, 0, stream>>>(xi0_bf, rp_ii, col_ii, inv_ii, agg_ii, NI_);
    gather_kernel<128, false><<<ggU_b128, 256, 0, stream>>>(xi0_bf, rp_iu, col_iu, inv_iu, agg_iu, NU_);
    item_upd512<64, 128, 128><<<gI2, 512, 0, stream>>>(
        agg_ub, wt_W1l_ub, b1_ub, agg_ii, wt_W1l_ii, b1_ii,
        wt_Wsum + 0, xi0_bf, xiA_bf, NI_);
    if (xu0b)
        user_upd512<128, 64, false><<<gU2, 512, 0, stream>>>(
            agg_iu, wt_W1l_iu, b1_iu, wt_W1r_iu, xu0b, xu_bf, NU_);
    else
        user_upd512<128, 64, true><<<gU2, 512, 0, stream>>>(
            agg_iu, wt_W1l_iu, b1_iu, wt_W1r_iu, x_user, xu_bf, NU_);

    // ---- layers 2-3 ----
    for (int l = 0; l < 2; ++l) {
        const u16* cur = (l == 0) ? xiA_bf : xiB_bf;
        u16* nxt = (l == 0) ? xiB_bf : xiA_bf;
        const u16* wl_ub = wt_W23l + (size_t)(l * 3 + 0) * 16384;
        const u16* wl_iu = wt_W23l + (size_t)(l * 3 + 1) * 16384;
        const u16* wr_iu = wt_W23r + (size_t)(l * 3 + 1) * 16384;
        const u16* wl_ii = wt_W23l + (size_t)(l * 3 + 2) * 16384;
        const u16* wsum = wt_Wsum + (size_t)(l + 1) * 16384;
        const float* b_ub = b23 + (size_t)(l * 3 + 0) * 128;
        const float* b_iu = b23 + (size_t)(l * 3 + 1) * 128;
        const float* b_ii = b23 + (size_t)(l * 3 + 2) * 128;

        gather_kernel<128, false><<<ggI_b128, 256, 0, stream>>>(xu_bf, rp_ub, col_ub, inv_ub, agg_ub, NI_);
        gather_kernel<128, false><<<ggI_b128, 256, 0, stream>>>(cur, rp_ii, col_ii, inv_ii, agg_ii, NI_);
        gather_kernel<128, false><<<ggU_b128, 256, 0, stream>>>(cur, rp_iu, col_iu, inv_iu, agg_iu, NU_);
        item_upd512<128, 128, 128><<<gI2, 512, 0, stream>>>(
            agg_ub, wl_ub, b_ub, agg_ii, wl_ii, b_ii,
            wsum, cur, nxt, NI_);
        user_upd512<128, 128, false><<<gU2, 512, 0, stream>>>(
            agg_iu, wl_iu, b_iu, wr_iu, xu_bf, xu_bf, NU_);
    }

    // ---- finals (layer-3 item output = xiA_bf); overwrite agg_iu/xiB (dead) ----
    float* out = (float*)d_out;
    final_upd<<<gUf, 256, 0, stream>>>(xu_bf, wt_Wf_u, bf_user, out, NU_);
    final_upd<<<gIf, 256, 0, stream>>>(xiA_bf, wt_Wf_i, bf_item, out + (size_t)NU_ * 64, NI_);
}

// Round 14
// 1061.372 us; speedup vs baseline: 3.2390x; 1.0002x over previous
//
#include <hip/hip_runtime.h>

typedef unsigned short u16;
typedef __attribute__((ext_vector_type(4))) unsigned short u16x4;
typedef __attribute__((ext_vector_type(8))) unsigned short u16x8;
typedef __attribute__((ext_vector_type(4))) short s16x4;
typedef __attribute__((ext_vector_type(8))) short s16x8;
typedef __attribute__((ext_vector_type(16))) float f32x16;

constexpr int NU_ = 200000, NI_ = 100000;
constexpr int E_UB = 1000000, E_IU = 1000000, E_II = 500000;
constexpr int SAP = 132;  // LDS row stride for final_upd's staged weights

__device__ inline float bf2f(u16 v) { return __uint_as_float(((unsigned)v) << 16); }
__device__ inline u16 f2bf(float f) {
    unsigned u = __float_as_uint(f);
    return (u16)((u + 0x7FFFu + ((u >> 16) & 1u)) >> 16);  // RNE
}

// ================= CSR build =================
__global__ void deg_kernel(const int* __restrict__ dst, int E, int* __restrict__ deg) {
    int i = blockIdx.x * blockDim.x + threadIdx.x;
    if (i < E) atomicAdd(&deg[dst[i]], 1);
}

__global__ void scanA_kernel(const int* __restrict__ deg, int N, int* __restrict__ bsum) {
    __shared__ int s[256];
    int b = blockIdx.x, t = threadIdx.x;
    int base = b * 1024 + t * 4;
    int v = 0;
#pragma unroll
    for (int j = 0; j < 4; ++j) { int i = base + j; if (i < N) v += deg[i]; }
    s[t] = v; __syncthreads();
    for (int off = 1; off < 256; off <<= 1) {
        int x = (t >= off) ? s[t - off] : 0;
        __syncthreads();
        s[t] += x;
        __syncthreads();
    }
    if (t == 255) bsum[b] = s[255];
}

__global__ void scanB_kernel(int* __restrict__ bsum, int nb) {
    __shared__ int s[256];
    int t = threadIdx.x;
    int v = (t < nb) ? bsum[t] : 0;
    s[t] = v; __syncthreads();
    for (int off = 1; off < 256; off <<= 1) {
        int x = (t >= off) ? s[t - off] : 0;
        __syncthreads();
        s[t] += x;
        __syncthreads();
    }
    if (t < nb) bsum[t] = s[t] - v;  // exclusive
}

__global__ void scanC_kernel(const int* __restrict__ deg, int N, const int* __restrict__ boff,
                             int* __restrict__ rp, int E) {
    __shared__ int s[256];
    int b = blockIdx.x, t = threadIdx.x;
    int base = b * 1024 + t * 4;
    int d[4]; int v = 0;
#pragma unroll
    for (int j = 0; j < 4; ++j) { int i = base + j; d[j] = (i < N) ? deg[i] : 0; v += d[j]; }
    s[t] = v; __syncthreads();
    for (int off = 1; off < 256; off <<= 1) {
        int x = (t >= off) ? s[t - off] : 0;
        __syncthreads();
        s[t] += x;
        __syncthreads();
    }
    int ex = boff[b] + s[t] - v;
#pragma unroll
    for (int j = 0; j < 4; ++j) { int i = base + j; if (i < N) rp[i] = ex; ex += d[j]; }
    if (b == 0 && t == 0) rp[N] = E;
}

__global__ void inv_from_deg(const int* __restrict__ deg, float* __restrict__ inv, int N) {
    int i = blockIdx.x * blockDim.x + threadIdx.x;
    if (i < N) inv[i] = 1.0f / fmaxf((float)deg[i], 1.0f);
}

__global__ void fill_kernel(const int* __restrict__ src, const int* __restrict__ dst, int E,
                            const int* __restrict__ rp, int* __restrict__ cur, int* __restrict__ col) {
    int e = blockIdx.x * blockDim.x + threadIdx.x;
    if (e < E) {
        int d = dst[e];
        int p = atomicAdd(&cur[d], 1);
        col[rp[d] + p] = src[e];
    }
}

// ================= conversions =================
__global__ void cvt_kernel(const float* __restrict__ in, u16* __restrict__ out, int n4) {
    int i = blockIdx.x * 256 + threadIdx.x;
    if (i < n4) {
        float4 v = reinterpret_cast<const float4*>(in)[i];
        u16x4 o = { f2bf(v.x), f2bf(v.y), f2bf(v.z), f2bf(v.w) };
        reinterpret_cast<u16x4*>(out)[i] = o;
    }
}

// src [K][N] f32 -> dst [N][K] bf16 (transposed)
__global__ void wt_kernel(const float* __restrict__ src, u16* __restrict__ dst, int K, int N) {
    int i = blockIdx.x * 256 + threadIdx.x;
    if (i < K * N) { int k = i / N, n = i - k * N; dst[n * K + k] = f2bf(src[i]); }
}

__global__ void wt_batch_kernel(const float* __restrict__ src, u16* __restrict__ dst, int nmat) {
    int i = blockIdx.x * 256 + threadIdx.x;
    if (i < nmat * 16384) {
        int m = i >> 14, rem = i & 16383;
        int k = rem >> 7, n = rem & 127;
        dst[(m << 14) + (n << 7) + k] = f2bf(src[i]);
    }
}

// dst[n][k] = bf16(A[k][n] + B[k][n])  (128x128)
__global__ void wt_sum_kernel(const float* __restrict__ A, const float* __restrict__ B,
                              u16* __restrict__ dst) {
    int i = blockIdx.x * 256 + threadIdx.x;
    if (i < 16384) { int k = i >> 7, n = i & 127; dst[n * 128 + k] = f2bf(A[i] + B[i]); }
}

// ================= standalone gather: 16B loads per lane (round 12/13, verified) =================
template<int K, bool F32SRC>
__global__ __launch_bounds__(256, 8) void gather_kernel(
    const void* __restrict__ xsrc, const int* __restrict__ rp, const int* __restrict__ col,
    const float* __restrict__ inv, u16* __restrict__ agg, int N) {
    constexpr int LPR = F32SRC ? (K / 4) : (K / 8);
    long long gt = (long long)blockIdx.x * 256 + threadIdx.x;
    int node = (int)(gt / LPR);
    int lane = (int)(gt % LPR);
    if (node >= N) return;
    int s = rp[node], e = rp[node + 1];
    float sc = inv[node];
    if constexpr (F32SRC) {
        float a0 = 0.f, a1 = 0.f, a2 = 0.f, a3 = 0.f;
        for (; s + 4 <= e; s += 4) {
            int c0 = col[s], c1 = col[s + 1], c2 = col[s + 2], c3 = col[s + 3];
            float4 v0 = reinterpret_cast<const float4*>(xsrc)[(size_t)c0 * LPR + lane];
            float4 v1 = reinterpret_cast<const float4*>(xsrc)[(size_t)c1 * LPR + lane];
            float4 v2 = reinterpret_cast<const float4*>(xsrc)[(size_t)c2 * LPR + lane];
            float4 v3 = reinterpret_cast<const float4*>(xsrc)[(size_t)c3 * LPR + lane];
            a0 += (v0.x + v1.x) + (v2.x + v3.x);
            a1 += (v0.y + v1.y) + (v2.y + v3.y);
            a2 += (v0.z + v1.z) + (v2.z + v3.z);
            a3 += (v0.w + v1.w) + (v2.w + v3.w);
        }
        for (; s < e; ++s) {
            int c = col[s];
            float4 v = reinterpret_cast<const float4*>(xsrc)[(size_t)c * LPR + lane];
            a0 += v.x; a1 += v.y; a2 += v.z; a3 += v.w;
        }
        u16x4 o = { f2bf(a0 * sc), f2bf(a1 * sc), f2bf(a2 * sc), f2bf(a3 * sc) };
        reinterpret_cast<u16x4*>(agg)[(size_t)node * LPR + lane] = o;
    } else {
        float a[8];
#pragma unroll
        for (int j = 0; j < 8; ++j) a[j] = 0.f;
        for (; s + 4 <= e; s += 4) {
            int c0 = col[s], c1 = col[s + 1], c2 = col[s + 2], c3 = col[s + 3];
            u16x8 v0 = reinterpret_cast<const u16x8*>(xsrc)[(size_t)c0 * LPR + lane];
            u16x8 v1 = reinterpret_cast<const u16x8*>(xsrc)[(size_t)c1 * LPR + lane];
            u16x8 v2 = reinterpret_cast<const u16x8*>(xsrc)[(size_t)c2 * LPR + lane];
            u16x8 v3 = reinterpret_cast<const u16x8*>(xsrc)[(size_t)c3 * LPR + lane];
#pragma unroll
            for (int j = 0; j < 8; ++j)
                a[j] += (bf2f(v0[j]) + bf2f(v1[j])) + (bf2f(v2[j]) + bf2f(v3[j]));
        }
        for (; s < e; ++s) {
            int c = col[s];
            u16x8 v = reinterpret_cast<const u16x8*>(xsrc)[(size_t)c * LPR + lane];
#pragma unroll
            for (int j = 0; j < 8; ++j) a[j] += bf2f(v[j]);
        }
        u16x8 o;
#pragma unroll
        for (int j = 0; j < 8; ++j) o[j] = f2bf(a[j] * sc);
        reinterpret_cast<u16x8*>(agg)[(size_t)node * LPR + lane] = o;
    }
}

// ================= 512-thread merged MFMA update (round 13) =================
// Change this round: k-loops FULLY unrolled so the scheduler can hoist more
// independent A-loads (latency-bound per round-13 counters: MfmaUtil 7%,
// VALUBusy 17%, HBM 18%).

__device__ inline s16x8 afrag_bf(const u16* __restrict__ A, int stride, int row, int e) {
    const u16* pa = A + (size_t)row * stride + e;
    s16x4 q0 = *reinterpret_cast<const s16x4*>(pa);
    s16x4 q1 = *reinterpret_cast<const s16x4*>(pa + 8);
    return s16x8{ q0.x, q0.y, q0.z, q0.w, q1.x, q1.y, q1.z, q1.w };
}

__device__ inline s16x8 afrag_f32(const float* __restrict__ A, int stride, int row, int e) {
    const float* pa = A + (size_t)row * stride + e;
    float4 f0 = *reinterpret_cast<const float4*>(pa);
    float4 f1 = *reinterpret_cast<const float4*>(pa + 8);
    return s16x8{ (short)f2bf(f0.x), (short)f2bf(f0.y), (short)f2bf(f0.z), (short)f2bf(f0.w),
                  (short)f2bf(f1.x), (short)f2bf(f1.y), (short)f2bf(f1.z), (short)f2bf(f1.w) };
}

// stage transposed weight [128 n-rows][K] -> LDS slot [128][128 u16], granule-swizzled
template<int K, int SWZ>
__device__ inline void stage_w_swz(const u16* __restrict__ Wt, u16* sW) {
    constexpr int CH = K / 4;           // 8B granules per row
    constexpr int TOT = 128 * CH;
#pragma unroll
    for (int i = threadIdx.x; i < TOT; i += 512) {
        int n = i / CH, g = i - n * CH;
        int gs = g ^ (n & SWZ);
        *reinterpret_cast<u16x4*>(sW + n * 128 + gs * 4) =
            *reinterpret_cast<const u16x4*>(Wt + (size_t)n * K + g * 4);
    }
}

template<int SWZ>
__device__ inline s16x8 bfrag(const u16* sW, int n, int e) {
    const u16* row = sW + n * 128;
    int m = n & SWZ;
    int g0 = ((e >> 2) ^ m) << 2;
    int g1 = (((e >> 2) + 2) ^ m) << 2;
    s16x4 r0 = *reinterpret_cast<const s16x4*>(row + g0);
    s16x4 r1 = *reinterpret_cast<const s16x4*>(row + g1);
    return s16x8{ r0.x, r0.y, r0.z, r0.w, r1.x, r1.y, r1.z, r1.w };
}

// user: out = relu(agg@Wl + self@Wr + b); out may alias xself (barrier before writes)
template<int KA, int KS, bool SELF_F32>
__global__ __launch_bounds__(512, 4) void user_upd512(
    const u16* __restrict__ agg, const u16* __restrict__ WlT, const float* __restrict__ bias,
    const u16* __restrict__ WrT, const void* xself, u16* out, int N) {
    __shared__ u16 sW[2 * 128 * 128];  // 64 KB
    u16* sW0 = sW;
    u16* sW1 = sW + 128 * 128;
    constexpr int SWA = 31;
    constexpr int SWS = (KS == 128) ? 31 : 15;
    f32x16 acc[2];
    const int lane = threadIdx.x & 63, wid = threadIdx.x >> 6;
    const int lm = lane & 31, hi = lane >> 5;
    const int rb = wid >> 1, cb0 = (wid & 1) * 2;
    const int rowBase = blockIdx.x * 128;
    const int arow = min(rowBase + rb * 32 + lm, N - 1);
#pragma unroll
    for (int t = 0; t < 2; ++t) {
        float bv = bias[(cb0 + t) * 32 + lm];
#pragma unroll
        for (int i = 0; i < 16; ++i) acc[t][i] = bv;
    }
    stage_w_swz<KA, SWA>(WlT, sW0);
    stage_w_swz<KS, SWS>(WrT, sW1);
    __syncthreads();
#pragma unroll
    for (int kc = 0; kc < KA; kc += 16) {
        const int e = kc + 4 * hi;
        s16x8 aA = afrag_bf(agg, KA, arow, e);
        s16x8 aS;
        if (kc < KS) {
            if constexpr (SELF_F32) aS = afrag_f32((const float*)xself, KS, arow, e);
            else aS = afrag_bf((const u16*)xself, KS, arow, e);
        }
#pragma unroll
        for (int t = 0; t < 2; ++t) {
            const int n = (cb0 + t) * 32 + lm;
            acc[t] = __builtin_amdgcn_mfma_f32_32x32x16_bf16(aA, bfrag<SWA>(sW0, n, e), acc[t], 0, 0, 0);
            if (kc < KS)
                acc[t] = __builtin_amdgcn_mfma_f32_32x32x16_bf16(aS, bfrag<SWS>(sW1, n, e), acc[t], 0, 0, 0);
        }
    }
    __syncthreads();  // in-place safety: all self reads done before any writes
#pragma unroll
    for (int t = 0; t < 2; ++t) {
        int colv = (cb0 + t) * 32 + lm;
#pragma unroll
        for (int r = 0; r < 16; ++r) {
            int row = rowBase + rb * 32 + (r & 3) + 8 * (r >> 2) + 4 * hi;
            if (row < N) out[(size_t)row * 128 + colv] = f2bf(fmaxf(acc[t][r], 0.f));
        }
    }
}

// item: out = relu(0.5*(aggA@WlA + aggB@WlB + self@Wsum + bA + bB)); out != inputs
template<int KA, int KB, int KS>
__global__ __launch_bounds__(512, 4) void item_upd512(
    const u16* __restrict__ aggA, const u16* __restrict__ WlAT, const float* __restrict__ bA,
    const u16* __restrict__ aggB, const u16* __restrict__ WlBT, const float* __restrict__ bB,
    const u16* __restrict__ WsumT, const u16* __restrict__ xself,
    u16* __restrict__ out, int N) {
    __shared__ u16 sW[2 * 128 * 128];  // 64 KB
    u16* sW0 = sW;
    u16* sW1 = sW + 128 * 128;
    constexpr int SWA = (KA == 128) ? 31 : 15;
    constexpr int SWB = 31;
    constexpr int SWS = 31;
    f32x16 acc[2];
    const int lane = threadIdx.x & 63, wid = threadIdx.x >> 6;
    const int lm = lane & 31, hi = lane >> 5;
    const int rb = wid >> 1, cb0 = (wid & 1) * 2;
    const int rowBase = blockIdx.x * 128;
    const int arow = min(rowBase + rb * 32 + lm, N - 1);
#pragma unroll
    for (int t = 0; t < 2; ++t) {
        int cv = (cb0 + t) * 32 + lm;
        float bv = bA[cv] + bB[cv];
#pragma unroll
        for (int i = 0; i < 16; ++i) acc[t][i] = bv;
    }
    stage_w_swz<KA, SWA>(WlAT, sW0);
    stage_w_swz<KB, SWB>(WlBT, sW1);
    __syncthreads();
#pragma unroll
    for (int kc = 0; kc < KB; kc += 16) {
        const int e = kc + 4 * hi;
        s16x8 aB = afrag_bf(aggB, KB, arow, e);
        s16x8 aA;
        if (kc < KA) aA = afrag_bf(aggA, KA, arow, e);
#pragma unroll
        for (int t = 0; t < 2; ++t) {
            const int n = (cb0 + t) * 32 + lm;
            acc[t] = __builtin_amdgcn_mfma_f32_32x32x16_bf16(aB, bfrag<SWB>(sW1, n, e), acc[t], 0, 0, 0);
            if (kc < KA)
                acc[t] = __builtin_amdgcn_mfma_f32_32x32x16_bf16(aA, bfrag<SWA>(sW0, n, e), acc[t], 0, 0, 0);
        }
    }
    __syncthreads();  // all reads of sW0 done
    stage_w_swz<KS, SWS>(WsumT, sW0);
    __syncthreads();
#pragma unroll
    for (int kc = 0; kc < KS; kc += 16) {
        const int e = kc + 4 * hi;
        s16x8 aS = afrag_bf(xself, KS, arow, e);
#pragma unroll
        for (int t = 0; t < 2; ++t) {
            const int n = (cb0 + t) * 32 + lm;
            acc[t] = __builtin_amdgcn_mfma_f32_32x32x16_bf16(aS, bfrag<SWS>(sW0, n, e), acc[t], 0, 0, 0);
        }
    }
#pragma unroll
    for (int t = 0; t < 2; ++t) {
        int colv = (cb0 + t) * 32 + lm;
#pragma unroll
        for (int r = 0; r < 16; ++r) {
            int row = rowBase + rb * 32 + (r & 3) + 8 * (r >> 2) + 4 * hi;
            if (row < N) out[(size_t)row * 128 + colv] = f2bf(fmaxf(0.5f * acc[t][r], 0.f));
        }
    }
}

// ================= final 128->64 linear, f32 out (round 11-13, verified) =================
template<int K, int NCOL>
__device__ inline void stage_w_sap(const u16* __restrict__ Wt, u16* sW) {
    constexpr int CH = K / 4;
    constexpr int TOT = NCOL * CH;
#pragma unroll
    for (int i = threadIdx.x; i < TOT; i += 256) {
        int n = i / CH, c = i - n * CH;
        *reinterpret_cast<u16x4*>(sW + n * SAP + c * 4) =
            *reinterpret_cast<const u16x4*>(Wt + (size_t)n * K + c * 4);
    }
}

__global__ __launch_bounds__(256, 4) void final_upd(
    const u16* __restrict__ x, const u16* __restrict__ WfT, const float* __restrict__ bias,
    float* __restrict__ out, int N) {
    __shared__ u16 sW[64 * SAP];
    f32x16 acc[1];
    const int lane = threadIdx.x & 63, wid = threadIdx.x >> 6;
    const int lm = lane & 31, hi = lane >> 5;
    const int rb = wid / 2;
    const int rowBase = blockIdx.x * 64;
    const int arow = min(rowBase + rb * 32 + lm, N - 1);
    {
        float bv = bias[(wid % 2) * 32 + lm];
#pragma unroll
        for (int i = 0; i < 16; ++i) acc[0][i] = bv;
    }
    stage_w_sap<128, 64>(WfT, sW);
    __syncthreads();
    const int cb = wid % 2;
#pragma unroll
    for (int kc = 0; kc < 128; kc += 16) {
        const int e = kc + 4 * hi;
        s16x8 a = afrag_bf(x, 128, arow, e);
        const u16* pb = sW + (cb * 32 + lm) * SAP + e;
        s16x4 r0 = *reinterpret_cast<const s16x4*>(pb);
        s16x4 r1 = *reinterpret_cast<const s16x4*>(pb + 8);
        s16x8 b = { r0.x, r0.y, r0.z, r0.w, r1.x, r1.y, r1.z, r1.w };
        acc[0] = __builtin_amdgcn_mfma_f32_32x32x16_bf16(a, b, acc[0], 0, 0, 0);
    }
    {
        int colv = cb * 32 + lm;
#pragma unroll
        for (int r = 0; r < 16; ++r) {
            int row = rowBase + rb * 32 + (r & 3) + 8 * (r >> 2) + 4 * hi;
            if (row < N) out[(size_t)row * 64 + colv] = acc[0][r];
        }
    }
}

// ================= host =================
static void build_csr(const int* src, const int* dst, int E, int N,
                      int* deg, int* bsum, int* rp, int* col, float* inv, hipStream_t stream) {
    const int B = 256;
    hipMemsetAsync(deg, 0, (size_t)N * sizeof(int), stream);
    deg_kernel<<<(E + B - 1) / B, B, 0, stream>>>(dst, E, deg);
    int nb = (N + 1023) / 1024;
    scanA_kernel<<<nb, B, 0, stream>>>(deg, N, bsum);
    scanB_kernel<<<1, B, 0, stream>>>(bsum, nb);
    scanC_kernel<<<nb, B, 0, stream>>>(deg, N, bsum, rp, E);
    inv_from_deg<<<(N + B - 1) / B, B, 0, stream>>>(deg, inv, N);
    hipMemsetAsync(deg, 0, (size_t)N * sizeof(int), stream);
    fill_kernel<<<(E + B - 1) / B, B, 0, stream>>>(src, dst, E, rp, deg, col);
}

extern "C" void kernel_launch(void* const* d_in, const int* in_sizes, int n_in,
                              void* d_out, int out_size, void* d_ws, size_t ws_size,
                              hipStream_t stream) {
    const float* x_user = (const float*)d_in[0];
    const float* x_item = (const float*)d_in[1];
    const int* ub_src = (const int*)d_in[2];
    const int* ub_dst = (const int*)d_in[3];
    const int* iu_src = (const int*)d_in[4];
    const int* iu_dst = (const int*)d_in[5];
    const int* ii_src = (const int*)d_in[6];
    const int* ii_dst = (const int*)d_in[7];
    const float* W1l_ub = (const float*)d_in[8];
    const float* W1r_ub = (const float*)d_in[9];
    const float* b1_ub = (const float*)d_in[10];
    const float* W1l_iu = (const float*)d_in[11];
    const float* W1r_iu = (const float*)d_in[12];
    const float* b1_iu = (const float*)d_in[13];
    const float* W1l_ii = (const float*)d_in[14];
    const float* W1r_ii = (const float*)d_in[15];
    const float* b1_ii = (const float*)d_in[16];
    const float* W23l = (const float*)d_in[17];
    const float* W23r = (const float*)d_in[18];
    const float* b23 = (const float*)d_in[19];
    const float* Wf_user = (const float*)d_in[20];
    const float* bf_user = (const float*)d_in[21];
    const float* Wf_item = (const float*)d_in[22];
    const float* bf_item = (const float*)d_in[23];

    // ---- workspace (~168 MB + optional 25.6 MB) ----
    char* p = (char*)d_ws;
    u16* xu_bf  = (u16*)p;  p += (size_t)NU_ * 128 * 2;   // 51.2 MB
    u16* xiA_bf = (u16*)p;  p += (size_t)NI_ * 128 * 2;   // 25.6
    u16* xi0_bf = (u16*)p;  p += (size_t)NI_ * 128 * 2;   // 25.6 (x_item bf16)
    u16* agg_ub = (u16*)p;  p += (size_t)NI_ * 128 * 2;   // 25.6 (deg/bsum alias pre-gather)
    u16* agg_ii = (u16*)p;  p += (size_t)NI_ * 128 * 2;   // 25.6
    u16* wt     = (u16*)p;  p += (size_t)344064 * 2;      // 0.69 (incl. 3 wsum slots)
    float* inv_iu = (float*)p; p += (size_t)NU_ * 4;
    float* inv_ub = (float*)p; p += (size_t)NI_ * 4;
    float* inv_ii = (float*)p; p += (size_t)NI_ * 4;
    int* rp_iu = (int*)p;  p += (size_t)(NU_ + 4) * 4;
    int* rp_ub = (int*)p;  p += (size_t)(NI_ + 4) * 4;
    int* rp_ii = (int*)p;  p += (size_t)(NI_ + 4) * 4;
    int* col_iu = (int*)p; p += (size_t)E_IU * 4;
    int* col_ub = (int*)p; p += (size_t)E_UB * 4;
    int* col_ii = (int*)p; p += (size_t)E_II * 4;
    // optional bf16 copy of x_user (used only if workspace is big enough)
    u16* xu0b = nullptr;
    {
        size_t used = (size_t)(p - (char*)d_ws);
        if (used + (size_t)NU_ * 64 * 2 <= ws_size) { xu0b = (u16*)p; }
    }
    // deg/bsum alias agg_ub region (CSR build completes before gathers write it)
    int* deg = (int*)agg_ub;
    int* bsum = deg + NU_;
    // d_out hosts agg_iu [NU][128] bf16 + xiB [NI][128] bf16; both dead before finals write.
    u16* agg_iu = (u16*)d_out;
    u16* xiB_bf = (u16*)((char*)d_out + (size_t)NU_ * 128 * 2);

    // weight slots (bf16, transposed [N][K])
    u16* wt_W1l_ub = wt + 0;        // [128][64]
    u16* wt_W1l_iu = wt + 24576;    // [128][128]
    u16* wt_W1r_iu = wt + 40960;    // [128][64]
    u16* wt_W1l_ii = wt + 49152;    // [128][128]
    u16* wt_W23l   = wt + 81920;    // 6 x [128][128]
    u16* wt_W23r   = wt + 180224;   // 6 x [128][128]
    u16* wt_Wf_u   = wt + 278528;   // [64][128]
    u16* wt_Wf_i   = wt + 286720;   // [64][128]
    u16* wt_Wsum   = wt + 294912;   // 3 x [128][128] presummed self weights (item)

    // ---- CSR build ----
    build_csr(iu_src, iu_dst, E_IU, NU_, deg, bsum, rp_iu, col_iu, inv_iu, stream);
    build_csr(ub_src, ub_dst, E_UB, NI_, deg, bsum, rp_ub, col_ub, inv_ub, stream);
    build_csr(ii_src, ii_dst, E_II, NI_, deg, bsum, rp_ii, col_ii, inv_ii, stream);

    // ---- conversions ----
    cvt_kernel<<<(NI_ * 32 + 255) / 256, 256, 0, stream>>>(x_item, xi0_bf, NI_ * 32);
    if (xu0b) cvt_kernel<<<(NU_ * 16 + 255) / 256, 256, 0, stream>>>(x_user, xu0b, NU_ * 16);
    wt_kernel<<<32, 256, 0, stream>>>(W1l_ub, wt_W1l_ub, 64, 128);
    wt_kernel<<<64, 256, 0, stream>>>(W1l_iu, wt_W1l_iu, 128, 128);
    wt_kernel<<<32, 256, 0, stream>>>(W1r_iu, wt_W1r_iu, 64, 128);
    wt_kernel<<<64, 256, 0, stream>>>(W1l_ii, wt_W1l_ii, 128, 128);
    wt_batch_kernel<<<384, 256, 0, stream>>>(W23l, wt_W23l, 6);
    wt_batch_kernel<<<384, 256, 0, stream>>>(W23r, wt_W23r, 6);
    wt_kernel<<<32, 256, 0, stream>>>(Wf_user, wt_Wf_u, 128, 64);
    wt_kernel<<<32, 256, 0, stream>>>(Wf_item, wt_Wf_i, 128, 64);
    // presummed item self weights: layer1 = W1r_ub + W1r_ii; layers 2-3 = W23r[l,0] + W23r[l,2]
    wt_sum_kernel<<<64, 256, 0, stream>>>(W1r_ub, W1r_ii, wt_Wsum + 0);
    wt_sum_kernel<<<64, 256, 0, stream>>>(W23r + 0 * 16384, W23r + 2 * 16384, wt_Wsum + 16384);
    wt_sum_kernel<<<64, 256, 0, stream>>>(W23r + 3 * 16384, W23r + 5 * 16384, wt_Wsum + 32768);

    const int gU2 = (NU_ + 127) / 128;  // 1563
    const int gI2 = (NI_ + 127) / 128;  // 782
    const int gUf = (NU_ + 63) / 64;    // finals
    const int gIf = (NI_ + 63) / 64;
    // gather grids: threads = N * LPR
    const int ggI_b128 = (NI_ * 16 + 255) / 256;   // bf16 K=128: LPR=16
    const int ggU_b128 = (NU_ * 16 + 255) / 256;
    const int ggI_b64  = (NI_ * 8 + 255) / 256;    // bf16 K=64: LPR=8
    const int ggI_f64  = (NI_ * 16 + 255) / 256;   // f32 K=64: LPR=16

    // ---- layer 1 ----
    if (xu0b)
        gather_kernel<64, false><<<ggI_b64, 256, 0, stream>>>(xu0b, rp_ub, col_ub, inv_ub, agg_ub, NI_);
    else
        gather_kernel<64, true><<<ggI_f64, 256, 0, stream>>>(x_user, rp_ub, col_ub, inv_ub, agg_ub, NI_);
    gather_kernel<128, false><<<ggI_b128, 256, 0, stream>>>(xi0_bf, rp_ii, col_ii, inv_ii, agg_ii, NI_);
    gather_kernel<128, false><<<ggU_b128, 256, 0, stream>>>(xi0_bf, rp_iu, col_iu, inv_iu, agg_iu, NU_);
    item_upd512<64, 128, 128><<<gI2, 512, 0, stream>>>(
        agg_ub, wt_W1l_ub, b1_ub, agg_ii, wt_W1l_ii, b1_ii,
        wt_Wsum + 0, xi0_bf, xiA_bf, NI_);
    if (xu0b)
        user_upd512<128, 64, false><<<gU2, 512, 0, stream>>>(
            agg_iu, wt_W1l_iu, b1_iu, wt_W1r_iu, xu0b, xu_bf, NU_);
    else
        user_upd512<128, 64, true><<<gU2, 512, 0, stream>>>(
            agg_iu, wt_W1l_iu, b1_iu, wt_W1r_iu, x_user, xu_bf, NU_);

    // ---- layers 2-3 ----
    for (int l = 0; l < 2; ++l) {
        const u16* cur = (l == 0) ? xiA_bf : xiB_bf;
        u16* nxt = (l == 0) ? xiB_bf : xiA_bf;
        const u16* wl_ub = wt_W23l + (size_t)(l * 3 + 0) * 16384;
        const u16* wl_iu = wt_W23l + (size_t)(l * 3 + 1) * 16384;
        const u16* wr_iu = wt_W23r + (size_t)(l * 3 + 1) * 16384;
        const u16* wl_ii = wt_W23l + (size_t)(l * 3 + 2) * 16384;
        const u16* wsum = wt_Wsum + (size_t)(l + 1) * 16384;
        const float* b_ub = b23 + (size_t)(l * 3 + 0) * 128;
        const float* b_iu = b23 + (size_t)(l * 3 + 1) * 128;
        const float* b_ii = b23 + (size_t)(l * 3 + 2) * 128;

        gather_kernel<128, false><<<ggI_b128, 256, 0, stream>>>(xu_bf, rp_ub, col_ub, inv_ub, agg_ub, NI_);
        gather_kernel<128, false><<<ggI_b128, 256, 0, stream>>>(cur, rp_ii, col_ii, inv_ii, agg_ii, NI_);
        gather_kernel<128, false><<<ggU_b128, 256, 0, stream>>>(cur, rp_iu, col_iu, inv_iu, agg_iu, NU_);
        item_upd512<128, 128, 128><<<gI2, 512, 0, stream>>>(
            agg_ub, wl_ub, b_ub, agg_ii, wl_ii, b_ii,
            wsum, cur, nxt, NI_);
        user_upd512<128, 128, false><<<gU2, 512, 0, stream>>>(
            agg_iu, wl_iu, b_iu, wr_iu, xu_bf, xu_bf, NU_);
    }

    // ---- finals (layer-3 item output = xiA_bf); overwrite agg_iu/xiB (dead) ----
    float* out = (float*)d_out;
    final_upd<<<gUf, 256, 0, stream>>>(xu_bf, wt_Wf_u, bf_user, out, NU_);
    final_upd<<<gIf, 256, 0, stream>>>(xiA_bf, wt_Wf_i, bf_item, out + (size_t)NU_ * 64, NI_);
}